// Round 6
// baseline (1554.029 us; speedup 1.0000x reference)
//
#include <hip/hip_runtime.h>
#include <hip/hip_bf16.h>
#include <math.h>

typedef unsigned short ushort_t;
typedef __attribute__((ext_vector_type(8))) short bf16x8;
typedef __attribute__((ext_vector_type(4))) float floatx4;

#define B_   8
#define T_   32
#define C_   4
#define HW_  84
#define P_   14
#define GP_  6
#define LOBS 36
#define S_   39
#define L_   (T_ * S_)          // 1248
#define D_   512
#define NH_  8
#define DH_  64
#define NL_  6
#define DFF_ 2048
#define NRET 120
#define NACT 18
#define NREW 3

#define ROWS (B_ * L_)          // 9984
#define OBS_ROWS (B_ * T_ * LOBS) // 9216
#define PK   (C_ * P_ * P_)     // 784
#define PKP  800                 // PK padded to %32

// workspace layout (float units)
#define OFF_H     0                         // fp32 9984*512
#define OFF_AB1   5111808                   // bf16 9984*512
#define OFF_AB2   (OFF_AB1 + 2555904)
#define OFF_QKVB  (OFF_AB2 + 2555904)       // bf16 9984*1536
#define OFF_FFNB  (OFF_QKVB + 7667712)      // bf16 9984*2048 (aliased: VtG / Xp+obs)
#define OFF_WB    (OFF_FFNB + 10223616)     // bf16 transposed weights
#define WS_FLOATS (OFF_WB + 9641984 + 16)

static __device__ __forceinline__ ushort_t f2b(float x) {
    union { float f; unsigned int u; } v; v.f = x;
    unsigned int r = v.u + 0x7FFFu + ((v.u >> 16) & 1u);
    return (ushort_t)(r >> 16);
}

// exact-GELU via Abramowitz-Stegun 7.1.26 erf (|err| <= 1.5e-7, far below bf16 ulp)
static __device__ __forceinline__ float gelu_f(float v) {
    float z = fabsf(v) * 0.70710678118654752f;
    float t = 1.0f / (1.0f + 0.3275911f * z);
    float p = fmaf(t, 1.061405429f, -1.453152027f);
    p = fmaf(t, p, 1.421413741f);
    p = fmaf(t, p, -0.284496736f);
    p = fmaf(t, p, 0.254829592f);
    float e = 1.0f - p * t * __expf(-z * z);
    float s = v < 0.0f ? -e : e;
    return 0.5f * v * (1.0f + s);
}

static __device__ __forceinline__ void gload16(const ushort_t* g, ushort_t* l) {
    __builtin_amdgcn_global_load_lds(
        (const __attribute__((address_space(1))) void*)g,
        (__attribute__((address_space(3))) void*)l, 16, 0, 0);
}

__global__ void sentinel_kernel(float* out, int n) {
    int i = blockIdx.x * 256 + threadIdx.x;
    if (i < n) out[i] = 100.0f;
}

// ---------------- weight transpose+convert: [K][N] fp32 -> [N][K] bf16, per layer -------
__global__ __launch_bounds__(256) void transpose_cvt_kernel(
    const float* __restrict__ src, ushort_t* __restrict__ dst, int K, int N)
{
    __shared__ float tile[32][33];
    int layer = blockIdx.z;
    int n0 = blockIdx.x * 32, k0 = blockIdx.y * 32;
    int tx = threadIdx.x & 31, ty = threadIdx.x >> 5;   // 32 x 8
    const float* s = src + (size_t)layer * K * N;
    ushort_t* d = dst + (size_t)layer * N * K;
#pragma unroll
    for (int r = 0; r < 32; r += 8)
        tile[ty + r][tx] = s[(size_t)(k0 + ty + r) * N + n0 + tx];
    __syncthreads();
#pragma unroll
    for (int r = 0; r < 32; r += 8)
        d[(size_t)(n0 + ty + r) * K + k0 + tx] = f2b(tile[tx][ty + r]);
}

// patch_W [784][512] fp32 -> [512][800] bf16 (k-pad zeros)
__global__ __launch_bounds__(256) void transpose_patchw_kernel(
    const float* __restrict__ src, ushort_t* __restrict__ dst)
{
    __shared__ float tile[32][33];
    int n0 = blockIdx.x * 32, k0 = blockIdx.y * 32;
    int tx = threadIdx.x & 31, ty = threadIdx.x >> 5;
#pragma unroll
    for (int r = 0; r < 32; r += 8) {
        int k = k0 + ty + r;
        tile[ty + r][tx] = (k < PK) ? src[(size_t)k * D_ + n0 + tx] : 0.0f;
    }
    __syncthreads();
#pragma unroll
    for (int r = 0; r < 32; r += 8)
        dst[(size_t)(n0 + ty + r) * PKP + k0 + tx] = f2b(tile[tx][ty + r]);
}

// ---------------- patchify: frames fp32 -> Xp bf16 (9216 x 800) ----------------
__global__ void patchify_kernel(const float* __restrict__ frames, ushort_t* __restrict__ Xp) {
    int idx = blockIdx.x * 256 + threadIdx.x;
    if (idx >= OBS_ROWS * PKP) return;
    int r = idx / PKP, c = idx % PKP;
    if (c >= PK) { Xp[idx] = 0; return; }
    int bt = r / LOBS, p = r % LOBS;
    int gy = p / GP_, gx = p % GP_;
    int ch = c / (P_ * P_), rem = c % (P_ * P_);
    int py = rem / P_, px = rem % P_;
    size_t src = (((size_t)bt * C_ + ch) * HW_ + gy * P_ + py) * HW_ + gx * P_ + px;
    Xp[idx] = f2b(frames[src]);
}

// ---------------- MFMA GEMM: 128xBN tile (BN=128 for large-N, 64 for N=512), ----------
// ---------------- BK=64, dbuf + counted vmcnt, XOR-swizzled LDS, XCD swizzle. ---------
// ---------------- BK=32 tail for K%64 (patch embed K=800). ----------------------------
template<int BN>
__global__ __launch_bounds__(256) void gemm_mfma(
    const ushort_t* __restrict__ A, const ushort_t* __restrict__ BT,
    const float* __restrict__ bias, const float* __restrict__ residual,
    float* __restrict__ Cf, ushort_t* __restrict__ Cb,
    int M, int N, int K, int do_gelu)
{
    constexpr int NJ = BN / 32;            // B frags / MFMA cols per wave (4 or 2)
    __shared__ ushort_t As[2][128 * 64];
    __shared__ ushort_t Bs[2][BN * 64];
    int t = threadIdx.x, lane = t & 63, w = t >> 6;

    // T1: bijective XCD swizzle (m204) -- consecutive blocks per XCD share A-panel
    int nx = gridDim.x;
    int nwg = nx * (int)gridDim.y;
    int orig = blockIdx.y * nx + blockIdx.x;
    int qq = nwg >> 3, rr = nwg & 7;
    int xcd = orig & 7, loc = orig >> 3;
    int wg = (xcd < rr ? xcd * (qq + 1) : rr * (qq + 1) + (xcd - rr) * qq) + loc;
    int row0 = (wg / nx) * 128, col0 = (wg % nx) * BN;

    // 4 waves as 2M x 2N; each wave 64 x (BN/2)
    int moff = (w & 1) << 6, noff = (w >> 1) * (BN / 2);
    int l16 = lane & 15, quad = lane >> 4;
    floatx4 acc[4][NJ];
#pragma unroll
    for (int i = 0; i < 4; ++i)
#pragma unroll
        for (int j = 0; j < NJ; ++j) acc[i][j] = (floatx4){0.f, 0.f, 0.f, 0.f};

    // staging: LDS linear [row][64] (128B rows); source pre-swizzled chunk^=row&7.
    int rsub = lane >> 3;
    int csw = (lane & 7) ^ rsub;
    const ushort_t* gA = A + (size_t)(row0 + w * 8 + rsub) * K + csw * 8;
    const ushort_t* gB = BT + (size_t)(col0 + w * 8 + rsub) * K + csw * 8;
    ushort_t* lA = &As[0][0] + w * 512;
    ushort_t* lB = &Bs[0][0] + w * 512;

    int nt = K >> 6;
    // prologue: tile 0 -> buf 0
#pragma unroll
    for (int s = 0; s < 4; ++s) gload16(gA + (size_t)s * 32 * K, lA + s * 2048);
#pragma unroll
    for (int s = 0; s < NJ; ++s) gload16(gB + (size_t)s * 32 * K, lB + s * 2048);

    int ch0 = (quad ^ (l16 & 7)) * 8;   // read-side swizzled chunk offset (ushorts), k-half 0
    for (int kt = 0; kt < nt; ++kt) {
        int cur = kt & 1, nxt = cur ^ 1;
        if (kt + 1 < nt) {
            int k0n = (kt + 1) << 6;
#pragma unroll
            for (int s = 0; s < 4; ++s)
                gload16(gA + (size_t)s * 32 * K + k0n, lA + nxt * 8192 + s * 2048);
#pragma unroll
            for (int s = 0; s < NJ; ++s)
                gload16(gB + (size_t)s * 32 * K + k0n, lB + nxt * (BN * 64) + s * 2048);
            if constexpr (BN == 128)
                asm volatile("s_waitcnt vmcnt(8)" ::: "memory");  // tile kt done; kt+1 in flight
            else
                asm volatile("s_waitcnt vmcnt(6)" ::: "memory");
        } else {
            asm volatile("s_waitcnt vmcnt(0)" ::: "memory");
        }
        __builtin_amdgcn_s_barrier();          // buf[cur] fully written, all waves
        bf16x8 af0[4], af1[4], bf0[NJ], bf1[NJ];
#pragma unroll
        for (int i = 0; i < 4; ++i) {
            const ushort_t* pa = &As[cur][(moff + i * 16 + l16) * 64];
            af0[i] = *(const bf16x8*)(pa + ch0);
            af1[i] = *(const bf16x8*)(pa + (ch0 ^ 32));
        }
#pragma unroll
        for (int j = 0; j < NJ; ++j) {
            const ushort_t* pb = &Bs[cur][(noff + j * 16 + l16) * 64];
            bf0[j] = *(const bf16x8*)(pb + ch0);
            bf1[j] = *(const bf16x8*)(pb + (ch0 ^ 32));
        }
        asm volatile("s_waitcnt lgkmcnt(0)" ::: "memory");
        __builtin_amdgcn_sched_barrier(0);     // rule #18: pin MFMA below the wait
        __builtin_amdgcn_s_barrier();          // all waves done READING buf[cur]
        __builtin_amdgcn_s_setprio(1);
#pragma unroll
        for (int i = 0; i < 4; ++i)
#pragma unroll
            for (int j = 0; j < NJ; ++j) {
                acc[i][j] = __builtin_amdgcn_mfma_f32_16x16x32_bf16(af0[i], bf0[j], acc[i][j], 0, 0, 0);
                acc[i][j] = __builtin_amdgcn_mfma_f32_16x16x32_bf16(af1[i], bf1[j], acc[i][j], 0, 0, 0);
            }
        __builtin_amdgcn_s_setprio(0);
    }
    if (K & 32) {   // BK=32 tail (patch embed K=800), one shot, no swizzle
        int k0 = nt << 6;
        int g0 = 2 * w * 64 + lane;        // A: 128 rows x 4 chunks = 512 slots
        int g1 = (2 * w + 1) * 64 + lane;
        gload16(A + (size_t)(row0 + (g0 >> 2)) * K + k0 + (g0 & 3) * 8, &As[0][0] + 2 * w * 512);
        gload16(A + (size_t)(row0 + (g1 >> 2)) * K + k0 + (g1 & 3) * 8, &As[0][0] + (2 * w + 1) * 512);
        if constexpr (BN == 64) {
            int gb = w * 64 + lane;        // B: 64 rows x 4 chunks = 256 slots
            gload16(BT + (size_t)(col0 + (gb >> 2)) * K + k0 + (gb & 3) * 8, &Bs[0][0] + w * 512);
        } else {
            int gb0 = 2 * w * 64 + lane;   // B: 128 rows x 4 chunks = 512 slots
            int gb1 = (2 * w + 1) * 64 + lane;
            gload16(BT + (size_t)(col0 + (gb0 >> 2)) * K + k0 + (gb0 & 3) * 8, &Bs[0][0] + 2 * w * 512);
            gload16(BT + (size_t)(col0 + (gb1 >> 2)) * K + k0 + (gb1 & 3) * 8, &Bs[0][0] + (2 * w + 1) * 512);
        }
        asm volatile("s_waitcnt vmcnt(0)" ::: "memory");
        __builtin_amdgcn_s_barrier();
        bf16x8 af[4], bfv[NJ];
#pragma unroll
        for (int i = 0; i < 4; ++i)
            af[i] = *(const bf16x8*)&As[0][(moff + i * 16 + l16) * 32 + quad * 8];
#pragma unroll
        for (int j = 0; j < NJ; ++j)
            bfv[j] = *(const bf16x8*)&Bs[0][(noff + j * 16 + l16) * 32 + quad * 8];
        asm volatile("s_waitcnt lgkmcnt(0)" ::: "memory");
        __builtin_amdgcn_sched_barrier(0);
#pragma unroll
        for (int i = 0; i < 4; ++i)
#pragma unroll
            for (int j = 0; j < NJ; ++j)
                acc[i][j] = __builtin_amdgcn_mfma_f32_16x16x32_bf16(af[i], bfv[j], acc[i][j], 0, 0, 0);
    }
    int rquad = quad << 2;
#pragma unroll
    for (int j = 0; j < NJ; ++j) {
        int col = col0 + noff + j * 16 + l16;
        float bv = bias ? bias[col] : 0.0f;
#pragma unroll
        for (int i = 0; i < 4; ++i) {
#pragma unroll
            for (int r = 0; r < 4; ++r) {
                int row = row0 + moff + i * 16 + rquad + r;
                float v = acc[i][j][r] + bv;
                if (do_gelu) v = gelu_f(v);
                if (residual) v += residual[(size_t)row * N + col];
                if (Cf) Cf[(size_t)row * N + col] = v;
                if (Cb) Cb[(size_t)row * N + col] = f2b(v);
            }
        }
    }
}

// ---------------- assemble tokens + embeddings -> h fp32 ----------------
__global__ void assemble_kernel(const float* __restrict__ obs,
                                const int* __restrict__ rtg,
                                const int* __restrict__ act,
                                const int* __restrict__ rew,
                                const float* __restrict__ retE,
                                const float* __restrict__ actE,
                                const float* __restrict__ rewE,
                                const float* __restrict__ posE,
                                const float* __restrict__ typeE,
                                float* __restrict__ h) {
    int idx = blockIdx.x * 256 + threadIdx.x;
    if (idx >= ROWS * D_) return;
    int d = idx & (D_ - 1);
    int bl = idx / D_;
    int l = bl % L_, b = bl / L_;
    int t = l / S_, off = l % S_;
    int bt = b * T_ + t;
    float v;
    int ty;
    if (off < LOBS) {
        v = obs[((size_t)bt * LOBS + off) * D_ + d];
        ty = 0;
    } else if (off == LOBS) {
        v = retE[(size_t)rtg[bt] * D_ + d];
        ty = 1;
    } else if (off == LOBS + 1) {
        v = actE[(size_t)act[bt] * D_ + d];
        ty = 2;
    } else {
        v = rewE[(size_t)rew[bt] * D_ + d];
        ty = 3;
    }
    v += posE[(size_t)l * D_ + d] + typeE[(size_t)ty * D_ + d];
    h[idx] = v;
}

// ---------------- LayerNorm fp32 in -> bf16 out ----------------
__global__ __launch_bounds__(256) void ln_fast(const float* __restrict__ x,
                                               const float* __restrict__ g,
                                               const float* __restrict__ bb,
                                               ushort_t* __restrict__ y) {
    int row = blockIdx.x;
    const float* xr = x + (size_t)row * D_;
    ushort_t* yr = y + (size_t)row * D_;
    int tid = threadIdx.x;
    float v0 = xr[tid], v1 = xr[tid + 256];
    __shared__ float red[4];
    int lane = tid & 63, wid = tid >> 6;
    float s = v0 + v1;
#pragma unroll
    for (int off = 32; off > 0; off >>= 1) s += __shfl_down(s, off, 64);
    if (lane == 0) red[wid] = s;
    __syncthreads();
    float mean = (red[0] + red[1] + red[2] + red[3]) * (1.0f / 512.0f);
    __syncthreads();
    float d0 = v0 - mean, d1 = v1 - mean;
    float vs = d0 * d0 + d1 * d1;
#pragma unroll
    for (int off = 32; off > 0; off >>= 1) vs += __shfl_down(vs, off, 64);
    if (lane == 0) red[wid] = vs;
    __syncthreads();
    float var = (red[0] + red[1] + red[2] + red[3]) * (1.0f / 512.0f);
    float rstd = rsqrtf(var + 1e-5f);
    yr[tid]       = f2b(d0 * rstd * g[tid]       + bb[tid]);
    yr[tid + 256] = f2b(d1 * rstd * g[tid + 256] + bb[tid + 256]);
}

// ---------------- V pre-transpose per layer: qkvb V -> VtG[bh][d][l] bf16 ------------
__global__ __launch_bounds__(256) void vt_prep(const ushort_t* __restrict__ qkvb,
                                               ushort_t* __restrict__ vtg)
{
    __shared__ ushort_t tl[32][33];
    int bh = blockIdx.z; int b = bh >> 3, hh = bh & 7;
    int l0 = blockIdx.x * 32, d0 = blockIdx.y * 32;
    int tx = threadIdx.x & 31, ty = threadIdx.x >> 5;
#pragma unroll
    for (int r = 0; r < 32; r += 8)
        tl[ty + r][tx] = qkvb[((size_t)b * L_ + l0 + ty + r) * 1536 + 1024 + hh * 64 + d0 + tx];
    __syncthreads();
#pragma unroll
    for (int r = 0; r < 32; r += 8)
        vtg[((size_t)bh * 64 + d0 + ty + r) * L_ + l0 + tx] = tl[tx][ty + r];
}

// ---------------- MFMA flash attention: LDS-staged K/V shared across waves, ----------
// ---------------- dbuf global_load_lds prefetch, XOR-swizzled, XCD-grouped bh --------
__global__ __launch_bounds__(256) void attn_mfma(const ushort_t* __restrict__ qkvb,
                                                 const ushort_t* __restrict__ vtg,
                                                 ushort_t* __restrict__ outb)
{
    // T1 for attn: group all 20 q-blocks of 8 consecutive bh on one XCD so each
    // XCD's K/V working set is 8 x 320KB = 2.5MB (L2-resident). 1280 % 8 == 0.
    int orig = blockIdx.y * 64 + blockIdx.x;       // launch dim3(64,20)
    int wg = (orig & 7) * 160 + (orig >> 3);       // bijective
    int bh = wg / 20;
    int qt = 19 - (wg % 20);                       // long blocks first within XCD
    int hh = bh & 7, b = bh >> 3;
    int q0 = qt << 6;
    int t = threadIdx.x, lane = t & 63, w = t >> 6;
    int l16 = lane & 15, quad = lane >> 4;
    __shared__ ushort_t Ks[2][64 * 64];
    __shared__ ushort_t Vs[2][64 * 64];
    __shared__ ushort_t Ps[64][72];
    const ushort_t* base = qkvb + (size_t)b * (L_ * 1536);
    const ushort_t* vbase = vtg + (size_t)bh * 64 * L_;

    int qrow_l = q0 + w * 16 + l16; if (qrow_l >= L_) qrow_l = L_ - 1;
    const ushort_t* qp = base + (size_t)qrow_l * 1536 + hh * 64 + quad * 8;
    bf16x8 aq0 = *(const bf16x8*)qp;
    bf16x8 aq1 = *(const bf16x8*)(qp + 32);
    int qg[4], stepq[4], obsq[4];
#pragma unroll
    for (int r = 0; r < 4; ++r) {
        qg[r] = q0 + w * 16 + quad * 4 + r;
        stepq[r] = qg[r] / S_;
        obsq[r] = (qg[r] - stepq[r] * S_) < LOBS;
    }
    int qlast = q0 + 63; if (qlast > L_ - 1) qlast = L_ - 1;
    int kend_max = qlast;
    int we = (qlast / S_) * S_ + LOBS - 1;
    if (we > kend_max) kend_max = we;
    int ntiles = (kend_max >> 6) + 1;

    int sub = lane >> 3, jj = lane & 7;
    int jsw = jj ^ sub;                       // swizzled 16B-chunk (row&7 == sub)
    int rk0 = (w << 4) + sub, rk1 = rk0 + 8;
    const ushort_t* kcol = base + 512 + hh * 64 + jsw * 8;
    const ushort_t* vr0 = vbase + (size_t)rk0 * L_;
    const ushort_t* vr1 = vbase + (size_t)rk1 * L_;
    ushort_t* ldsK0 = &Ks[0][0] + (w << 10);
    ushort_t* ldsK1 = ldsK0 + 512;
    ushort_t* ldsV0 = &Vs[0][0] + (w << 10);
    ushort_t* ldsV1 = ldsV0 + 512;

    gload16(kcol + (size_t)rk0 * 1536, ldsK0);
    gload16(kcol + (size_t)rk1 * 1536, ldsK1);
    gload16(vr0 + jsw * 8, ldsV0);
    gload16(vr1 + jsw * 8, ldsV1);
    __syncthreads();

    float psum[4] = {0.f, 0.f, 0.f, 0.f};
    floatx4 O[4];
#pragma unroll
    for (int nb = 0; nb < 4; ++nb) O[nb] = (floatx4){0.f, 0.f, 0.f, 0.f};

    int swz = (quad ^ (l16 & 7)) << 4;        // read-side swizzled byte offset
    int buf = 0;
    for (int kt = 0; kt < ntiles; ++kt) {
        int nxt = buf ^ 1;
        if (kt + 1 < ntiles) {                // prefetch next tile (uniform branch)
            int k0n = (kt + 1) << 6;
            int g0 = k0n + rk0; if (g0 > L_ - 1) g0 = L_ - 1;
            int g1 = k0n + rk1; if (g1 > L_ - 1) g1 = L_ - 1;
            gload16(kcol + (size_t)g0 * 1536, ldsK0 + (nxt << 12));
            gload16(kcol + (size_t)g1 * 1536, ldsK1 + (nxt << 12));
            int cv = k0n + jsw * 8; if (cv > L_ - 8) cv = L_ - 8;
            gload16(vr0 + cv, ldsV0 + (nxt << 12));
            gload16(vr1 + cv, ldsV1 + (nxt << 12));
        }
        int k0 = kt << 6;
        const ushort_t* Kb = &Ks[0][0] + (buf << 12);
        const ushort_t* Vb = &Vs[0][0] + (buf << 12);
        floatx4 sc4[4];
        __builtin_amdgcn_s_setprio(1);
#pragma unroll
        for (int nb = 0; nb < 4; ++nb) {
            const char* kp = (const char*)(Kb + ((nb * 16 + l16) << 6));
            bf16x8 bk0 = *(const bf16x8*)(kp + swz);
            bf16x8 bk1 = *(const bf16x8*)(kp + (swz ^ 64));
            floatx4 z = (floatx4){0.f, 0.f, 0.f, 0.f};
            z = __builtin_amdgcn_mfma_f32_16x16x32_bf16(aq0, bk0, z, 0, 0, 0);
            z = __builtin_amdgcn_mfma_f32_16x16x32_bf16(aq1, bk1, z, 0, 0, 0);
            sc4[nb] = z;
        }
        __builtin_amdgcn_s_setprio(0);
        if (kt < qt) {
#pragma unroll
            for (int nb = 0; nb < 4; ++nb)
#pragma unroll
                for (int r = 0; r < 4; ++r) {
                    float p = __expf(sc4[nb][r] * 0.125f);
                    psum[r] += p;
                    Ps[w * 16 + quad * 4 + r][nb * 16 + l16] = f2b(p);
                }
        } else {
#pragma unroll
            for (int nb = 0; nb < 4; ++nb) {
                int kg = k0 + nb * 16 + l16;
                int stepk = kg / S_;
                int kobs = (kg - stepk * S_) < LOBS;
#pragma unroll
                for (int r = 0; r < 4; ++r) {
                    int allowed = (kg <= qg[r]) || (obsq[r] && kobs && (stepk == stepq[r]));
                    float p = allowed ? __expf(sc4[nb][r] * 0.125f) : 0.0f;
                    psum[r] += p;
                    Ps[w * 16 + quad * 4 + r][nb * 16 + l16] = f2b(p);
                }
            }
        }
        bf16x8 ap0 = *(const bf16x8*)&Ps[w * 16 + l16][quad * 8];
        bf16x8 ap1 = *(const bf16x8*)&Ps[w * 16 + l16][quad * 8 + 32];
        __builtin_amdgcn_s_setprio(1);
#pragma unroll
        for (int nb = 0; nb < 4; ++nb) {
            const char* vp = (const char*)(Vb + ((nb * 16 + l16) << 6));
            bf16x8 bv0 = *(const bf16x8*)(vp + swz);
            bf16x8 bv1 = *(const bf16x8*)(vp + (swz ^ 64));
            O[nb] = __builtin_amdgcn_mfma_f32_16x16x32_bf16(ap0, bv0, O[nb], 0, 0, 0);
            O[nb] = __builtin_amdgcn_mfma_f32_16x16x32_bf16(ap1, bv1, O[nb], 0, 0, 0);
        }
        __builtin_amdgcn_s_setprio(0);
        __syncthreads();    // drains the prefetch (vmcnt) + protects buffer reuse
        buf = nxt;
    }
#pragma unroll
    for (int off = 1; off < 16; off <<= 1)
#pragma unroll
        for (int r = 0; r < 4; ++r)
            psum[r] += __shfl_xor(psum[r], off, 64);
#pragma unroll
    for (int r = 0; r < 4; ++r) {
        if (qg[r] < L_) {
            float inv = 1.0f / psum[r];
#pragma unroll
            for (int nb = 0; nb < 4; ++nb)
                outb[((size_t)b * L_ + qg[r]) * 512 + hh * 64 + nb * 16 + l16] =
                    f2b(O[nb][r] * inv);
        }
    }
}

// ---------------- heads: LDS-staged, unrolled; one block per (b,t) ----------------
__global__ __launch_bounds__(256) void heads_fast(const float* __restrict__ h,
                            const float* __restrict__ hW_ret, const float* __restrict__ hb_ret,
                            const float* __restrict__ hW_act, const float* __restrict__ hb_act,
                            const float* __restrict__ hW_rew, const float* __restrict__ hb_rew,
                            float* __restrict__ out) {
    int bt = blockIdx.x;
    int b = bt >> 5, t = bt & 31;
    __shared__ float hr[D_], ha[D_], hw[D_];
    size_t base = ((size_t)b * L_ + (size_t)t * S_) * D_;
    int tid = threadIdx.x;
    for (int i = tid; i < D_; i += 256) {
        hr[i] = h[base + (size_t)(LOBS - 1) * D_ + i];
        ha[i] = h[base + (size_t)LOBS * D_ + i];
        hw[i] = h[base + (size_t)(LOBS + 1) * D_ + i];
    }
    __syncthreads();
    if (tid < NRET) {
        float acc = hb_ret[tid];
#pragma unroll 16
        for (int k = 0; k < D_; ++k) acc = fmaf(hr[k], hW_ret[(size_t)k * NRET + tid], acc);
        out[(size_t)bt * NRET + tid] = acc;
    } else if (tid < NRET + NACT) {
        int n = tid - NRET;
        float acc = hb_act[n];
#pragma unroll 16
        for (int k = 0; k < D_; ++k) acc = fmaf(ha[k], hW_act[(size_t)k * NACT + n], acc);
        out[(size_t)(B_ * T_ * NRET) + (size_t)bt * NACT + n] = acc;
    } else if (tid < NRET + NACT + NREW) {
        int n = tid - NRET - NACT;
        float acc = hb_rew[n];
#pragma unroll 16
        for (int k = 0; k < D_; ++k) acc = fmaf(hw[k], hW_rew[(size_t)k * NREW + n], acc);
        out[(size_t)(B_ * T_ * (NRET + NACT)) + (size_t)bt * NREW + n] = acc;
    }
}

static inline int cdiv_i(long long a, int b) { return (int)((a + b - 1) / b); }

extern "C" void kernel_launch(void* const* d_in, const int* in_sizes, int n_in,
                              void* d_out, int out_size, void* d_ws, size_t ws_size,
                              hipStream_t stream) {
    if (ws_size < (size_t)WS_FLOATS * sizeof(float)) {
        sentinel_kernel<<<(out_size + 255) / 256, 256, 0, stream>>>((float*)d_out, out_size);
        return;
    }
    const float* frames  = (const float*)d_in[0];
    const int*   rtg     = (const int*)d_in[1];
    const int*   actions = (const int*)d_in[2];
    const int*   rewards = (const int*)d_in[3];

    float* ws   = (float*)d_ws;
    float* h    = ws + OFF_H;
    ushort_t* ab1  = (ushort_t*)(ws + OFF_AB1);
    ushort_t* ab2  = (ushort_t*)(ws + OFF_AB2);
    ushort_t* qkvb = (ushort_t*)(ws + OFF_QKVB);
    ushort_t* ffnb = (ushort_t*)(ws + OFF_FFNB);
    ushort_t* vtg  = (ushort_t*)(ws + OFF_FFNB);
    ushort_t* xpb  = (ushort_t*)(ws + OFF_FFNB);
    float*    obs  = ws + OFF_FFNB + 3686400;
    ushort_t* wpatchT = (ushort_t*)(ws + OFF_WB);
    ushort_t* wqkvT = wpatchT + PKP * D_;
    ushort_t* woT   = wqkvT + NL_ * D_ * 3 * D_;
    ushort_t* w1T   = woT + NL_ * D_ * D_;
    ushort_t* w2T   = w1T + NL_ * D_ * DFF_;

    // ---- weight transpose + fp32->bf16 ----
    transpose_patchw_kernel<<<dim3(16, 25), 256, 0, stream>>>((const float*)d_in[4], wpatchT);
    transpose_cvt_kernel<<<dim3(48, 16, NL_), 256, 0, stream>>>((const float*)d_in[11], wqkvT, D_, 3 * D_);
    transpose_cvt_kernel<<<dim3(16, 16, NL_), 256, 0, stream>>>((const float*)d_in[13], woT, D_, D_);
    transpose_cvt_kernel<<<dim3(64, 16, NL_), 256, 0, stream>>>((const float*)d_in[19], w1T, D_, DFF_);
    transpose_cvt_kernel<<<dim3(16, 64, NL_), 256, 0, stream>>>((const float*)d_in[21], w2T, DFF_, D_);

    // ---- patchify + patch embed ----
    patchify_kernel<<<cdiv_i((long long)OBS_ROWS * PKP, 256), 256, 0, stream>>>(frames, xpb);
    gemm_mfma<64><<<dim3(D_ / 64, OBS_ROWS / 128), 256, 0, stream>>>(
        xpb, wpatchT, (const float*)d_in[5], nullptr, obs, nullptr, OBS_ROWS, D_, PKP, 0);

    // ---- assemble sequence ----
    assemble_kernel<<<cdiv_i((long long)ROWS * D_, 256), 256, 0, stream>>>(
        obs, rtg, actions, rewards,
        (const float*)d_in[6], (const float*)d_in[7], (const float*)d_in[8],
        (const float*)d_in[9], (const float*)d_in[10], h);

    // ---- transformer layers ----
    for (int i = 0; i < NL_; ++i) {
        ln_fast<<<ROWS, 256, 0, stream>>>(h, (const float*)d_in[15] + i * D_,
                                          (const float*)d_in[16] + i * D_, ab1);
        gemm_mfma<128><<<dim3(3 * D_ / 128, ROWS / 128), 256, 0, stream>>>(
            ab1, wqkvT + (size_t)i * D_ * 3 * D_, (const float*)d_in[12] + i * 3 * D_,
            nullptr, nullptr, qkvb, ROWS, 3 * D_, D_, 0);
        vt_prep<<<dim3(39, 2, 64), 256, 0, stream>>>(qkvb, vtg);
        attn_mfma<<<dim3(64, 20), 256, 0, stream>>>(qkvb, vtg, ab2);
        gemm_mfma<64><<<dim3(D_ / 64, ROWS / 128), 256, 0, stream>>>(
            ab2, woT + (size_t)i * D_ * D_, (const float*)d_in[14] + i * D_,
            h, h, nullptr, ROWS, D_, D_, 0);
        ln_fast<<<ROWS, 256, 0, stream>>>(h, (const float*)d_in[17] + i * D_,
                                          (const float*)d_in[18] + i * D_, ab1);
        gemm_mfma<128><<<dim3(DFF_ / 128, ROWS / 128), 256, 0, stream>>>(
            ab1, w1T + (size_t)i * D_ * DFF_, (const float*)d_in[20] + i * DFF_,
            nullptr, nullptr, ffnb, ROWS, DFF_, D_, 1);
        gemm_mfma<64><<<dim3(D_ / 64, ROWS / 128), 256, 0, stream>>>(
            ffnb, w2T + (size_t)i * DFF_ * D_, (const float*)d_in[22] + i * D_,
            h, h, nullptr, ROWS, D_, DFF_, 0);
    }

    // ---- heads ----
    heads_fast<<<B_ * T_, 256, 0, stream>>>(h,
        (const float*)d_in[23], (const float*)d_in[24],
        (const float*)d_in[25], (const float*)d_in[26],
        (const float*)d_in[27], (const float*)d_in[28], (float*)d_out);
}

// Round 7
// 1481.754 us; speedup vs baseline: 1.0488x; 1.0488x over previous
//
#include <hip/hip_runtime.h>
#include <hip/hip_bf16.h>
#include <math.h>

typedef unsigned short ushort_t;
typedef __attribute__((ext_vector_type(8))) short bf16x8;
typedef __attribute__((ext_vector_type(4))) float floatx4;

#define B_   8
#define T_   32
#define C_   4
#define HW_  84
#define P_   14
#define GP_  6
#define LOBS 36
#define S_   39
#define L_   (T_ * S_)          // 1248
#define D_   512
#define NH_  8
#define DH_  64
#define NL_  6
#define DFF_ 2048
#define NRET 120
#define NACT 18
#define NREW 3

#define ROWS (B_ * L_)          // 9984
#define OBS_ROWS (B_ * T_ * LOBS) // 9216
#define PK   (C_ * P_ * P_)     // 784
#define PKP  800                 // PK padded to %32

// workspace layout (float units)
#define OFF_H     0                         // fp32 9984*512
#define OFF_AB1   5111808                   // bf16 9984*512
#define OFF_AB2   (OFF_AB1 + 2555904)
#define OFF_QKVB  (OFF_AB2 + 2555904)       // bf16 9984*1536
#define OFF_FFNB  (OFF_QKVB + 7667712)      // bf16 9984*2048 (aliased: VtG / Xp+obs)
#define OFF_WB    (OFF_FFNB + 10223616)     // bf16 transposed weights
#define WS_FLOATS (OFF_WB + 9641984 + 16)

static __device__ __forceinline__ ushort_t f2b(float x) {
    union { float f; unsigned int u; } v; v.f = x;
    unsigned int r = v.u + 0x7FFFu + ((v.u >> 16) & 1u);
    return (ushort_t)(r >> 16);
}

// exact-GELU via Abramowitz-Stegun 7.1.26 erf (|err| <= 1.5e-7, far below bf16 ulp)
static __device__ __forceinline__ float gelu_f(float v) {
    float z = fabsf(v) * 0.70710678118654752f;
    float t = 1.0f / (1.0f + 0.3275911f * z);
    float p = fmaf(t, 1.061405429f, -1.453152027f);
    p = fmaf(t, p, 1.421413741f);
    p = fmaf(t, p, -0.284496736f);
    p = fmaf(t, p, 0.254829592f);
    float e = 1.0f - p * t * __expf(-z * z);
    float s = v < 0.0f ? -e : e;
    return 0.5f * v * (1.0f + s);
}

static __device__ __forceinline__ void gload16(const ushort_t* g, ushort_t* l) {
    __builtin_amdgcn_global_load_lds(
        (const __attribute__((address_space(1))) void*)g,
        (__attribute__((address_space(3))) void*)l, 16, 0, 0);
}

__global__ void sentinel_kernel(float* out, int n) {
    int i = blockIdx.x * 256 + threadIdx.x;
    if (i < n) out[i] = 100.0f;
}

// ---------------- weight transpose+convert: [K][N] fp32 -> [N][K] bf16, per layer -------
__global__ __launch_bounds__(256) void transpose_cvt_kernel(
    const float* __restrict__ src, ushort_t* __restrict__ dst, int K, int N)
{
    __shared__ float tile[32][33];
    int layer = blockIdx.z;
    int n0 = blockIdx.x * 32, k0 = blockIdx.y * 32;
    int tx = threadIdx.x & 31, ty = threadIdx.x >> 5;   // 32 x 8
    const float* s = src + (size_t)layer * K * N;
    ushort_t* d = dst + (size_t)layer * N * K;
#pragma unroll
    for (int r = 0; r < 32; r += 8)
        tile[ty + r][tx] = s[(size_t)(k0 + ty + r) * N + n0 + tx];
    __syncthreads();
#pragma unroll
    for (int r = 0; r < 32; r += 8)
        d[(size_t)(n0 + ty + r) * K + k0 + tx] = f2b(tile[tx][ty + r]);
}

// patch_W [784][512] fp32 -> [512][800] bf16 (k-pad zeros)
__global__ __launch_bounds__(256) void transpose_patchw_kernel(
    const float* __restrict__ src, ushort_t* __restrict__ dst)
{
    __shared__ float tile[32][33];
    int n0 = blockIdx.x * 32, k0 = blockIdx.y * 32;
    int tx = threadIdx.x & 31, ty = threadIdx.x >> 5;
#pragma unroll
    for (int r = 0; r < 32; r += 8) {
        int k = k0 + ty + r;
        tile[ty + r][tx] = (k < PK) ? src[(size_t)k * D_ + n0 + tx] : 0.0f;
    }
    __syncthreads();
#pragma unroll
    for (int r = 0; r < 32; r += 8)
        dst[(size_t)(n0 + ty + r) * PKP + k0 + tx] = f2b(tile[tx][ty + r]);
}

// ---------------- patchify: frames fp32 -> Xp bf16 (9216 x 800) ----------------
__global__ void patchify_kernel(const float* __restrict__ frames, ushort_t* __restrict__ Xp) {
    int idx = blockIdx.x * 256 + threadIdx.x;
    if (idx >= OBS_ROWS * PKP) return;
    int r = idx / PKP, c = idx % PKP;
    if (c >= PK) { Xp[idx] = 0; return; }
    int bt = r / LOBS, p = r % LOBS;
    int gy = p / GP_, gx = p % GP_;
    int ch = c / (P_ * P_), rem = c % (P_ * P_);
    int py = rem / P_, px = rem % P_;
    size_t src = (((size_t)bt * C_ + ch) * HW_ + gy * P_ + py) * HW_ + gx * P_ + px;
    Xp[idx] = f2b(frames[src]);
}

// ---------------- MFMA GEMM: 128xBN tile (BN=128 for FFN1, 64 elsewhere), -------------
// ---------------- BK=64, dbuf + counted vmcnt, XOR-swizzled LDS, XCD swizzle. ---------
// ---------------- BK=32 tail for K%64 (patch embed K=800). ----------------------------
template<int BN>
__global__ __launch_bounds__(256) void gemm_mfma(
    const ushort_t* __restrict__ A, const ushort_t* __restrict__ BT,
    const float* __restrict__ bias, const float* __restrict__ residual,
    float* __restrict__ Cf, ushort_t* __restrict__ Cb,
    int M, int N, int K, int do_gelu)
{
    constexpr int NJ = BN / 32;            // B frags / MFMA cols per wave (4 or 2)
    __shared__ ushort_t As[2][128 * 64];
    __shared__ ushort_t Bs[2][BN * 64];
    int t = threadIdx.x, lane = t & 63, w = t >> 6;

    // T1: bijective XCD swizzle (m204) -- consecutive blocks per XCD share A-panel
    int nx = gridDim.x;
    int nwg = nx * (int)gridDim.y;
    int orig = blockIdx.y * nx + blockIdx.x;
    int qq = nwg >> 3, rr = nwg & 7;
    int xcd = orig & 7, loc = orig >> 3;
    int wg = (xcd < rr ? xcd * (qq + 1) : rr * (qq + 1) + (xcd - rr) * qq) + loc;
    int row0 = (wg / nx) * 128, col0 = (wg % nx) * BN;

    // 4 waves as 2M x 2N; each wave 64 x (BN/2)
    int moff = (w & 1) << 6, noff = (w >> 1) * (BN / 2);
    int l16 = lane & 15, quad = lane >> 4;
    floatx4 acc[4][NJ];
#pragma unroll
    for (int i = 0; i < 4; ++i)
#pragma unroll
        for (int j = 0; j < NJ; ++j) acc[i][j] = (floatx4){0.f, 0.f, 0.f, 0.f};

    // staging: LDS linear [row][64] (128B rows); source pre-swizzled chunk^=row&7.
    int rsub = lane >> 3;
    int csw = (lane & 7) ^ rsub;
    const ushort_t* gA = A + (size_t)(row0 + w * 8 + rsub) * K + csw * 8;
    const ushort_t* gB = BT + (size_t)(col0 + w * 8 + rsub) * K + csw * 8;
    ushort_t* lA = &As[0][0] + w * 512;
    ushort_t* lB = &Bs[0][0] + w * 512;

    int nt = K >> 6;
    // prologue: tile 0 -> buf 0
#pragma unroll
    for (int s = 0; s < 4; ++s) gload16(gA + (size_t)s * 32 * K, lA + s * 2048);
#pragma unroll
    for (int s = 0; s < NJ; ++s) gload16(gB + (size_t)s * 32 * K, lB + s * 2048);

    int ch0 = (quad ^ (l16 & 7)) * 8;   // read-side swizzled chunk offset (ushorts), k-half 0
    for (int kt = 0; kt < nt; ++kt) {
        int cur = kt & 1, nxt = cur ^ 1;
        if (kt + 1 < nt) {
            int k0n = (kt + 1) << 6;
#pragma unroll
            for (int s = 0; s < 4; ++s)
                gload16(gA + (size_t)s * 32 * K + k0n, lA + nxt * 8192 + s * 2048);
#pragma unroll
            for (int s = 0; s < NJ; ++s)
                gload16(gB + (size_t)s * 32 * K + k0n, lB + nxt * (BN * 64) + s * 2048);
            if constexpr (BN == 128)
                asm volatile("s_waitcnt vmcnt(8)" ::: "memory");  // tile kt done; kt+1 in flight
            else
                asm volatile("s_waitcnt vmcnt(6)" ::: "memory");
        } else {
            asm volatile("s_waitcnt vmcnt(0)" ::: "memory");
        }
        __builtin_amdgcn_s_barrier();          // buf[cur] fully written, all waves
        bf16x8 af0[4], af1[4], bf0[NJ], bf1[NJ];
#pragma unroll
        for (int i = 0; i < 4; ++i) {
            const ushort_t* pa = &As[cur][(moff + i * 16 + l16) * 64];
            af0[i] = *(const bf16x8*)(pa + ch0);
            af1[i] = *(const bf16x8*)(pa + (ch0 ^ 32));
        }
#pragma unroll
        for (int j = 0; j < NJ; ++j) {
            const ushort_t* pb = &Bs[cur][(noff + j * 16 + l16) * 64];
            bf0[j] = *(const bf16x8*)(pb + ch0);
            bf1[j] = *(const bf16x8*)(pb + (ch0 ^ 32));
        }
        asm volatile("s_waitcnt lgkmcnt(0)" ::: "memory");
        __builtin_amdgcn_sched_barrier(0);     // rule #18: pin MFMA below the wait
        __builtin_amdgcn_s_barrier();          // all waves done READING buf[cur]
        __builtin_amdgcn_s_setprio(1);
#pragma unroll
        for (int i = 0; i < 4; ++i)
#pragma unroll
            for (int j = 0; j < NJ; ++j) {
                acc[i][j] = __builtin_amdgcn_mfma_f32_16x16x32_bf16(af0[i], bf0[j], acc[i][j], 0, 0, 0);
                acc[i][j] = __builtin_amdgcn_mfma_f32_16x16x32_bf16(af1[i], bf1[j], acc[i][j], 0, 0, 0);
            }
        __builtin_amdgcn_s_setprio(0);
    }
    if (K & 32) {   // BK=32 tail (patch embed K=800), one shot, no swizzle
        int k0 = nt << 6;
        int g0 = 2 * w * 64 + lane;        // A: 128 rows x 4 chunks = 512 slots
        int g1 = (2 * w + 1) * 64 + lane;
        gload16(A + (size_t)(row0 + (g0 >> 2)) * K + k0 + (g0 & 3) * 8, &As[0][0] + 2 * w * 512);
        gload16(A + (size_t)(row0 + (g1 >> 2)) * K + k0 + (g1 & 3) * 8, &As[0][0] + (2 * w + 1) * 512);
        if constexpr (BN == 64) {
            int gb = w * 64 + lane;        // B: 64 rows x 4 chunks = 256 slots
            gload16(BT + (size_t)(col0 + (gb >> 2)) * K + k0 + (gb & 3) * 8, &Bs[0][0] + w * 512);
        } else {
            int gb0 = 2 * w * 64 + lane;   // B: 128 rows x 4 chunks = 512 slots
            int gb1 = (2 * w + 1) * 64 + lane;
            gload16(BT + (size_t)(col0 + (gb0 >> 2)) * K + k0 + (gb0 & 3) * 8, &Bs[0][0] + 2 * w * 512);
            gload16(BT + (size_t)(col0 + (gb1 >> 2)) * K + k0 + (gb1 & 3) * 8, &Bs[0][0] + (2 * w + 1) * 512);
        }
        asm volatile("s_waitcnt vmcnt(0)" ::: "memory");
        __builtin_amdgcn_s_barrier();
        bf16x8 af[4], bfv[NJ];
#pragma unroll
        for (int i = 0; i < 4; ++i)
            af[i] = *(const bf16x8*)&As[0][(moff + i * 16 + l16) * 32 + quad * 8];
#pragma unroll
        for (int j = 0; j < NJ; ++j)
            bfv[j] = *(const bf16x8*)&Bs[0][(noff + j * 16 + l16) * 32 + quad * 8];
        asm volatile("s_waitcnt lgkmcnt(0)" ::: "memory");
        __builtin_amdgcn_sched_barrier(0);
#pragma unroll
        for (int i = 0; i < 4; ++i)
#pragma unroll
            for (int j = 0; j < NJ; ++j)
                acc[i][j] = __builtin_amdgcn_mfma_f32_16x16x32_bf16(af[i], bfv[j], acc[i][j], 0, 0, 0);
    }
    int rquad = quad << 2;
#pragma unroll
    for (int j = 0; j < NJ; ++j) {
        int col = col0 + noff + j * 16 + l16;
        float bv = bias ? bias[col] : 0.0f;
#pragma unroll
        for (int i = 0; i < 4; ++i) {
#pragma unroll
            for (int r = 0; r < 4; ++r) {
                int row = row0 + moff + i * 16 + rquad + r;
                float v = acc[i][j][r] + bv;
                if (do_gelu) v = gelu_f(v);
                if (residual) v += residual[(size_t)row * N + col];
                if (Cf) Cf[(size_t)row * N + col] = v;
                if (Cb) Cb[(size_t)row * N + col] = f2b(v);
            }
        }
    }
}

// ---------------- assemble tokens + embeddings -> h fp32 ----------------
__global__ void assemble_kernel(const float* __restrict__ obs,
                                const int* __restrict__ rtg,
                                const int* __restrict__ act,
                                const int* __restrict__ rew,
                                const float* __restrict__ retE,
                                const float* __restrict__ actE,
                                const float* __restrict__ rewE,
                                const float* __restrict__ posE,
                                const float* __restrict__ typeE,
                                float* __restrict__ h) {
    int idx = blockIdx.x * 256 + threadIdx.x;
    if (idx >= ROWS * D_) return;
    int d = idx & (D_ - 1);
    int bl = idx / D_;
    int l = bl % L_, b = bl / L_;
    int t = l / S_, off = l % S_;
    int bt = b * T_ + t;
    float v;
    int ty;
    if (off < LOBS) {
        v = obs[((size_t)bt * LOBS + off) * D_ + d];
        ty = 0;
    } else if (off == LOBS) {
        v = retE[(size_t)rtg[bt] * D_ + d];
        ty = 1;
    } else if (off == LOBS + 1) {
        v = actE[(size_t)act[bt] * D_ + d];
        ty = 2;
    } else {
        v = rewE[(size_t)rew[bt] * D_ + d];
        ty = 3;
    }
    v += posE[(size_t)l * D_ + d] + typeE[(size_t)ty * D_ + d];
    h[idx] = v;
}

// ---------------- LayerNorm fp32 in -> bf16 out ----------------
__global__ __launch_bounds__(256) void ln_fast(const float* __restrict__ x,
                                               const float* __restrict__ g,
                                               const float* __restrict__ bb,
                                               ushort_t* __restrict__ y) {
    int row = blockIdx.x;
    const float* xr = x + (size_t)row * D_;
    ushort_t* yr = y + (size_t)row * D_;
    int tid = threadIdx.x;
    float v0 = xr[tid], v1 = xr[tid + 256];
    __shared__ float red[4];
    int lane = tid & 63, wid = tid >> 6;
    float s = v0 + v1;
#pragma unroll
    for (int off = 32; off > 0; off >>= 1) s += __shfl_down(s, off, 64);
    if (lane == 0) red[wid] = s;
    __syncthreads();
    float mean = (red[0] + red[1] + red[2] + red[3]) * (1.0f / 512.0f);
    __syncthreads();
    float d0 = v0 - mean, d1 = v1 - mean;
    float vs = d0 * d0 + d1 * d1;
#pragma unroll
    for (int off = 32; off > 0; off >>= 1) vs += __shfl_down(vs, off, 64);
    if (lane == 0) red[wid] = vs;
    __syncthreads();
    float var = (red[0] + red[1] + red[2] + red[3]) * (1.0f / 512.0f);
    float rstd = rsqrtf(var + 1e-5f);
    yr[tid]       = f2b(d0 * rstd * g[tid]       + bb[tid]);
    yr[tid + 256] = f2b(d1 * rstd * g[tid + 256] + bb[tid + 256]);
}

// ---------------- V pre-transpose per layer: qkvb V -> VtG[bh][d][l] bf16 ------------
__global__ __launch_bounds__(256) void vt_prep(const ushort_t* __restrict__ qkvb,
                                               ushort_t* __restrict__ vtg)
{
    __shared__ ushort_t tl[32][33];
    int bh = blockIdx.z; int b = bh >> 3, hh = bh & 7;
    int l0 = blockIdx.x * 32, d0 = blockIdx.y * 32;
    int tx = threadIdx.x & 31, ty = threadIdx.x >> 5;
#pragma unroll
    for (int r = 0; r < 32; r += 8)
        tl[ty + r][tx] = qkvb[((size_t)b * L_ + l0 + ty + r) * 1536 + 1024 + hh * 64 + d0 + tx];
    __syncthreads();
#pragma unroll
    for (int r = 0; r < 32; r += 8)
        vtg[((size_t)bh * 64 + d0 + ty + r) * L_ + l0 + tx] = tl[tx][ty + r];
}

// ---------------- MFMA flash attention: LDS-staged K/V shared across waves, ----------
// ---------------- double-buffered global_load_lds prefetch, XOR-swizzled ------------
__global__ __launch_bounds__(256) void attn_mfma(const ushort_t* __restrict__ qkvb,
                                                 const ushort_t* __restrict__ vtg,
                                                 ushort_t* __restrict__ outb)
{
    int bh = blockIdx.x; int hh = bh & 7, b = bh >> 3;
    int qt = 19 - blockIdx.y;            // long blocks first (tail scheduling)
    int q0 = qt << 6;
    int t = threadIdx.x, lane = t & 63, w = t >> 6;
    int l16 = lane & 15, quad = lane >> 4;
    __shared__ ushort_t Ks[2][64 * 64];
    __shared__ ushort_t Vs[2][64 * 64];
    __shared__ ushort_t Ps[64][72];
    const ushort_t* base = qkvb + (size_t)b * (L_ * 1536);
    const ushort_t* vbase = vtg + (size_t)bh * 64 * L_;

    int qrow_l = q0 + w * 16 + l16; if (qrow_l >= L_) qrow_l = L_ - 1;
    const ushort_t* qp = base + (size_t)qrow_l * 1536 + hh * 64 + quad * 8;
    bf16x8 aq0 = *(const bf16x8*)qp;
    bf16x8 aq1 = *(const bf16x8*)(qp + 32);
    int qg[4], stepq[4], obsq[4];
#pragma unroll
    for (int r = 0; r < 4; ++r) {
        qg[r] = q0 + w * 16 + quad * 4 + r;
        stepq[r] = qg[r] / S_;
        obsq[r] = (qg[r] - stepq[r] * S_) < LOBS;
    }
    int qlast = q0 + 63; if (qlast > L_ - 1) qlast = L_ - 1;
    int kend_max = qlast;
    int we = (qlast / S_) * S_ + LOBS - 1;
    if (we > kend_max) kend_max = we;
    int ntiles = (kend_max >> 6) + 1;

    int sub = lane >> 3, jj = lane & 7;
    int jsw = jj ^ sub;                       // swizzled 16B-chunk (row&7 == sub)
    int rk0 = (w << 4) + sub, rk1 = rk0 + 8;
    const ushort_t* kcol = base + 512 + hh * 64 + jsw * 8;
    const ushort_t* vr0 = vbase + (size_t)rk0 * L_;
    const ushort_t* vr1 = vbase + (size_t)rk1 * L_;
    ushort_t* ldsK0 = &Ks[0][0] + (w << 10);
    ushort_t* ldsK1 = ldsK0 + 512;
    ushort_t* ldsV0 = &Vs[0][0] + (w << 10);
    ushort_t* ldsV1 = ldsV0 + 512;

    gload16(kcol + (size_t)rk0 * 1536, ldsK0);
    gload16(kcol + (size_t)rk1 * 1536, ldsK1);
    gload16(vr0 + jsw * 8, ldsV0);
    gload16(vr1 + jsw * 8, ldsV1);
    __syncthreads();

    float psum[4] = {0.f, 0.f, 0.f, 0.f};
    floatx4 O[4];
#pragma unroll
    for (int nb = 0; nb < 4; ++nb) O[nb] = (floatx4){0.f, 0.f, 0.f, 0.f};

    int swz = (quad ^ (l16 & 7)) << 4;        // read-side swizzled byte offset
    int buf = 0;
    for (int kt = 0; kt < ntiles; ++kt) {
        int nxt = buf ^ 1;
        if (kt + 1 < ntiles) {                // prefetch next tile (uniform branch)
            int k0n = (kt + 1) << 6;
            int g0 = k0n + rk0; if (g0 > L_ - 1) g0 = L_ - 1;
            int g1 = k0n + rk1; if (g1 > L_ - 1) g1 = L_ - 1;
            gload16(kcol + (size_t)g0 * 1536, ldsK0 + (nxt << 12));
            gload16(kcol + (size_t)g1 * 1536, ldsK1 + (nxt << 12));
            int cv = k0n + jsw * 8; if (cv > L_ - 8) cv = L_ - 8;
            gload16(vr0 + cv, ldsV0 + (nxt << 12));
            gload16(vr1 + cv, ldsV1 + (nxt << 12));
        }
        int k0 = kt << 6;
        const ushort_t* Kb = &Ks[0][0] + (buf << 12);
        const ushort_t* Vb = &Vs[0][0] + (buf << 12);
        floatx4 sc4[4];
        __builtin_amdgcn_s_setprio(1);
#pragma unroll
        for (int nb = 0; nb < 4; ++nb) {
            const char* kp = (const char*)(Kb + ((nb * 16 + l16) << 6));
            bf16x8 bk0 = *(const bf16x8*)(kp + swz);
            bf16x8 bk1 = *(const bf16x8*)(kp + (swz ^ 64));
            floatx4 z = (floatx4){0.f, 0.f, 0.f, 0.f};
            z = __builtin_amdgcn_mfma_f32_16x16x32_bf16(aq0, bk0, z, 0, 0, 0);
            z = __builtin_amdgcn_mfma_f32_16x16x32_bf16(aq1, bk1, z, 0, 0, 0);
            sc4[nb] = z;
        }
        __builtin_amdgcn_s_setprio(0);
        if (kt < qt) {
#pragma unroll
            for (int nb = 0; nb < 4; ++nb)
#pragma unroll
                for (int r = 0; r < 4; ++r) {
                    float p = __expf(sc4[nb][r] * 0.125f);
                    psum[r] += p;
                    Ps[w * 16 + quad * 4 + r][nb * 16 + l16] = f2b(p);
                }
        } else {
#pragma unroll
            for (int nb = 0; nb < 4; ++nb) {
                int kg = k0 + nb * 16 + l16;
                int stepk = kg / S_;
                int kobs = (kg - stepk * S_) < LOBS;
#pragma unroll
                for (int r = 0; r < 4; ++r) {
                    int allowed = (kg <= qg[r]) || (obsq[r] && kobs && (stepk == stepq[r]));
                    float p = allowed ? __expf(sc4[nb][r] * 0.125f) : 0.0f;
                    psum[r] += p;
                    Ps[w * 16 + quad * 4 + r][nb * 16 + l16] = f2b(p);
                }
            }
        }
        bf16x8 ap0 = *(const bf16x8*)&Ps[w * 16 + l16][quad * 8];
        bf16x8 ap1 = *(const bf16x8*)&Ps[w * 16 + l16][quad * 8 + 32];
        __builtin_amdgcn_s_setprio(1);
#pragma unroll
        for (int nb = 0; nb < 4; ++nb) {
            const char* vp = (const char*)(Vb + ((nb * 16 + l16) << 6));
            bf16x8 bv0 = *(const bf16x8*)(vp + swz);
            bf16x8 bv1 = *(const bf16x8*)(vp + (swz ^ 64));
            O[nb] = __builtin_amdgcn_mfma_f32_16x16x32_bf16(ap0, bv0, O[nb], 0, 0, 0);
            O[nb] = __builtin_amdgcn_mfma_f32_16x16x32_bf16(ap1, bv1, O[nb], 0, 0, 0);
        }
        __builtin_amdgcn_s_setprio(0);
        __syncthreads();    // drains the prefetch (vmcnt) + protects buffer reuse
        buf = nxt;
    }
#pragma unroll
    for (int off = 1; off < 16; off <<= 1)
#pragma unroll
        for (int r = 0; r < 4; ++r)
            psum[r] += __shfl_xor(psum[r], off, 64);
#pragma unroll
    for (int r = 0; r < 4; ++r) {
        if (qg[r] < L_) {
            float inv = 1.0f / psum[r];
#pragma unroll
            for (int nb = 0; nb < 4; ++nb)
                outb[((size_t)b * L_ + qg[r]) * 512 + hh * 64 + nb * 16 + l16] =
                    f2b(O[nb][r] * inv);
        }
    }
}

// ---------------- heads: LDS-staged, unrolled; one block per (b,t) ----------------
__global__ __launch_bounds__(256) void heads_fast(const float* __restrict__ h,
                            const float* __restrict__ hW_ret, const float* __restrict__ hb_ret,
                            const float* __restrict__ hW_act, const float* __restrict__ hb_act,
                            const float* __restrict__ hW_rew, const float* __restrict__ hb_rew,
                            float* __restrict__ out) {
    int bt = blockIdx.x;
    int b = bt >> 5, t = bt & 31;
    __shared__ float hr[D_], ha[D_], hw[D_];
    size_t base = ((size_t)b * L_ + (size_t)t * S_) * D_;
    int tid = threadIdx.x;
    for (int i = tid; i < D_; i += 256) {
        hr[i] = h[base + (size_t)(LOBS - 1) * D_ + i];
        ha[i] = h[base + (size_t)LOBS * D_ + i];
        hw[i] = h[base + (size_t)(LOBS + 1) * D_ + i];
    }
    __syncthreads();
    if (tid < NRET) {
        float acc = hb_ret[tid];
#pragma unroll 16
        for (int k = 0; k < D_; ++k) acc = fmaf(hr[k], hW_ret[(size_t)k * NRET + tid], acc);
        out[(size_t)bt * NRET + tid] = acc;
    } else if (tid < NRET + NACT) {
        int n = tid - NRET;
        float acc = hb_act[n];
#pragma unroll 16
        for (int k = 0; k < D_; ++k) acc = fmaf(ha[k], hW_act[(size_t)k * NACT + n], acc);
        out[(size_t)(B_ * T_ * NRET) + (size_t)bt * NACT + n] = acc;
    } else if (tid < NRET + NACT + NREW) {
        int n = tid - NRET - NACT;
        float acc = hb_rew[n];
#pragma unroll 16
        for (int k = 0; k < D_; ++k) acc = fmaf(hw[k], hW_rew[(size_t)k * NREW + n], acc);
        out[(size_t)(B_ * T_ * (NRET + NACT)) + (size_t)bt * NREW + n] = acc;
    }
}

static inline int cdiv_i(long long a, int b) { return (int)((a + b - 1) / b); }

extern "C" void kernel_launch(void* const* d_in, const int* in_sizes, int n_in,
                              void* d_out, int out_size, void* d_ws, size_t ws_size,
                              hipStream_t stream) {
    if (ws_size < (size_t)WS_FLOATS * sizeof(float)) {
        sentinel_kernel<<<(out_size + 255) / 256, 256, 0, stream>>>((float*)d_out, out_size);
        return;
    }
    const float* frames  = (const float*)d_in[0];
    const int*   rtg     = (const int*)d_in[1];
    const int*   actions = (const int*)d_in[2];
    const int*   rewards = (const int*)d_in[3];

    float* ws   = (float*)d_ws;
    float* h    = ws + OFF_H;
    ushort_t* ab1  = (ushort_t*)(ws + OFF_AB1);
    ushort_t* ab2  = (ushort_t*)(ws + OFF_AB2);
    ushort_t* qkvb = (ushort_t*)(ws + OFF_QKVB);
    ushort_t* ffnb = (ushort_t*)(ws + OFF_FFNB);
    ushort_t* vtg  = (ushort_t*)(ws + OFF_FFNB);
    ushort_t* xpb  = (ushort_t*)(ws + OFF_FFNB);
    float*    obs  = ws + OFF_FFNB + 3686400;
    ushort_t* wpatchT = (ushort_t*)(ws + OFF_WB);
    ushort_t* wqkvT = wpatchT + PKP * D_;
    ushort_t* woT   = wqkvT + NL_ * D_ * 3 * D_;
    ushort_t* w1T   = woT + NL_ * D_ * D_;
    ushort_t* w2T   = w1T + NL_ * D_ * DFF_;

    // ---- weight transpose + fp32->bf16 ----
    transpose_patchw_kernel<<<dim3(16, 25), 256, 0, stream>>>((const float*)d_in[4], wpatchT);
    transpose_cvt_kernel<<<dim3(48, 16, NL_), 256, 0, stream>>>((const float*)d_in[11], wqkvT, D_, 3 * D_);
    transpose_cvt_kernel<<<dim3(16, 16, NL_), 256, 0, stream>>>((const float*)d_in[13], woT, D_, D_);
    transpose_cvt_kernel<<<dim3(64, 16, NL_), 256, 0, stream>>>((const float*)d_in[19], w1T, D_, DFF_);
    transpose_cvt_kernel<<<dim3(16, 64, NL_), 256, 0, stream>>>((const float*)d_in[21], w2T, DFF_, D_);

    // ---- patchify + patch embed ----
    patchify_kernel<<<cdiv_i((long long)OBS_ROWS * PKP, 256), 256, 0, stream>>>(frames, xpb);
    gemm_mfma<64><<<dim3(D_ / 64, OBS_ROWS / 128), 256, 0, stream>>>(
        xpb, wpatchT, (const float*)d_in[5], nullptr, obs, nullptr, OBS_ROWS, D_, PKP, 0);

    // ---- assemble sequence ----
    assemble_kernel<<<cdiv_i((long long)ROWS * D_, 256), 256, 0, stream>>>(
        obs, rtg, actions, rewards,
        (const float*)d_in[6], (const float*)d_in[7], (const float*)d_in[8],
        (const float*)d_in[9], (const float*)d_in[10], h);

    // ---- transformer layers ----
    for (int i = 0; i < NL_; ++i) {
        ln_fast<<<ROWS, 256, 0, stream>>>(h, (const float*)d_in[15] + i * D_,
                                          (const float*)d_in[16] + i * D_, ab1);
        gemm_mfma<64><<<dim3(3 * D_ / 64, ROWS / 128), 256, 0, stream>>>(
            ab1, wqkvT + (size_t)i * D_ * 3 * D_, (const float*)d_in[12] + i * 3 * D_,
            nullptr, nullptr, qkvb, ROWS, 3 * D_, D_, 0);
        vt_prep<<<dim3(39, 2, 64), 256, 0, stream>>>(qkvb, vtg);
        attn_mfma<<<dim3(64, 20), 256, 0, stream>>>(qkvb, vtg, ab2);
        gemm_mfma<64><<<dim3(D_ / 64, ROWS / 128), 256, 0, stream>>>(
            ab2, woT + (size_t)i * D_ * D_, (const float*)d_in[14] + i * D_,
            h, h, nullptr, ROWS, D_, D_, 0);
        ln_fast<<<ROWS, 256, 0, stream>>>(h, (const float*)d_in[17] + i * D_,
                                          (const float*)d_in[18] + i * D_, ab1);
        gemm_mfma<128><<<dim3(DFF_ / 128, ROWS / 128), 256, 0, stream>>>(
            ab1, w1T + (size_t)i * D_ * DFF_, (const float*)d_in[20] + i * DFF_,
            nullptr, nullptr, ffnb, ROWS, DFF_, D_, 1);
        gemm_mfma<64><<<dim3(D_ / 64, ROWS / 128), 256, 0, stream>>>(
            ffnb, w2T + (size_t)i * DFF_ * D_, (const float*)d_in[22] + i * D_,
            h, h, nullptr, ROWS, D_, DFF_, 0);
    }

    // ---- heads ----
    heads_fast<<<B_ * T_, 256, 0, stream>>>(h,
        (const float*)d_in[23], (const float*)d_in[24],
        (const float*)d_in[25], (const float*)d_in[26],
        (const float*)d_in[27], (const float*)d_in[28], (float*)d_out);
}

// Round 8
// 1397.250 us; speedup vs baseline: 1.1122x; 1.0605x over previous
//
#include <hip/hip_runtime.h>
#include <hip/hip_bf16.h>
#include <math.h>

typedef unsigned short ushort_t;
typedef __attribute__((ext_vector_type(8))) short bf16x8;
typedef __attribute__((ext_vector_type(4))) float floatx4;

#define B_   8
#define T_   32
#define C_   4
#define HW_  84
#define P_   14
#define GP_  6
#define LOBS 36
#define S_   39
#define L_   (T_ * S_)          // 1248
#define D_   512
#define NH_  8
#define DH_  64
#define NL_  6
#define DFF_ 2048
#define NRET 120
#define NACT 18
#define NREW 3

#define ROWS (B_ * L_)          // 9984
#define OBS_ROWS (B_ * T_ * LOBS) // 9216
#define PK   (C_ * P_ * P_)     // 784
#define PKP  800                 // PK padded to %32

// workspace layout (float units)
#define OFF_H     0                         // fp32 9984*512
#define OFF_AB1   5111808                   // bf16 9984*512
#define OFF_AB2   (OFF_AB1 + 2555904)
#define OFF_QKVB  (OFF_AB2 + 2555904)       // bf16 9984*1536
#define OFF_FFNB  (OFF_QKVB + 7667712)      // bf16 9984*2048 (aliased: VtG / Xp+obs)
#define OFF_WB    (OFF_FFNB + 10223616)     // bf16 transposed weights
#define WS_FLOATS (OFF_WB + 9641984 + 16)

static __device__ __forceinline__ ushort_t f2b(float x) {
    union { float f; unsigned int u; } v; v.f = x;
    unsigned int r = v.u + 0x7FFFu + ((v.u >> 16) & 1u);
    return (ushort_t)(r >> 16);
}

// exact-GELU via Abramowitz-Stegun 7.1.26 erf (|err| <= 1.5e-7, far below bf16 ulp)
static __device__ __forceinline__ float gelu_f(float v) {
    float z = fabsf(v) * 0.70710678118654752f;
    float t = 1.0f / (1.0f + 0.3275911f * z);
    float p = fmaf(t, 1.061405429f, -1.453152027f);
    p = fmaf(t, p, 1.421413741f);
    p = fmaf(t, p, -0.284496736f);
    p = fmaf(t, p, 0.254829592f);
    float e = 1.0f - p * t * __expf(-z * z);
    float s = v < 0.0f ? -e : e;
    return 0.5f * v * (1.0f + s);
}

static __device__ __forceinline__ void gload16(const ushort_t* g, ushort_t* l) {
    __builtin_amdgcn_global_load_lds(
        (const __attribute__((address_space(1))) void*)g,
        (__attribute__((address_space(3))) void*)l, 16, 0, 0);
}

__global__ void sentinel_kernel(float* out, int n) {
    int i = blockIdx.x * 256 + threadIdx.x;
    if (i < n) out[i] = 100.0f;
}

// ---------------- weight transpose+convert: [K][N] fp32 -> [N][K] bf16, per layer -------
__global__ __launch_bounds__(256) void transpose_cvt_kernel(
    const float* __restrict__ src, ushort_t* __restrict__ dst, int K, int N)
{
    __shared__ float tile[32][33];
    int layer = blockIdx.z;
    int n0 = blockIdx.x * 32, k0 = blockIdx.y * 32;
    int tx = threadIdx.x & 31, ty = threadIdx.x >> 5;   // 32 x 8
    const float* s = src + (size_t)layer * K * N;
    ushort_t* d = dst + (size_t)layer * N * K;
#pragma unroll
    for (int r = 0; r < 32; r += 8)
        tile[ty + r][tx] = s[(size_t)(k0 + ty + r) * N + n0 + tx];
    __syncthreads();
#pragma unroll
    for (int r = 0; r < 32; r += 8)
        d[(size_t)(n0 + ty + r) * K + k0 + tx] = f2b(tile[tx][ty + r]);
}

// patch_W [784][512] fp32 -> [512][800] bf16 (k-pad zeros)
__global__ __launch_bounds__(256) void transpose_patchw_kernel(
    const float* __restrict__ src, ushort_t* __restrict__ dst)
{
    __shared__ float tile[32][33];
    int n0 = blockIdx.x * 32, k0 = blockIdx.y * 32;
    int tx = threadIdx.x & 31, ty = threadIdx.x >> 5;
#pragma unroll
    for (int r = 0; r < 32; r += 8) {
        int k = k0 + ty + r;
        tile[ty + r][tx] = (k < PK) ? src[(size_t)k * D_ + n0 + tx] : 0.0f;
    }
    __syncthreads();
#pragma unroll
    for (int r = 0; r < 32; r += 8)
        dst[(size_t)(n0 + ty + r) * PKP + k0 + tx] = f2b(tile[tx][ty + r]);
}

// ---------------- patchify: frames fp32 -> Xp bf16 (9216 x 800) ----------------
__global__ void patchify_kernel(const float* __restrict__ frames, ushort_t* __restrict__ Xp) {
    int idx = blockIdx.x * 256 + threadIdx.x;
    if (idx >= OBS_ROWS * PKP) return;
    int r = idx / PKP, c = idx % PKP;
    if (c >= PK) { Xp[idx] = 0; return; }
    int bt = r / LOBS, p = r % LOBS;
    int gy = p / GP_, gx = p % GP_;
    int ch = c / (P_ * P_), rem = c % (P_ * P_);
    int py = rem / P_, px = rem % P_;
    size_t src = (((size_t)bt * C_ + ch) * HW_ + gy * P_ + py) * HW_ + gx * P_ + px;
    Xp[idx] = f2b(frames[src]);
}

// ---------------- MFMA GEMM: 128xBN tile (BN=128 for FFN1, 64 elsewhere), -------------
// ---------------- BK=64, dbuf + counted vmcnt, XOR-swizzled LDS, XCD swizzle. ---------
// ---------------- LDS-repacked epilogue: 16B vectorized stores + residual loads. ------
template<int BN>
__global__ __launch_bounds__(256) void gemm_mfma(
    const ushort_t* __restrict__ A, const ushort_t* __restrict__ BT,
    const float* __restrict__ bias, const float* __restrict__ residual,
    float* __restrict__ Cf, ushort_t* __restrict__ Cb,
    int M, int N, int K, int do_gelu)
{
    constexpr int NJ = BN / 32;            // B frags / MFMA cols per wave (4 or 2)
    __shared__ ushort_t As[2][128 * 64];
    __shared__ ushort_t Bs[2][BN * 64];
    int t = threadIdx.x, lane = t & 63, w = t >> 6;

    // T1: bijective XCD swizzle (m204) -- consecutive blocks per XCD share A-panel
    int nx = gridDim.x;
    int nwg = nx * (int)gridDim.y;
    int orig = blockIdx.y * nx + blockIdx.x;
    int qq = nwg >> 3, rr = nwg & 7;
    int xcd = orig & 7, loc = orig >> 3;
    int wg = (xcd < rr ? xcd * (qq + 1) : rr * (qq + 1) + (xcd - rr) * qq) + loc;
    int row0 = (wg / nx) * 128, col0 = (wg % nx) * BN;

    // 4 waves as 2M x 2N; each wave 64 x (BN/2)
    int moff = (w & 1) << 6, noff = (w >> 1) * (BN / 2);
    int l16 = lane & 15, quad = lane >> 4;
    floatx4 acc[4][NJ];
#pragma unroll
    for (int i = 0; i < 4; ++i)
#pragma unroll
        for (int j = 0; j < NJ; ++j) acc[i][j] = (floatx4){0.f, 0.f, 0.f, 0.f};

    // staging: LDS linear [row][64] (128B rows); source pre-swizzled chunk^=row&7.
    int rsub = lane >> 3;
    int csw = (lane & 7) ^ rsub;
    const ushort_t* gA = A + (size_t)(row0 + w * 8 + rsub) * K + csw * 8;
    const ushort_t* gB = BT + (size_t)(col0 + w * 8 + rsub) * K + csw * 8;
    ushort_t* lA = &As[0][0] + w * 512;
    ushort_t* lB = &Bs[0][0] + w * 512;

    int nt = K >> 6;
    // prologue: tile 0 -> buf 0
#pragma unroll
    for (int s = 0; s < 4; ++s) gload16(gA + (size_t)s * 32 * K, lA + s * 2048);
#pragma unroll
    for (int s = 0; s < NJ; ++s) gload16(gB + (size_t)s * 32 * K, lB + s * 2048);

    int ch0 = (quad ^ (l16 & 7)) * 8;   // read-side swizzled chunk offset (ushorts), k-half 0
    for (int kt = 0; kt < nt; ++kt) {
        int cur = kt & 1, nxt = cur ^ 1;
        if (kt + 1 < nt) {
            int k0n = (kt + 1) << 6;
#pragma unroll
            for (int s = 0; s < 4; ++s)
                gload16(gA + (size_t)s * 32 * K + k0n, lA + nxt * 8192 + s * 2048);
#pragma unroll
            for (int s = 0; s < NJ; ++s)
                gload16(gB + (size_t)s * 32 * K + k0n, lB + nxt * (BN * 64) + s * 2048);
            if constexpr (BN == 128)
                asm volatile("s_waitcnt vmcnt(8)" ::: "memory");  // tile kt done; kt+1 in flight
            else
                asm volatile("s_waitcnt vmcnt(6)" ::: "memory");
        } else {
            asm volatile("s_waitcnt vmcnt(0)" ::: "memory");
        }
        __builtin_amdgcn_s_barrier();          // buf[cur] fully written, all waves
        bf16x8 af0[4], af1[4], bf0[NJ], bf1[NJ];
#pragma unroll
        for (int i = 0; i < 4; ++i) {
            const ushort_t* pa = &As[cur][(moff + i * 16 + l16) * 64];
            af0[i] = *(const bf16x8*)(pa + ch0);
            af1[i] = *(const bf16x8*)(pa + (ch0 ^ 32));
        }
#pragma unroll
        for (int j = 0; j < NJ; ++j) {
            const ushort_t* pb = &Bs[cur][(noff + j * 16 + l16) * 64];
            bf0[j] = *(const bf16x8*)(pb + ch0);
            bf1[j] = *(const bf16x8*)(pb + (ch0 ^ 32));
        }
        asm volatile("s_waitcnt lgkmcnt(0)" ::: "memory");
        __builtin_amdgcn_sched_barrier(0);     // rule #18: pin MFMA below the wait
        __builtin_amdgcn_s_barrier();          // all waves done READING buf[cur]
        __builtin_amdgcn_s_setprio(1);
#pragma unroll
        for (int i = 0; i < 4; ++i)
#pragma unroll
            for (int j = 0; j < NJ; ++j) {
                acc[i][j] = __builtin_amdgcn_mfma_f32_16x16x32_bf16(af0[i], bf0[j], acc[i][j], 0, 0, 0);
                acc[i][j] = __builtin_amdgcn_mfma_f32_16x16x32_bf16(af1[i], bf1[j], acc[i][j], 0, 0, 0);
            }
        __builtin_amdgcn_s_setprio(0);
    }
    if (K & 32) {   // BK=32 tail (patch embed K=800), one shot, no swizzle
        int k0 = nt << 6;
        int g0 = 2 * w * 64 + lane;        // A: 128 rows x 4 chunks = 512 slots
        int g1 = (2 * w + 1) * 64 + lane;
        gload16(A + (size_t)(row0 + (g0 >> 2)) * K + k0 + (g0 & 3) * 8, &As[0][0] + 2 * w * 512);
        gload16(A + (size_t)(row0 + (g1 >> 2)) * K + k0 + (g1 & 3) * 8, &As[0][0] + (2 * w + 1) * 512);
        if constexpr (BN == 64) {
            int gb = w * 64 + lane;        // B: 64 rows x 4 chunks = 256 slots
            gload16(BT + (size_t)(col0 + (gb >> 2)) * K + k0 + (gb & 3) * 8, &Bs[0][0] + w * 512);
        } else {
            int gb0 = 2 * w * 64 + lane;   // B: 128 rows x 4 chunks = 512 slots
            int gb1 = (2 * w + 1) * 64 + lane;
            gload16(BT + (size_t)(col0 + (gb0 >> 2)) * K + k0 + (gb0 & 3) * 8, &Bs[0][0] + 2 * w * 512);
            gload16(BT + (size_t)(col0 + (gb1 >> 2)) * K + k0 + (gb1 & 3) * 8, &Bs[0][0] + (2 * w + 1) * 512);
        }
        asm volatile("s_waitcnt vmcnt(0)" ::: "memory");
        __builtin_amdgcn_s_barrier();
        bf16x8 af[4], bfv[NJ];
#pragma unroll
        for (int i = 0; i < 4; ++i)
            af[i] = *(const bf16x8*)&As[0][(moff + i * 16 + l16) * 32 + quad * 8];
#pragma unroll
        for (int j = 0; j < NJ; ++j)
            bfv[j] = *(const bf16x8*)&Bs[0][(noff + j * 16 + l16) * 32 + quad * 8];
        asm volatile("s_waitcnt lgkmcnt(0)" ::: "memory");
        __builtin_amdgcn_sched_barrier(0);
#pragma unroll
        for (int i = 0; i < 4; ++i)
#pragma unroll
            for (int j = 0; j < NJ; ++j)
                acc[i][j] = __builtin_amdgcn_mfma_f32_16x16x32_bf16(af[i], bfv[j], acc[i][j], 0, 0, 0);
    }

    // ---- epilogue: repack C tile through LDS (As, now free) for 16B stores ----
    __syncthreads();                           // all waves' LDS reads complete
    int rquad = quad << 2;
    if (Cb) {
        // bf16 output tile [128][BN], 16B-chunk XOR swizzle (chunk ^= row&7)
        ushort_t* Ct = &As[0][0];              // BN=128: 32KB (all of As); BN=64: 16KB
#pragma unroll
        for (int j = 0; j < NJ; ++j) {
            int colL = noff + j * 16 + l16;
            float bv = bias ? bias[col0 + colL] : 0.0f;
#pragma unroll
            for (int i = 0; i < 4; ++i) {
#pragma unroll
                for (int r = 0; r < 4; ++r) {
                    int row = moff + i * 16 + rquad + r;
                    float v = acc[i][j][r] + bv;
                    if (do_gelu) v = gelu_f(v);
                    Ct[row * BN + ((((colL >> 3) ^ (row & 7)) << 3) | (colL & 7))] = f2b(v);
                }
            }
        }
        __syncthreads();
        constexpr int CPR = BN / 8;            // 16B chunks per row
        constexpr int NS = 128 * CPR / 256;    // chunks per thread (4 or 8)
#pragma unroll
        for (int s = 0; s < NS; ++s) {
            int c = t + 256 * s;
            int row = c / CPR, ch = c % CPR;
            bf16x8 val = *(const bf16x8*)&Ct[row * BN + ((ch ^ (row & 7)) << 3)];
            *(bf16x8*)&Cb[(size_t)(row0 + row) * N + col0 + ch * 8] = val;
        }
    } else if constexpr (BN == 64) {
        // fp32 output tile [128][64] (+vectorized residual), 4-float-chunk XOR swizzle
        float* Ctf = (float*)&As[0][0];        // 128*64*4B = 32KB (all of As)
#pragma unroll
        for (int j = 0; j < NJ; ++j) {
            int colL = noff + j * 16 + l16;
            float bv = bias ? bias[col0 + colL] : 0.0f;
#pragma unroll
            for (int i = 0; i < 4; ++i) {
#pragma unroll
                for (int r = 0; r < 4; ++r) {
                    int row = moff + i * 16 + rquad + r;
                    float v = acc[i][j][r] + bv;
                    if (do_gelu) v = gelu_f(v);
                    Ctf[row * 64 + ((((colL >> 2) ^ (row & 7)) << 2) | (colL & 3))] = v;
                }
            }
        }
        __syncthreads();
#pragma unroll
        for (int s = 0; s < 8; ++s) {          // 128 rows x 16 chunks / 256 threads
            int c = t + 256 * s;
            int row = c >> 4, ch = c & 15;
            floatx4 val = *(const floatx4*)&Ctf[row * 64 + ((ch ^ (row & 7)) << 2)];
            if (residual) {
                floatx4 rv = *(const floatx4*)&residual[(size_t)(row0 + row) * N + col0 + ch * 4];
                val += rv;
            }
            *(floatx4*)&Cf[(size_t)(row0 + row) * N + col0 + ch * 4] = val;
        }
    } else {
        // BN=128 fp32 path (unused by launcher): legacy scalar fallback
#pragma unroll
        for (int j = 0; j < NJ; ++j) {
            int col = col0 + noff + j * 16 + l16;
            float bv = bias ? bias[col] : 0.0f;
#pragma unroll
            for (int i = 0; i < 4; ++i) {
#pragma unroll
                for (int r = 0; r < 4; ++r) {
                    int row = row0 + moff + i * 16 + rquad + r;
                    float v = acc[i][j][r] + bv;
                    if (do_gelu) v = gelu_f(v);
                    if (residual) v += residual[(size_t)row * N + col];
                    if (Cf) Cf[(size_t)row * N + col] = v;
                }
            }
        }
    }
}

// ---------------- assemble tokens + embeddings -> h fp32 ----------------
__global__ void assemble_kernel(const float* __restrict__ obs,
                                const int* __restrict__ rtg,
                                const int* __restrict__ act,
                                const int* __restrict__ rew,
                                const float* __restrict__ retE,
                                const float* __restrict__ actE,
                                const float* __restrict__ rewE,
                                const float* __restrict__ posE,
                                const float* __restrict__ typeE,
                                float* __restrict__ h) {
    int idx = blockIdx.x * 256 + threadIdx.x;
    if (idx >= ROWS * D_) return;
    int d = idx & (D_ - 1);
    int bl = idx / D_;
    int l = bl % L_, b = bl / L_;
    int t = l / S_, off = l % S_;
    int bt = b * T_ + t;
    float v;
    int ty;
    if (off < LOBS) {
        v = obs[((size_t)bt * LOBS + off) * D_ + d];
        ty = 0;
    } else if (off == LOBS) {
        v = retE[(size_t)rtg[bt] * D_ + d];
        ty = 1;
    } else if (off == LOBS + 1) {
        v = actE[(size_t)act[bt] * D_ + d];
        ty = 2;
    } else {
        v = rewE[(size_t)rew[bt] * D_ + d];
        ty = 3;
    }
    v += posE[(size_t)l * D_ + d] + typeE[(size_t)ty * D_ + d];
    h[idx] = v;
}

// ---------------- LayerNorm fp32 in -> bf16 out ----------------
__global__ __launch_bounds__(256) void ln_fast(const float* __restrict__ x,
                                               const float* __restrict__ g,
                                               const float* __restrict__ bb,
                                               ushort_t* __restrict__ y) {
    int row = blockIdx.x;
    const float* xr = x + (size_t)row * D_;
    ushort_t* yr = y + (size_t)row * D_;
    int tid = threadIdx.x;
    float v0 = xr[tid], v1 = xr[tid + 256];
    __shared__ float red[4];
    int lane = tid & 63, wid = tid >> 6;
    float s = v0 + v1;
#pragma unroll
    for (int off = 32; off > 0; off >>= 1) s += __shfl_down(s, off, 64);
    if (lane == 0) red[wid] = s;
    __syncthreads();
    float mean = (red[0] + red[1] + red[2] + red[3]) * (1.0f / 512.0f);
    __syncthreads();
    float d0 = v0 - mean, d1 = v1 - mean;
    float vs = d0 * d0 + d1 * d1;
#pragma unroll
    for (int off = 32; off > 0; off >>= 1) vs += __shfl_down(vs, off, 64);
    if (lane == 0) red[wid] = vs;
    __syncthreads();
    float var = (red[0] + red[1] + red[2] + red[3]) * (1.0f / 512.0f);
    float rstd = rsqrtf(var + 1e-5f);
    yr[tid]       = f2b(d0 * rstd * g[tid]       + bb[tid]);
    yr[tid + 256] = f2b(d1 * rstd * g[tid + 256] + bb[tid + 256]);
}

// ---------------- V pre-transpose per layer: qkvb V -> VtG[bh][d][l] bf16 ------------
__global__ __launch_bounds__(256) void vt_prep(const ushort_t* __restrict__ qkvb,
                                               ushort_t* __restrict__ vtg)
{
    __shared__ ushort_t tl[32][33];
    int bh = blockIdx.z; int b = bh >> 3, hh = bh & 7;
    int l0 = blockIdx.x * 32, d0 = blockIdx.y * 32;
    int tx = threadIdx.x & 31, ty = threadIdx.x >> 5;
#pragma unroll
    for (int r = 0; r < 32; r += 8)
        tl[ty + r][tx] = qkvb[((size_t)b * L_ + l0 + ty + r) * 1536 + 1024 + hh * 64 + d0 + tx];
    __syncthreads();
#pragma unroll
    for (int r = 0; r < 32; r += 8)
        vtg[((size_t)bh * 64 + d0 + ty + r) * L_ + l0 + tx] = tl[tx][ty + r];
}

// ---------------- MFMA flash attention: LDS-staged K/V shared across waves, ----------
// ---------------- double-buffered global_load_lds prefetch, XOR-swizzled ------------
__global__ __launch_bounds__(256) void attn_mfma(const ushort_t* __restrict__ qkvb,
                                                 const ushort_t* __restrict__ vtg,
                                                 ushort_t* __restrict__ outb)
{
    int bh = blockIdx.x; int hh = bh & 7, b = bh >> 3;
    int qt = 19 - blockIdx.y;            // long blocks first (tail scheduling)
    int q0 = qt << 6;
    int t = threadIdx.x, lane = t & 63, w = t >> 6;
    int l16 = lane & 15, quad = lane >> 4;
    __shared__ ushort_t Ks[2][64 * 64];
    __shared__ ushort_t Vs[2][64 * 64];
    __shared__ ushort_t Ps[64][72];
    const ushort_t* base = qkvb + (size_t)b * (L_ * 1536);
    const ushort_t* vbase = vtg + (size_t)bh * 64 * L_;

    int qrow_l = q0 + w * 16 + l16; if (qrow_l >= L_) qrow_l = L_ - 1;
    const ushort_t* qp = base + (size_t)qrow_l * 1536 + hh * 64 + quad * 8;
    bf16x8 aq0 = *(const bf16x8*)qp;
    bf16x8 aq1 = *(const bf16x8*)(qp + 32);
    int qg[4], stepq[4], obsq[4];
#pragma unroll
    for (int r = 0; r < 4; ++r) {
        qg[r] = q0 + w * 16 + quad * 4 + r;
        stepq[r] = qg[r] / S_;
        obsq[r] = (qg[r] - stepq[r] * S_) < LOBS;
    }
    int qlast = q0 + 63; if (qlast > L_ - 1) qlast = L_ - 1;
    int kend_max = qlast;
    int we = (qlast / S_) * S_ + LOBS - 1;
    if (we > kend_max) kend_max = we;
    int ntiles = (kend_max >> 6) + 1;

    int sub = lane >> 3, jj = lane & 7;
    int jsw = jj ^ sub;                       // swizzled 16B-chunk (row&7 == sub)
    int rk0 = (w << 4) + sub, rk1 = rk0 + 8;
    const ushort_t* kcol = base + 512 + hh * 64 + jsw * 8;
    const ushort_t* vr0 = vbase + (size_t)rk0 * L_;
    const ushort_t* vr1 = vbase + (size_t)rk1 * L_;
    ushort_t* ldsK0 = &Ks[0][0] + (w << 10);
    ushort_t* ldsK1 = ldsK0 + 512;
    ushort_t* ldsV0 = &Vs[0][0] + (w << 10);
    ushort_t* ldsV1 = ldsV0 + 512;

    gload16(kcol + (size_t)rk0 * 1536, ldsK0);
    gload16(kcol + (size_t)rk1 * 1536, ldsK1);
    gload16(vr0 + jsw * 8, ldsV0);
    gload16(vr1 + jsw * 8, ldsV1);
    __syncthreads();

    float psum[4] = {0.f, 0.f, 0.f, 0.f};
    floatx4 O[4];
#pragma unroll
    for (int nb = 0; nb < 4; ++nb) O[nb] = (floatx4){0.f, 0.f, 0.f, 0.f};

    int swz = (quad ^ (l16 & 7)) << 4;        // read-side swizzled byte offset
    int buf = 0;
    for (int kt = 0; kt < ntiles; ++kt) {
        int nxt = buf ^ 1;
        if (kt + 1 < ntiles) {                // prefetch next tile (uniform branch)
            int k0n = (kt + 1) << 6;
            int g0 = k0n + rk0; if (g0 > L_ - 1) g0 = L_ - 1;
            int g1 = k0n + rk1; if (g1 > L_ - 1) g1 = L_ - 1;
            gload16(kcol + (size_t)g0 * 1536, ldsK0 + (nxt << 12));
            gload16(kcol + (size_t)g1 * 1536, ldsK1 + (nxt << 12));
            int cv = k0n + jsw * 8; if (cv > L_ - 8) cv = L_ - 8;
            gload16(vr0 + cv, ldsV0 + (nxt << 12));
            gload16(vr1 + cv, ldsV1 + (nxt << 12));
        }
        int k0 = kt << 6;
        const ushort_t* Kb = &Ks[0][0] + (buf << 12);
        const ushort_t* Vb = &Vs[0][0] + (buf << 12);
        floatx4 sc4[4];
        __builtin_amdgcn_s_setprio(1);
#pragma unroll
        for (int nb = 0; nb < 4; ++nb) {
            const char* kp = (const char*)(Kb + ((nb * 16 + l16) << 6));
            bf16x8 bk0 = *(const bf16x8*)(kp + swz);
            bf16x8 bk1 = *(const bf16x8*)(kp + (swz ^ 64));
            floatx4 z = (floatx4){0.f, 0.f, 0.f, 0.f};
            z = __builtin_amdgcn_mfma_f32_16x16x32_bf16(aq0, bk0, z, 0, 0, 0);
            z = __builtin_amdgcn_mfma_f32_16x16x32_bf16(aq1, bk1, z, 0, 0, 0);
            sc4[nb] = z;
        }
        __builtin_amdgcn_s_setprio(0);
        if (kt < qt) {
#pragma unroll
            for (int nb = 0; nb < 4; ++nb)
#pragma unroll
                for (int r = 0; r < 4; ++r) {
                    float p = __expf(sc4[nb][r] * 0.125f);
                    psum[r] += p;
                    Ps[w * 16 + quad * 4 + r][nb * 16 + l16] = f2b(p);
                }
        } else {
#pragma unroll
            for (int nb = 0; nb < 4; ++nb) {
                int kg = k0 + nb * 16 + l16;
                int stepk = kg / S_;
                int kobs = (kg - stepk * S_) < LOBS;
#pragma unroll
                for (int r = 0; r < 4; ++r) {
                    int allowed = (kg <= qg[r]) || (obsq[r] && kobs && (stepk == stepq[r]));
                    float p = allowed ? __expf(sc4[nb][r] * 0.125f) : 0.0f;
                    psum[r] += p;
                    Ps[w * 16 + quad * 4 + r][nb * 16 + l16] = f2b(p);
                }
            }
        }
        bf16x8 ap0 = *(const bf16x8*)&Ps[w * 16 + l16][quad * 8];
        bf16x8 ap1 = *(const bf16x8*)&Ps[w * 16 + l16][quad * 8 + 32];
        __builtin_amdgcn_s_setprio(1);
#pragma unroll
        for (int nb = 0; nb < 4; ++nb) {
            const char* vp = (const char*)(Vb + ((nb * 16 + l16) << 6));
            bf16x8 bv0 = *(const bf16x8*)(vp + swz);
            bf16x8 bv1 = *(const bf16x8*)(vp + (swz ^ 64));
            O[nb] = __builtin_amdgcn_mfma_f32_16x16x32_bf16(ap0, bv0, O[nb], 0, 0, 0);
            O[nb] = __builtin_amdgcn_mfma_f32_16x16x32_bf16(ap1, bv1, O[nb], 0, 0, 0);
        }
        __builtin_amdgcn_s_setprio(0);
        __syncthreads();    // drains the prefetch (vmcnt) + protects buffer reuse
        buf = nxt;
    }
#pragma unroll
    for (int off = 1; off < 16; off <<= 1)
#pragma unroll
        for (int r = 0; r < 4; ++r)
            psum[r] += __shfl_xor(psum[r], off, 64);
#pragma unroll
    for (int r = 0; r < 4; ++r) {
        if (qg[r] < L_) {
            float inv = 1.0f / psum[r];
#pragma unroll
            for (int nb = 0; nb < 4; ++nb)
                outb[((size_t)b * L_ + qg[r]) * 512 + hh * 64 + nb * 16 + l16] =
                    f2b(O[nb][r] * inv);
        }
    }
}

// ---------------- heads: LDS-staged, unrolled; one block per (b,t) ----------------
__global__ __launch_bounds__(256) void heads_fast(const float* __restrict__ h,
                            const float* __restrict__ hW_ret, const float* __restrict__ hb_ret,
                            const float* __restrict__ hW_act, const float* __restrict__ hb_act,
                            const float* __restrict__ hW_rew, const float* __restrict__ hb_rew,
                            float* __restrict__ out) {
    int bt = blockIdx.x;
    int b = bt >> 5, t = bt & 31;
    __shared__ float hr[D_], ha[D_], hw[D_];
    size_t base = ((size_t)b * L_ + (size_t)t * S_) * D_;
    int tid = threadIdx.x;
    for (int i = tid; i < D_; i += 256) {
        hr[i] = h[base + (size_t)(LOBS - 1) * D_ + i];
        ha[i] = h[base + (size_t)LOBS * D_ + i];
        hw[i] = h[base + (size_t)(LOBS + 1) * D_ + i];
    }
    __syncthreads();
    if (tid < NRET) {
        float acc = hb_ret[tid];
#pragma unroll 16
        for (int k = 0; k < D_; ++k) acc = fmaf(hr[k], hW_ret[(size_t)k * NRET + tid], acc);
        out[(size_t)bt * NRET + tid] = acc;
    } else if (tid < NRET + NACT) {
        int n = tid - NRET;
        float acc = hb_act[n];
#pragma unroll 16
        for (int k = 0; k < D_; ++k) acc = fmaf(ha[k], hW_act[(size_t)k * NACT + n], acc);
        out[(size_t)(B_ * T_ * NRET) + (size_t)bt * NACT + n] = acc;
    } else if (tid < NRET + NACT + NREW) {
        int n = tid - NRET - NACT;
        float acc = hb_rew[n];
#pragma unroll 16
        for (int k = 0; k < D_; ++k) acc = fmaf(hw[k], hW_rew[(size_t)k * NREW + n], acc);
        out[(size_t)(B_ * T_ * (NRET + NACT)) + (size_t)bt * NREW + n] = acc;
    }
}

static inline int cdiv_i(long long a, int b) { return (int)((a + b - 1) / b); }

extern "C" void kernel_launch(void* const* d_in, const int* in_sizes, int n_in,
                              void* d_out, int out_size, void* d_ws, size_t ws_size,
                              hipStream_t stream) {
    if (ws_size < (size_t)WS_FLOATS * sizeof(float)) {
        sentinel_kernel<<<(out_size + 255) / 256, 256, 0, stream>>>((float*)d_out, out_size);
        return;
    }
    const float* frames  = (const float*)d_in[0];
    const int*   rtg     = (const int*)d_in[1];
    const int*   actions = (const int*)d_in[2];
    const int*   rewards = (const int*)d_in[3];

    float* ws   = (float*)d_ws;
    float* h    = ws + OFF_H;
    ushort_t* ab1  = (ushort_t*)(ws + OFF_AB1);
    ushort_t* ab2  = (ushort_t*)(ws + OFF_AB2);
    ushort_t* qkvb = (ushort_t*)(ws + OFF_QKVB);
    ushort_t* ffnb = (ushort_t*)(ws + OFF_FFNB);
    ushort_t* vtg  = (ushort_t*)(ws + OFF_FFNB);
    ushort_t* xpb  = (ushort_t*)(ws + OFF_FFNB);
    float*    obs  = ws + OFF_FFNB + 3686400;
    ushort_t* wpatchT = (ushort_t*)(ws + OFF_WB);
    ushort_t* wqkvT = wpatchT + PKP * D_;
    ushort_t* woT   = wqkvT + NL_ * D_ * 3 * D_;
    ushort_t* w1T   = woT + NL_ * D_ * D_;
    ushort_t* w2T   = w1T + NL_ * D_ * DFF_;

    // ---- weight transpose + fp32->bf16 ----
    transpose_patchw_kernel<<<dim3(16, 25), 256, 0, stream>>>((const float*)d_in[4], wpatchT);
    transpose_cvt_kernel<<<dim3(48, 16, NL_), 256, 0, stream>>>((const float*)d_in[11], wqkvT, D_, 3 * D_);
    transpose_cvt_kernel<<<dim3(16, 16, NL_), 256, 0, stream>>>((const float*)d_in[13], woT, D_, D_);
    transpose_cvt_kernel<<<dim3(64, 16, NL_), 256, 0, stream>>>((const float*)d_in[19], w1T, D_, DFF_);
    transpose_cvt_kernel<<<dim3(16, 64, NL_), 256, 0, stream>>>((const float*)d_in[21], w2T, DFF_, D_);

    // ---- patchify + patch embed ----
    patchify_kernel<<<cdiv_i((long long)OBS_ROWS * PKP, 256), 256, 0, stream>>>(frames, xpb);
    gemm_mfma<64><<<dim3(D_ / 64, OBS_ROWS / 128), 256, 0, stream>>>(
        xpb, wpatchT, (const float*)d_in[5], nullptr, obs, nullptr, OBS_ROWS, D_, PKP, 0);

    // ---- assemble sequence ----
    assemble_kernel<<<cdiv_i((long long)ROWS * D_, 256), 256, 0, stream>>>(
        obs, rtg, actions, rewards,
        (const float*)d_in[6], (const float*)d_in[7], (const float*)d_in[8],
        (const float*)d_in[9], (const float*)d_in[10], h);

    // ---- transformer layers ----
    for (int i = 0; i < NL_; ++i) {
        ln_fast<<<ROWS, 256, 0, stream>>>(h, (const float*)d_in[15] + i * D_,
                                          (const float*)d_in[16] + i * D_, ab1);
        gemm_mfma<64><<<dim3(3 * D_ / 64, ROWS / 128), 256, 0, stream>>>(
            ab1, wqkvT + (size_t)i * D_ * 3 * D_, (const float*)d_in[12] + i * 3 * D_,
            nullptr, nullptr, qkvb, ROWS, 3 * D_, D_, 0);
        vt_prep<<<dim3(39, 2, 64), 256, 0, stream>>>(qkvb, vtg);
        attn_mfma<<<dim3(64, 20), 256, 0, stream>>>(qkvb, vtg, ab2);
        gemm_mfma<64><<<dim3(D_ / 64, ROWS / 128), 256, 0, stream>>>(
            ab2, woT + (size_t)i * D_ * D_, (const float*)d_in[14] + i * D_,
            h, h, nullptr, ROWS, D_, D_, 0);
        ln_fast<<<ROWS, 256, 0, stream>>>(h, (const float*)d_in[17] + i * D_,
                                          (const float*)d_in[18] + i * D_, ab1);
        gemm_mfma<128><<<dim3(DFF_ / 128, ROWS / 128), 256, 0, stream>>>(
            ab1, w1T + (size_t)i * D_ * DFF_, (const float*)d_in[20] + i * DFF_,
            nullptr, nullptr, ffnb, ROWS, DFF_, D_, 1);
        gemm_mfma<64><<<dim3(D_ / 64, ROWS / 128), 256, 0, stream>>>(
            ffnb, w2T + (size_t)i * DFF_ * D_, (const float*)d_in[22] + i * D_,
            h, h, nullptr, ROWS, D_, DFF_, 0);
    }

    // ---- heads ----
    heads_fast<<<B_ * T_, 256, 0, stream>>>(h,
        (const float*)d_in[23], (const float*)d_in[24],
        (const float*)d_in[25], (const float*)d_in[26],
        (const float*)d_in[27], (const float*)d_in[28], (float*)d_out);
}

// Round 10
// 1347.424 us; speedup vs baseline: 1.1533x; 1.0370x over previous
//
#include <hip/hip_runtime.h>
#include <hip/hip_bf16.h>
#include <math.h>

typedef unsigned short ushort_t;
typedef __attribute__((ext_vector_type(8))) short bf16x8;
typedef __attribute__((ext_vector_type(4))) float floatx4;

#define B_   8
#define T_   32
#define C_   4
#define HW_  84
#define P_   14
#define GP_  6
#define LOBS 36
#define S_   39
#define L_   (T_ * S_)          // 1248
#define D_   512
#define NH_  8
#define DH_  64
#define NL_  6
#define DFF_ 2048
#define NRET 120
#define NACT 18
#define NREW 3

#define ROWS (B_ * L_)          // 9984
#define OBS_ROWS (B_ * T_ * LOBS) // 9216
#define PK   (C_ * P_ * P_)     // 784
#define PKP  800                 // PK padded to %32

// workspace layout (float units)
#define OFF_H     0                         // fp32 9984*512
#define OFF_AB1   5111808                   // bf16 9984*512
#define OFF_AB2   (OFF_AB1 + 2555904)
#define OFF_QKVB  (OFF_AB2 + 2555904)       // bf16 9984*1536
#define OFF_FFNB  (OFF_QKVB + 7667712)      // bf16 9984*2048 (aliased: VtG / Xp+obs)
#define OFF_WB    (OFF_FFNB + 10223616)     // bf16 transposed weights
#define WS_FLOATS (OFF_WB + 9641984 + 16)

static __device__ __forceinline__ ushort_t f2b(float x) {
    union { float f; unsigned int u; } v; v.f = x;
    unsigned int r = v.u + 0x7FFFu + ((v.u >> 16) & 1u);
    return (ushort_t)(r >> 16);
}

// exact-GELU via Abramowitz-Stegun 7.1.26 erf (|err| <= 1.5e-7, far below bf16 ulp)
static __device__ __forceinline__ float gelu_f(float v) {
    float z = fabsf(v) * 0.70710678118654752f;
    float t = 1.0f / (1.0f + 0.3275911f * z);
    float p = fmaf(t, 1.061405429f, -1.453152027f);
    p = fmaf(t, p, 1.421413741f);
    p = fmaf(t, p, -0.284496736f);
    p = fmaf(t, p, 0.254829592f);
    float e = 1.0f - p * t * __expf(-z * z);
    float s = v < 0.0f ? -e : e;
    return 0.5f * v * (1.0f + s);
}

static __device__ __forceinline__ void gload16(const ushort_t* g, ushort_t* l) {
    __builtin_amdgcn_global_load_lds(
        (const __attribute__((address_space(1))) void*)g,
        (__attribute__((address_space(3))) void*)l, 16, 0, 0);
}

__global__ void sentinel_kernel(float* out, int n) {
    int i = blockIdx.x * 256 + threadIdx.x;
    if (i < n) out[i] = 100.0f;
}

// ---------------- weight transpose+convert: [K][N] fp32 -> [N][K] bf16, per layer -------
__global__ __launch_bounds__(256) void transpose_cvt_kernel(
    const float* __restrict__ src, ushort_t* __restrict__ dst, int K, int N)
{
    __shared__ float tile[32][33];
    int layer = blockIdx.z;
    int n0 = blockIdx.x * 32, k0 = blockIdx.y * 32;
    int tx = threadIdx.x & 31, ty = threadIdx.x >> 5;   // 32 x 8
    const float* s = src + (size_t)layer * K * N;
    ushort_t* d = dst + (size_t)layer * N * K;
#pragma unroll
    for (int r = 0; r < 32; r += 8)
        tile[ty + r][tx] = s[(size_t)(k0 + ty + r) * N + n0 + tx];
    __syncthreads();
#pragma unroll
    for (int r = 0; r < 32; r += 8)
        d[(size_t)(n0 + ty + r) * K + k0 + tx] = f2b(tile[tx][ty + r]);
}

// patch_W [784][512] fp32 -> [512][800] bf16 (k-pad zeros)
__global__ __launch_bounds__(256) void transpose_patchw_kernel(
    const float* __restrict__ src, ushort_t* __restrict__ dst)
{
    __shared__ float tile[32][33];
    int n0 = blockIdx.x * 32, k0 = blockIdx.y * 32;
    int tx = threadIdx.x & 31, ty = threadIdx.x >> 5;
#pragma unroll
    for (int r = 0; r < 32; r += 8) {
        int k = k0 + ty + r;
        tile[ty + r][tx] = (k < PK) ? src[(size_t)k * D_ + n0 + tx] : 0.0f;
    }
    __syncthreads();
#pragma unroll
    for (int r = 0; r < 32; r += 8)
        dst[(size_t)(n0 + ty + r) * PKP + k0 + tx] = f2b(tile[tx][ty + r]);
}

// ---------------- patchify: frames fp32 -> Xp bf16 (9216 x 800) ----------------
__global__ void patchify_kernel(const float* __restrict__ frames, ushort_t* __restrict__ Xp) {
    int idx = blockIdx.x * 256 + threadIdx.x;
    if (idx >= OBS_ROWS * PKP) return;
    int r = idx / PKP, c = idx % PKP;
    if (c >= PK) { Xp[idx] = 0; return; }
    int bt = r / LOBS, p = r % LOBS;
    int gy = p / GP_, gx = p % GP_;
    int ch = c / (P_ * P_), rem = c % (P_ * P_);
    int py = rem / P_, px = rem % P_;
    size_t src = (((size_t)bt * C_ + ch) * HW_ + gy * P_ + py) * HW_ + gx * P_ + px;
    Xp[idx] = f2b(frames[src]);
}

// ---------------- MFMA GEMM: 128xBN tile (BN=128 for FFN1, 64 elsewhere), -------------
// ---------------- BK=64, dbuf + counted vmcnt, XOR-swizzled LDS, XCD swizzle. ---------
// ---------------- LDS-repacked epilogue: 16B vectorized stores + residual loads. ------
template<int BN>
__global__ __launch_bounds__(256) void gemm_mfma(
    const ushort_t* __restrict__ A, const ushort_t* __restrict__ BT,
    const float* __restrict__ bias, const float* __restrict__ residual,
    float* __restrict__ Cf, ushort_t* __restrict__ Cb,
    int M, int N, int K, int do_gelu)
{
    constexpr int NJ = BN / 32;            // B frags / MFMA cols per wave (4 or 2)
    __shared__ ushort_t As[2][128 * 64];
    __shared__ ushort_t Bs[2][BN * 64];
    int t = threadIdx.x, lane = t & 63, w = t >> 6;

    // T1: bijective XCD swizzle (m204) -- consecutive blocks per XCD share A-panel
    int nx = gridDim.x;
    int nwg = nx * (int)gridDim.y;
    int orig = blockIdx.y * nx + blockIdx.x;
    int qq = nwg >> 3, rr = nwg & 7;
    int xcd = orig & 7, loc = orig >> 3;
    int wg = (xcd < rr ? xcd * (qq + 1) : rr * (qq + 1) + (xcd - rr) * qq) + loc;
    int row0 = (wg / nx) * 128, col0 = (wg % nx) * BN;

    // 4 waves as 2M x 2N; each wave 64 x (BN/2)
    int moff = (w & 1) << 6, noff = (w >> 1) * (BN / 2);
    int l16 = lane & 15, quad = lane >> 4;
    floatx4 acc[4][NJ];
#pragma unroll
    for (int i = 0; i < 4; ++i)
#pragma unroll
        for (int j = 0; j < NJ; ++j) acc[i][j] = (floatx4){0.f, 0.f, 0.f, 0.f};

    // staging: LDS linear [row][64] (128B rows); source pre-swizzled chunk^=row&7.
    int rsub = lane >> 3;
    int csw = (lane & 7) ^ rsub;
    const ushort_t* gA = A + (size_t)(row0 + w * 8 + rsub) * K + csw * 8;
    const ushort_t* gB = BT + (size_t)(col0 + w * 8 + rsub) * K + csw * 8;
    ushort_t* lA = &As[0][0] + w * 512;
    ushort_t* lB = &Bs[0][0] + w * 512;

    int nt = K >> 6;
    // prologue: tile 0 -> buf 0
#pragma unroll
    for (int s = 0; s < 4; ++s) gload16(gA + (size_t)s * 32 * K, lA + s * 2048);
#pragma unroll
    for (int s = 0; s < NJ; ++s) gload16(gB + (size_t)s * 32 * K, lB + s * 2048);

    int ch0 = (quad ^ (l16 & 7)) * 8;   // read-side swizzled chunk offset (ushorts), k-half 0
    for (int kt = 0; kt < nt; ++kt) {
        int cur = kt & 1, nxt = cur ^ 1;
        if (kt + 1 < nt) {
            int k0n = (kt + 1) << 6;
#pragma unroll
            for (int s = 0; s < 4; ++s)
                gload16(gA + (size_t)s * 32 * K + k0n, lA + nxt * 8192 + s * 2048);
#pragma unroll
            for (int s = 0; s < NJ; ++s)
                gload16(gB + (size_t)s * 32 * K + k0n, lB + nxt * (BN * 64) + s * 2048);
            if constexpr (BN == 128)
                asm volatile("s_waitcnt vmcnt(8)" ::: "memory");  // tile kt done; kt+1 in flight
            else
                asm volatile("s_waitcnt vmcnt(6)" ::: "memory");
        } else {
            asm volatile("s_waitcnt vmcnt(0)" ::: "memory");
        }
        __builtin_amdgcn_s_barrier();          // buf[cur] fully written, all waves
        bf16x8 af0[4], af1[4], bf0[NJ], bf1[NJ];
#pragma unroll
        for (int i = 0; i < 4; ++i) {
            const ushort_t* pa = &As[cur][(moff + i * 16 + l16) * 64];
            af0[i] = *(const bf16x8*)(pa + ch0);
            af1[i] = *(const bf16x8*)(pa + (ch0 ^ 32));
        }
#pragma unroll
        for (int j = 0; j < NJ; ++j) {
            const ushort_t* pb = &Bs[cur][(noff + j * 16 + l16) * 64];
            bf0[j] = *(const bf16x8*)(pb + ch0);
            bf1[j] = *(const bf16x8*)(pb + (ch0 ^ 32));
        }
        asm volatile("s_waitcnt lgkmcnt(0)" ::: "memory");
        __builtin_amdgcn_sched_barrier(0);     // rule #18: pin MFMA below the wait
        __builtin_amdgcn_s_barrier();          // all waves done READING buf[cur]
        __builtin_amdgcn_s_setprio(1);
#pragma unroll
        for (int i = 0; i < 4; ++i)
#pragma unroll
            for (int j = 0; j < NJ; ++j) {
                acc[i][j] = __builtin_amdgcn_mfma_f32_16x16x32_bf16(af0[i], bf0[j], acc[i][j], 0, 0, 0);
                acc[i][j] = __builtin_amdgcn_mfma_f32_16x16x32_bf16(af1[i], bf1[j], acc[i][j], 0, 0, 0);
            }
        __builtin_amdgcn_s_setprio(0);
    }
    if (K & 32) {   // BK=32 tail (patch embed K=800), one shot, no swizzle
        int k0 = nt << 6;
        int g0 = 2 * w * 64 + lane;        // A: 128 rows x 4 chunks = 512 slots
        int g1 = (2 * w + 1) * 64 + lane;
        gload16(A + (size_t)(row0 + (g0 >> 2)) * K + k0 + (g0 & 3) * 8, &As[0][0] + 2 * w * 512);
        gload16(A + (size_t)(row0 + (g1 >> 2)) * K + k0 + (g1 & 3) * 8, &As[0][0] + (2 * w + 1) * 512);
        if constexpr (BN == 64) {
            int gb = w * 64 + lane;        // B: 64 rows x 4 chunks = 256 slots
            gload16(BT + (size_t)(col0 + (gb >> 2)) * K + k0 + (gb & 3) * 8, &Bs[0][0] + w * 512);
        } else {
            int gb0 = 2 * w * 64 + lane;   // B: 128 rows x 4 chunks = 512 slots
            int gb1 = (2 * w + 1) * 64 + lane;
            gload16(BT + (size_t)(col0 + (gb0 >> 2)) * K + k0 + (gb0 & 3) * 8, &Bs[0][0] + 2 * w * 512);
            gload16(BT + (size_t)(col0 + (gb1 >> 2)) * K + k0 + (gb1 & 3) * 8, &Bs[0][0] + (2 * w + 1) * 512);
        }
        asm volatile("s_waitcnt vmcnt(0)" ::: "memory");
        __builtin_amdgcn_s_barrier();
        bf16x8 af[4], bfv[NJ];
#pragma unroll
        for (int i = 0; i < 4; ++i)
            af[i] = *(const bf16x8*)&As[0][(moff + i * 16 + l16) * 32 + quad * 8];
#pragma unroll
        for (int j = 0; j < NJ; ++j)
            bfv[j] = *(const bf16x8*)&Bs[0][(noff + j * 16 + l16) * 32 + quad * 8];
        asm volatile("s_waitcnt lgkmcnt(0)" ::: "memory");
        __builtin_amdgcn_sched_barrier(0);
#pragma unroll
        for (int i = 0; i < 4; ++i)
#pragma unroll
            for (int j = 0; j < NJ; ++j)
                acc[i][j] = __builtin_amdgcn_mfma_f32_16x16x32_bf16(af[i], bfv[j], acc[i][j], 0, 0, 0);
    }

    // ---- epilogue: repack C tile through LDS (As, now free) for 16B stores ----
    __syncthreads();                           // all waves' LDS reads complete
    int rquad = quad << 2;
    if (Cb) {
        // bf16 output tile [128][BN], 16B-chunk XOR swizzle (chunk ^= row&7)
        ushort_t* Ct = &As[0][0];              // BN=128: 32KB (all of As); BN=64: 16KB
#pragma unroll
        for (int j = 0; j < NJ; ++j) {
            int colL = noff + j * 16 + l16;
            float bv = bias ? bias[col0 + colL] : 0.0f;
#pragma unroll
            for (int i = 0; i < 4; ++i) {
#pragma unroll
                for (int r = 0; r < 4; ++r) {
                    int row = moff + i * 16 + rquad + r;
                    float v = acc[i][j][r] + bv;
                    if (do_gelu) v = gelu_f(v);
                    Ct[row * BN + ((((colL >> 3) ^ (row & 7)) << 3) | (colL & 7))] = f2b(v);
                }
            }
        }
        __syncthreads();
        constexpr int CPR = BN / 8;            // 16B chunks per row
        constexpr int NS = 128 * CPR / 256;    // chunks per thread (4 or 8)
#pragma unroll
        for (int s = 0; s < NS; ++s) {
            int c = t + 256 * s;
            int row = c / CPR, ch = c % CPR;
            bf16x8 val = *(const bf16x8*)&Ct[row * BN + ((ch ^ (row & 7)) << 3)];
            *(bf16x8*)&Cb[(size_t)(row0 + row) * N + col0 + ch * 8] = val;
        }
    } else if constexpr (BN == 64) {
        // fp32 output tile [128][64] (+vectorized residual), 4-float-chunk XOR swizzle
        float* Ctf = (float*)&As[0][0];        // 128*64*4B = 32KB (all of As)
#pragma unroll
        for (int j = 0; j < NJ; ++j) {
            int colL = noff + j * 16 + l16;
            float bv = bias ? bias[col0 + colL] : 0.0f;
#pragma unroll
            for (int i = 0; i < 4; ++i) {
#pragma unroll
                for (int r = 0; r < 4; ++r) {
                    int row = moff + i * 16 + rquad + r;
                    float v = acc[i][j][r] + bv;
                    if (do_gelu) v = gelu_f(v);
                    Ctf[row * 64 + ((((colL >> 2) ^ (row & 7)) << 2) | (colL & 3))] = v;
                }
            }
        }
        __syncthreads();
#pragma unroll
        for (int s = 0; s < 8; ++s) {          // 128 rows x 16 chunks / 256 threads
            int c = t + 256 * s;
            int row = c >> 4, ch = c & 15;
            floatx4 val = *(const floatx4*)&Ctf[row * 64 + ((ch ^ (row & 7)) << 2)];
            if (residual) {
                floatx4 rv = *(const floatx4*)&residual[(size_t)(row0 + row) * N + col0 + ch * 4];
                val += rv;
            }
            *(floatx4*)&Cf[(size_t)(row0 + row) * N + col0 + ch * 4] = val;
        }
    } else {
        // BN=128 fp32 path (unused by launcher): legacy scalar fallback
#pragma unroll
        for (int j = 0; j < NJ; ++j) {
            int col = col0 + noff + j * 16 + l16;
            float bv = bias ? bias[col] : 0.0f;
#pragma unroll
            for (int i = 0; i < 4; ++i) {
#pragma unroll
                for (int r = 0; r < 4; ++r) {
                    int row = row0 + moff + i * 16 + rquad + r;
                    float v = acc[i][j][r] + bv;
                    if (do_gelu) v = gelu_f(v);
                    if (residual) v += residual[(size_t)row * N + col];
                    if (Cf) Cf[(size_t)row * N + col] = v;
                }
            }
        }
    }
}

// ---------------- assemble tokens + embeddings -> h fp32 (float4 vectorized) ----------
__global__ void assemble_kernel(const float* __restrict__ obs,
                                const int* __restrict__ rtg,
                                const int* __restrict__ act,
                                const int* __restrict__ rew,
                                const float* __restrict__ retE,
                                const float* __restrict__ actE,
                                const float* __restrict__ rewE,
                                const float* __restrict__ posE,
                                const float* __restrict__ typeE,
                                float* __restrict__ h) {
    int idx = blockIdx.x * 256 + threadIdx.x;
    if (idx >= ROWS * (D_ / 4)) return;
    int d4 = idx & (D_ / 4 - 1);
    int bl = idx / (D_ / 4);
    int l = bl % L_, b = bl / L_;
    int t = l / S_, off = l % S_;
    int bt = b * T_ + t;
    floatx4 v;
    int ty;
    if (off < LOBS) {
        v = *(const floatx4*)&obs[((size_t)bt * LOBS + off) * D_ + d4 * 4];
        ty = 0;
    } else if (off == LOBS) {
        v = *(const floatx4*)&retE[(size_t)rtg[bt] * D_ + d4 * 4];
        ty = 1;
    } else if (off == LOBS + 1) {
        v = *(const floatx4*)&actE[(size_t)act[bt] * D_ + d4 * 4];
        ty = 2;
    } else {
        v = *(const floatx4*)&rewE[(size_t)rew[bt] * D_ + d4 * 4];
        ty = 3;
    }
    v += *(const floatx4*)&posE[(size_t)l * D_ + d4 * 4];
    v += *(const floatx4*)&typeE[(size_t)ty * D_ + d4 * 4];
    *(floatx4*)&h[(size_t)bl * D_ + d4 * 4] = v;
}

// ---------------- LayerNorm fp32 in -> bf16 out: one row per WAVE, no barriers -------
__global__ __launch_bounds__(256) void ln_fast(const float* __restrict__ x,
                                               const float* __restrict__ g,
                                               const float* __restrict__ bb,
                                               ushort_t* __restrict__ y) {
    int row = blockIdx.x * 4 + (threadIdx.x >> 6);
    int lane = threadIdx.x & 63;
    const float* xr = x + (size_t)row * D_ + lane * 8;
    floatx4 a = *(const floatx4*)xr;
    floatx4 c = *(const floatx4*)(xr + 4);
    float s = a[0] + a[1] + a[2] + a[3] + c[0] + c[1] + c[2] + c[3];
#pragma unroll
    for (int off = 1; off < 64; off <<= 1) s += __shfl_xor(s, off, 64);
    float mean = s * (1.0f / 512.0f);
    float vs = 0.f;
#pragma unroll
    for (int j = 0; j < 4; ++j) { float d = a[j] - mean; vs += d * d; }
#pragma unroll
    for (int j = 0; j < 4; ++j) { float d = c[j] - mean; vs += d * d; }
#pragma unroll
    for (int off = 1; off < 64; off <<= 1) vs += __shfl_xor(vs, off, 64);
    float rstd = rsqrtf(vs * (1.0f / 512.0f) + 1e-5f);
    const float* gp = g + lane * 8;
    const float* bp = bb + lane * 8;
    floatx4 g0 = *(const floatx4*)gp, g1 = *(const floatx4*)(gp + 4);
    floatx4 b0 = *(const floatx4*)bp, b1 = *(const floatx4*)(bp + 4);
    bf16x8 out;
#pragma unroll
    for (int j = 0; j < 4; ++j) out[j]     = (short)f2b((a[j] - mean) * rstd * g0[j] + b0[j]);
#pragma unroll
    for (int j = 0; j < 4; ++j) out[j + 4] = (short)f2b((c[j] - mean) * rstd * g1[j] + b1[j]);
    *(bf16x8*)&y[(size_t)row * D_ + lane * 8] = out;
}

// ---------------- V pre-transpose: 64x64 tiles, 16B loads/stores via LDS -------------
__global__ __launch_bounds__(256) void vt_prep(const ushort_t* __restrict__ qkvb,
                                               ushort_t* __restrict__ vtg)
{
    __shared__ ushort_t tile[64][72];          // pad 8: col-read conflict-free
    int bh = blockIdx.y; int b = bh >> 3, hh = bh & 7;
    int l0 = blockIdx.x * 64;
    int t = threadIdx.x;
    int rowl = t >> 2, c0 = (t & 3) * 16;
    int lsrc = l0 + rowl; if (lsrc >= L_) lsrc = L_ - 1;
    const ushort_t* src = &qkvb[((size_t)b * L_ + lsrc) * 1536 + 1024 + hh * 64 + c0];
    *(bf16x8*)&tile[rowl][c0]     = *(const bf16x8*)src;
    *(bf16x8*)&tile[rowl][c0 + 8] = *(const bf16x8*)(src + 8);
    __syncthreads();
#pragma unroll
    for (int s = 0; s < 2; ++s) {              // 64 d x 8 l-chunks = 512 / 256 threads
        int c = t + 256 * s;
        int d = c >> 3, lc = c & 7;
        int lg = l0 + lc * 8;
        if (lg < L_) {                         // L_%8==0: chunk fully valid or fully out
            bf16x8 v;
#pragma unroll
            for (int k = 0; k < 8; ++k) v[k] = (short)tile[lc * 8 + k][d];
            *(bf16x8*)&vtg[((size_t)bh * 64 + d) * L_ + lg] = v;
        }
    }
}

// ---------------- MFMA flash attention: LDS-staged K/V shared across waves, ----------
// ---------------- double-buffered global_load_lds prefetch, XOR-swizzled ------------
__global__ __launch_bounds__(256) void attn_mfma(const ushort_t* __restrict__ qkvb,
                                                 const ushort_t* __restrict__ vtg,
                                                 ushort_t* __restrict__ outb)
{
    int bh = blockIdx.x; int hh = bh & 7, b = bh >> 3;
    int qt = 19 - blockIdx.y;            // long blocks first (tail scheduling)
    int q0 = qt << 6;
    int t = threadIdx.x, lane = t & 63, w = t >> 6;
    int l16 = lane & 15, quad = lane >> 4;
    __shared__ ushort_t Ks[2][64 * 64];
    __shared__ ushort_t Vs[2][64 * 64];
    __shared__ ushort_t Ps[64][72];
    const ushort_t* base = qkvb + (size_t)b * (L_ * 1536);
    const ushort_t* vbase = vtg + (size_t)bh * 64 * L_;

    int qrow_l = q0 + w * 16 + l16; if (qrow_l >= L_) qrow_l = L_ - 1;
    const ushort_t* qp = base + (size_t)qrow_l * 1536 + hh * 64 + quad * 8;
    bf16x8 aq0 = *(const bf16x8*)qp;
    bf16x8 aq1 = *(const bf16x8*)(qp + 32);
    int qg[4], stepq[4], obsq[4];
#pragma unroll
    for (int r = 0; r < 4; ++r) {
        qg[r] = q0 + w * 16 + quad * 4 + r;
        stepq[r] = qg[r] / S_;
        obsq[r] = (qg[r] - stepq[r] * S_) < LOBS;
    }
    int qlast = q0 + 63; if (qlast > L_ - 1) qlast = L_ - 1;
    int kend_max = qlast;
    int we = (qlast / S_) * S_ + LOBS - 1;
    if (we > kend_max) kend_max = we;
    int ntiles = (kend_max >> 6) + 1;

    int sub = lane >> 3, jj = lane & 7;
    int jsw = jj ^ sub;                       // swizzled 16B-chunk (row&7 == sub)
    int rk0 = (w << 4) + sub, rk1 = rk0 + 8;
    const ushort_t* kcol = base + 512 + hh * 64 + jsw * 8;
    const ushort_t* vr0 = vbase + (size_t)rk0 * L_;
    const ushort_t* vr1 = vbase + (size_t)rk1 * L_;
    ushort_t* ldsK0 = &Ks[0][0] + (w << 10);
    ushort_t* ldsK1 = ldsK0 + 512;
    ushort_t* ldsV0 = &Vs[0][0] + (w << 10);
    ushort_t* ldsV1 = ldsV0 + 512;

    gload16(kcol + (size_t)rk0 * 1536, ldsK0);
    gload16(kcol + (size_t)rk1 * 1536, ldsK1);
    gload16(vr0 + jsw * 8, ldsV0);
    gload16(vr1 + jsw * 8, ldsV1);
    __syncthreads();

    float psum[4] = {0.f, 0.f, 0.f, 0.f};
    floatx4 O[4];
#pragma unroll
    for (int nb = 0; nb < 4; ++nb) O[nb] = (floatx4){0.f, 0.f, 0.f, 0.f};

    int swz = (quad ^ (l16 & 7)) << 4;        // read-side swizzled byte offset
    int buf = 0;
    for (int kt = 0; kt < ntiles; ++kt) {
        int nxt = buf ^ 1;
        if (kt + 1 < ntiles) {                // prefetch next tile (uniform branch)
            int k0n = (kt + 1) << 6;
            int g0 = k0n + rk0; if (g0 > L_ - 1) g0 = L_ - 1;
            int g1 = k0n + rk1; if (g1 > L_ - 1) g1 = L_ - 1;
            gload16(kcol + (size_t)g0 * 1536, ldsK0 + (nxt << 12));
            gload16(kcol + (size_t)g1 * 1536, ldsK1 + (nxt << 12));
            int cv = k0n + jsw * 8; if (cv > L_ - 8) cv = L_ - 8;
            gload16(vr0 + cv, ldsV0 + (nxt << 12));
            gload16(vr1 + cv, ldsV1 + (nxt << 12));
        }
        int k0 = kt << 6;
        const ushort_t* Kb = &Ks[0][0] + (buf << 12);
        const ushort_t* Vb = &Vs[0][0] + (buf << 12);
        floatx4 sc4[4];
        __builtin_amdgcn_s_setprio(1);
#pragma unroll
        for (int nb = 0; nb < 4; ++nb) {
            const char* kp = (const char*)(Kb + ((nb * 16 + l16) << 6));
            bf16x8 bk0 = *(const bf16x8*)(kp + swz);
            bf16x8 bk1 = *(const bf16x8*)(kp + (swz ^ 64));
            floatx4 z = (floatx4){0.f, 0.f, 0.f, 0.f};
            z = __builtin_amdgcn_mfma_f32_16x16x32_bf16(aq0, bk0, z, 0, 0, 0);
            z = __builtin_amdgcn_mfma_f32_16x16x32_bf16(aq1, bk1, z, 0, 0, 0);
            sc4[nb] = z;
        }
        __builtin_amdgcn_s_setprio(0);
        if (kt < qt) {
#pragma unroll
            for (int nb = 0; nb < 4; ++nb)
#pragma unroll
                for (int r = 0; r < 4; ++r) {
                    float p = __expf(sc4[nb][r] * 0.125f);
                    psum[r] += p;
                    Ps[w * 16 + quad * 4 + r][nb * 16 + l16] = f2b(p);
                }
        } else {
#pragma unroll
            for (int nb = 0; nb < 4; ++nb) {
                int kg = k0 + nb * 16 + l16;
                int stepk = kg / S_;
                int kobs = (kg - stepk * S_) < LOBS;
#pragma unroll
                for (int r = 0; r < 4; ++r) {
                    int allowed = (kg <= qg[r]) || (obsq[r] && kobs && (stepk == stepq[r]));
                    float p = allowed ? __expf(sc4[nb][r] * 0.125f) : 0.0f;
                    psum[r] += p;
                    Ps[w * 16 + quad * 4 + r][nb * 16 + l16] = f2b(p);
                }
            }
        }
        bf16x8 ap0 = *(const bf16x8*)&Ps[w * 16 + l16][quad * 8];
        bf16x8 ap1 = *(const bf16x8*)&Ps[w * 16 + l16][quad * 8 + 32];
        __builtin_amdgcn_s_setprio(1);
#pragma unroll
        for (int nb = 0; nb < 4; ++nb) {
            const char* vp = (const char*)(Vb + ((nb * 16 + l16) << 6));
            bf16x8 bv0 = *(const bf16x8*)(vp + swz);
            bf16x8 bv1 = *(const bf16x8*)(vp + (swz ^ 64));
            O[nb] = __builtin_amdgcn_mfma_f32_16x16x32_bf16(ap0, bv0, O[nb], 0, 0, 0);
            O[nb] = __builtin_amdgcn_mfma_f32_16x16x32_bf16(ap1, bv1, O[nb], 0, 0, 0);
        }
        __builtin_amdgcn_s_setprio(0);
        __syncthreads();    // drains the prefetch (vmcnt) + protects buffer reuse
        buf = nxt;
    }
#pragma unroll
    for (int off = 1; off < 16; off <<= 1)
#pragma unroll
        for (int r = 0; r < 4; ++r)
            psum[r] += __shfl_xor(psum[r], off, 64);
#pragma unroll
    for (int r = 0; r < 4; ++r) {
        if (qg[r] < L_) {
            float inv = 1.0f / psum[r];
#pragma unroll
            for (int nb = 0; nb < 4; ++nb)
                outb[((size_t)b * L_ + qg[r]) * 512 + hh * 64 + nb * 16 + l16] =
                    f2b(O[nb][r] * inv);
        }
    }
}

// ---------------- heads: LDS-staged, unrolled; one block per (b,t) ----------------
__global__ __launch_bounds__(256) void heads_fast(const float* __restrict__ h,
                            const float* __restrict__ hW_ret, const float* __restrict__ hb_ret,
                            const float* __restrict__ hW_act, const float* __restrict__ hb_act,
                            const float* __restrict__ hW_rew, const float* __restrict__ hb_rew,
                            float* __restrict__ out) {
    int bt = blockIdx.x;
    int b = bt >> 5, t = bt & 31;
    __shared__ float hr[D_], ha[D_], hw[D_];
    size_t base = ((size_t)b * L_ + (size_t)t * S_) * D_;
    int tid = threadIdx.x;
    for (int i = tid; i < D_; i += 256) {
        hr[i] = h[base + (size_t)(LOBS - 1) * D_ + i];
        ha[i] = h[base + (size_t)LOBS * D_ + i];
        hw[i] = h[base + (size_t)(LOBS + 1) * D_ + i];
    }
    __syncthreads();
    if (tid < NRET) {
        float acc = hb_ret[tid];
#pragma unroll 16
        for (int k = 0; k < D_; ++k) acc = fmaf(hr[k], hW_ret[(size_t)k * NRET + tid], acc);
        out[(size_t)bt * NRET + tid] = acc;
    } else if (tid < NRET + NACT) {
        int n = tid - NRET;
        float acc = hb_act[n];
#pragma unroll 16
        for (int k = 0; k < D_; ++k) acc = fmaf(ha[k], hW_act[(size_t)k * NACT + n], acc);
        out[(size_t)(B_ * T_ * NRET) + (size_t)bt * NACT + n] = acc;
    } else if (tid < NRET + NACT + NREW) {
        int n = tid - NRET - NACT;
        float acc = hb_rew[n];
#pragma unroll 16
        for (int k = 0; k < D_; ++k) acc = fmaf(hw[k], hW_rew[(size_t)k * NREW + n], acc);
        out[(size_t)(B_ * T_ * (NRET + NACT)) + (size_t)bt * NREW + n] = acc;
    }
}

static inline int cdiv_i(long long a, int b) { return (int)((a + b - 1) / b); }

extern "C" void kernel_launch(void* const* d_in, const int* in_sizes, int n_in,
                              void* d_out, int out_size, void* d_ws, size_t ws_size,
                              hipStream_t stream) {
    if (ws_size < (size_t)WS_FLOATS * sizeof(float)) {
        sentinel_kernel<<<(out_size + 255) / 256, 256, 0, stream>>>((float*)d_out, out_size);
        return;
    }
    const float* frames  = (const float*)d_in[0];
    const int*   rtg     = (const int*)d_in[1];
    const int*   actions = (const int*)d_in[2];
    const int*   rewards = (const int*)d_in[3];

    float* ws   = (float*)d_ws;
    float* h    = ws + OFF_H;
    ushort_t* ab1  = (ushort_t*)(ws + OFF_AB1);
    ushort_t* ab2  = (ushort_t*)(ws + OFF_AB2);
    ushort_t* qkvb = (ushort_t*)(ws + OFF_QKVB);
    ushort_t* ffnb = (ushort_t*)(ws + OFF_FFNB);
    ushort_t* vtg  = (ushort_t*)(ws + OFF_FFNB);
    ushort_t* xpb  = (ushort_t*)(ws + OFF_FFNB);
    float*    obs  = ws + OFF_FFNB + 3686400;
    ushort_t* wpatchT = (ushort_t*)(ws + OFF_WB);
    ushort_t* wqkvT = wpatchT + PKP * D_;
    ushort_t* woT   = wqkvT + NL_ * D_ * 3 * D_;
    ushort_t* w1T   = woT + NL_ * D_ * D_;
    ushort_t* w2T   = w1T + NL_ * D_ * DFF_;

    // ---- weight transpose + fp32->bf16 ----
    transpose_patchw_kernel<<<dim3(16, 25), 256, 0, stream>>>((const float*)d_in[4], wpatchT);
    transpose_cvt_kernel<<<dim3(48, 16, NL_), 256, 0, stream>>>((const float*)d_in[11], wqkvT, D_, 3 * D_);
    transpose_cvt_kernel<<<dim3(16, 16, NL_), 256, 0, stream>>>((const float*)d_in[13], woT, D_, D_);
    transpose_cvt_kernel<<<dim3(64, 16, NL_), 256, 0, stream>>>((const float*)d_in[19], w1T, D_, DFF_);
    transpose_cvt_kernel<<<dim3(16, 64, NL_), 256, 0, stream>>>((const float*)d_in[21], w2T, DFF_, D_);

    // ---- patchify + patch embed ----
    patchify_kernel<<<cdiv_i((long long)OBS_ROWS * PKP, 256), 256, 0, stream>>>(frames, xpb);
    gemm_mfma<64><<<dim3(D_ / 64, OBS_ROWS / 128), 256, 0, stream>>>(
        xpb, wpatchT, (const float*)d_in[5], nullptr, obs, nullptr, OBS_ROWS, D_, PKP, 0);

    // ---- assemble sequence ----
    assemble_kernel<<<cdiv_i((long long)ROWS * (D_ / 4), 256), 256, 0, stream>>>(
        obs, rtg, actions, rewards,
        (const float*)d_in[6], (const float*)d_in[7], (const float*)d_in[8],
        (const float*)d_in[9], (const float*)d_in[10], h);

    // ---- transformer layers ----
    for (int i = 0; i < NL_; ++i) {
        ln_fast<<<ROWS / 4, 256, 0, stream>>>(h, (const float*)d_in[15] + i * D_,
                                              (const float*)d_in[16] + i * D_, ab1);
        gemm_mfma<64><<<dim3(3 * D_ / 64, ROWS / 128), 256, 0, stream>>>(
            ab1, wqkvT + (size_t)i * D_ * 3 * D_, (const float*)d_in[12] + i * 3 * D_,
            nullptr, nullptr, qkvb, ROWS, 3 * D_, D_, 0);
        vt_prep<<<dim3(20, 64), 256, 0, stream>>>(qkvb, vtg);
        attn_mfma<<<dim3(64, 20), 256, 0, stream>>>(qkvb, vtg, ab2);
        gemm_mfma<64><<<dim3(D_ / 64, ROWS / 128), 256, 0, stream>>>(
            ab2, woT + (size_t)i * D_ * D_, (const float*)d_in[14] + i * D_,
            h, h, nullptr, ROWS, D_, D_, 0);
        ln_fast<<<ROWS / 4, 256, 0, stream>>>(h, (const float*)d_in[17] + i * D_,
                                              (const float*)d_in[18] + i * D_, ab1);
        gemm_mfma<128><<<dim3(DFF_ / 128, ROWS / 128), 256, 0, stream>>>(
            ab1, w1T + (size_t)i * D_ * DFF_, (const float*)d_in[20] + i * DFF_,
            nullptr, nullptr, ffnb, ROWS, DFF_, D_, 1);
        gemm_mfma<64><<<dim3(D_ / 64, ROWS / 128), 256, 0, stream>>>(
            ffnb, w2T + (size_t)i * DFF_ * D_, (const float*)d_in[22] + i * D_,
            h, h, nullptr, ROWS, D_, DFF_, 0);
    }

    // ---- heads ----
    heads_fast<<<B_ * T_, 256, 0, stream>>>(h,
        (const float*)d_in[23], (const float*)d_in[24],
        (const float*)d_in[25], (const float*)d_in[26],
        (const float*)d_in[27], (const float*)d_in[28], (float*)d_out);
}

// Round 11
// 1330.110 us; speedup vs baseline: 1.1683x; 1.0130x over previous
//
#include <hip/hip_runtime.h>
#include <hip/hip_bf16.h>
#include <math.h>

typedef unsigned short ushort_t;
typedef __attribute__((ext_vector_type(8))) short bf16x8;
typedef __attribute__((ext_vector_type(4))) float floatx4;

#define B_   8
#define T_   32
#define C_   4
#define HW_  84
#define P_   14
#define GP_  6
#define LOBS 36
#define S_   39
#define L_   (T_ * S_)          // 1248
#define D_   512
#define NH_  8
#define DH_  64
#define NL_  6
#define DFF_ 2048
#define NRET 120
#define NACT 18
#define NREW 3

#define ROWS (B_ * L_)          // 9984
#define OBS_ROWS (B_ * T_ * LOBS) // 9216
#define PK   (C_ * P_ * P_)     // 784
#define PKP  800                 // PK padded to %32

// workspace layout (float units)
#define OFF_H     0                         // fp32 9984*512
#define OFF_AB1   5111808                   // bf16 9984*512
#define OFF_AB2   (OFF_AB1 + 2555904)
#define OFF_QKVB  (OFF_AB2 + 2555904)       // bf16 9984*1536
#define OFF_FFNB  (OFF_QKVB + 7667712)      // bf16 9984*2048 (aliased: VtG / Xp+obs)
#define OFF_WB    (OFF_FFNB + 10223616)     // bf16 transposed weights
#define WS_FLOATS (OFF_WB + 9641984 + 16)

static __device__ __forceinline__ ushort_t f2b(float x) {
    union { float f; unsigned int u; } v; v.f = x;
    unsigned int r = v.u + 0x7FFFu + ((v.u >> 16) & 1u);
    return (ushort_t)(r >> 16);
}

// exact-GELU via Abramowitz-Stegun 7.1.26 erf (|err| <= 1.5e-7, far below bf16 ulp)
static __device__ __forceinline__ float gelu_f(float v) {
    float z = fabsf(v) * 0.70710678118654752f;
    float t = 1.0f / (1.0f + 0.3275911f * z);
    float p = fmaf(t, 1.061405429f, -1.453152027f);
    p = fmaf(t, p, 1.421413741f);
    p = fmaf(t, p, -0.284496736f);
    p = fmaf(t, p, 0.254829592f);
    float e = 1.0f - p * t * __expf(-z * z);
    float s = v < 0.0f ? -e : e;
    return 0.5f * v * (1.0f + s);
}

static __device__ __forceinline__ void gload16(const ushort_t* g, ushort_t* l) {
    __builtin_amdgcn_global_load_lds(
        (const __attribute__((address_space(1))) void*)g,
        (__attribute__((address_space(3))) void*)l, 16, 0, 0);
}

__global__ void sentinel_kernel(float* out, int n) {
    int i = blockIdx.x * 256 + threadIdx.x;
    if (i < n) out[i] = 100.0f;
}

// ---------------- weight transpose+convert: [K][N] fp32 -> [N][K] bf16, per layer -------
__global__ __launch_bounds__(256) void transpose_cvt_kernel(
    const float* __restrict__ src, ushort_t* __restrict__ dst, int K, int N)
{
    __shared__ float tile[32][33];
    int layer = blockIdx.z;
    int n0 = blockIdx.x * 32, k0 = blockIdx.y * 32;
    int tx = threadIdx.x & 31, ty = threadIdx.x >> 5;   // 32 x 8
    const float* s = src + (size_t)layer * K * N;
    ushort_t* d = dst + (size_t)layer * N * K;
#pragma unroll
    for (int r = 0; r < 32; r += 8)
        tile[ty + r][tx] = s[(size_t)(k0 + ty + r) * N + n0 + tx];
    __syncthreads();
#pragma unroll
    for (int r = 0; r < 32; r += 8)
        d[(size_t)(n0 + ty + r) * K + k0 + tx] = f2b(tile[tx][ty + r]);
}

// patch_W [784][512] fp32 -> [512][800] bf16 (k-pad zeros)
__global__ __launch_bounds__(256) void transpose_patchw_kernel(
    const float* __restrict__ src, ushort_t* __restrict__ dst)
{
    __shared__ float tile[32][33];
    int n0 = blockIdx.x * 32, k0 = blockIdx.y * 32;
    int tx = threadIdx.x & 31, ty = threadIdx.x >> 5;
#pragma unroll
    for (int r = 0; r < 32; r += 8) {
        int k = k0 + ty + r;
        tile[ty + r][tx] = (k < PK) ? src[(size_t)k * D_ + n0 + tx] : 0.0f;
    }
    __syncthreads();
#pragma unroll
    for (int r = 0; r < 32; r += 8)
        dst[(size_t)(n0 + ty + r) * PKP + k0 + tx] = f2b(tile[tx][ty + r]);
}

// ---------------- patchify: frames fp32 -> Xp bf16 (9216 x 800) ----------------
__global__ void patchify_kernel(const float* __restrict__ frames, ushort_t* __restrict__ Xp) {
    int idx = blockIdx.x * 256 + threadIdx.x;
    if (idx >= OBS_ROWS * PKP) return;
    int r = idx / PKP, c = idx % PKP;
    if (c >= PK) { Xp[idx] = 0; return; }
    int bt = r / LOBS, p = r % LOBS;
    int gy = p / GP_, gx = p % GP_;
    int ch = c / (P_ * P_), rem = c % (P_ * P_);
    int py = rem / P_, px = rem % P_;
    size_t src = (((size_t)bt * C_ + ch) * HW_ + gy * P_ + py) * HW_ + gx * P_ + px;
    Xp[idx] = f2b(frames[src]);
}

// ---------------- MFMA GEMM: 128xBN tile (BN=128 for FFN1, 64 elsewhere), -------------
// ---------------- BK=64, dbuf, SINGLE barrier per K-step (stage issued post-barrier, -
// ---------------- so the read-protect barrier is subsumed), XOR-swizzled LDS, ---------
// ---------------- XCD swizzle, LDS-repacked 16B epilogue. -----------------------------
template<int BN>
__global__ __launch_bounds__(256) void gemm_mfma(
    const ushort_t* __restrict__ A, const ushort_t* __restrict__ BT,
    const float* __restrict__ bias, const float* __restrict__ residual,
    float* __restrict__ Cf, ushort_t* __restrict__ Cb,
    int M, int N, int K, int do_gelu)
{
    constexpr int NJ = BN / 32;            // B frags / MFMA cols per wave (4 or 2)
    __shared__ ushort_t As[2][128 * 64];
    __shared__ ushort_t Bs[2][BN * 64];
    int t = threadIdx.x, lane = t & 63, w = t >> 6;

    // T1: bijective XCD swizzle (m204) -- consecutive blocks per XCD share A-panel
    int nx = gridDim.x;
    int nwg = nx * (int)gridDim.y;
    int orig = blockIdx.y * nx + blockIdx.x;
    int qq = nwg >> 3, rr = nwg & 7;
    int xcd = orig & 7, loc = orig >> 3;
    int wg = (xcd < rr ? xcd * (qq + 1) : rr * (qq + 1) + (xcd - rr) * qq) + loc;
    int row0 = (wg / nx) * 128, col0 = (wg % nx) * BN;

    // 4 waves as 2M x 2N; each wave 64 x (BN/2)
    int moff = (w & 1) << 6, noff = (w >> 1) * (BN / 2);
    int l16 = lane & 15, quad = lane >> 4;
    floatx4 acc[4][NJ];
#pragma unroll
    for (int i = 0; i < 4; ++i)
#pragma unroll
        for (int j = 0; j < NJ; ++j) acc[i][j] = (floatx4){0.f, 0.f, 0.f, 0.f};

    // staging: LDS linear [row][64] (128B rows); source pre-swizzled chunk^=row&7.
    int rsub = lane >> 3;
    int csw = (lane & 7) ^ rsub;
    const ushort_t* gA = A + (size_t)(row0 + w * 8 + rsub) * K + csw * 8;
    const ushort_t* gB = BT + (size_t)(col0 + w * 8 + rsub) * K + csw * 8;
    ushort_t* lA = &As[0][0] + w * 512;
    ushort_t* lB = &Bs[0][0] + w * 512;

    int nt = K >> 6;
    // prologue: tile 0 -> buf 0
#pragma unroll
    for (int s = 0; s < 4; ++s) gload16(gA + (size_t)s * 32 * K, lA + s * 2048);
#pragma unroll
    for (int s = 0; s < NJ; ++s) gload16(gB + (size_t)s * 32 * K, lB + s * 2048);

    int ch0 = (quad ^ (l16 & 7)) * 8;   // read-side swizzled chunk offset (ushorts), k-half 0
    for (int kt = 0; kt < nt; ++kt) {
        int cur = kt & 1, nxt = cur ^ 1;
        // stage-kt (issued last iter, ~1 iter in flight) complete -- own lanes...
        asm volatile("s_waitcnt vmcnt(0)" ::: "memory");
        // ...and everyone's; also: all reads of buf[nxt] (iter kt-1) are done
        // (each wave's lgkmcnt(0) preceded its MFMA preceded this barrier).
        __builtin_amdgcn_s_barrier();
        if (kt + 1 < nt) {                 // stage next tile into buf[nxt] (safe now)
            int k0n = (kt + 1) << 6;
#pragma unroll
            for (int s = 0; s < 4; ++s)
                gload16(gA + (size_t)s * 32 * K + k0n, lA + nxt * 8192 + s * 2048);
#pragma unroll
            for (int s = 0; s < NJ; ++s)
                gload16(gB + (size_t)s * 32 * K + k0n, lB + nxt * (BN * 64) + s * 2048);
        }
        bf16x8 af0[4], af1[4], bf0[NJ], bf1[NJ];
#pragma unroll
        for (int i = 0; i < 4; ++i) {
            const ushort_t* pa = &As[cur][(moff + i * 16 + l16) * 64];
            af0[i] = *(const bf16x8*)(pa + ch0);
            af1[i] = *(const bf16x8*)(pa + (ch0 ^ 32));
        }
#pragma unroll
        for (int j = 0; j < NJ; ++j) {
            const ushort_t* pb = &Bs[cur][(noff + j * 16 + l16) * 64];
            bf0[j] = *(const bf16x8*)(pb + ch0);
            bf1[j] = *(const bf16x8*)(pb + (ch0 ^ 32));
        }
        asm volatile("s_waitcnt lgkmcnt(0)" ::: "memory");
        __builtin_amdgcn_sched_barrier(0);     // rule #18: pin MFMA below the wait
        __builtin_amdgcn_s_setprio(1);
#pragma unroll
        for (int i = 0; i < 4; ++i)
#pragma unroll
            for (int j = 0; j < NJ; ++j) {
                acc[i][j] = __builtin_amdgcn_mfma_f32_16x16x32_bf16(af0[i], bf0[j], acc[i][j], 0, 0, 0);
                acc[i][j] = __builtin_amdgcn_mfma_f32_16x16x32_bf16(af1[i], bf1[j], acc[i][j], 0, 0, 0);
            }
        __builtin_amdgcn_s_setprio(0);
    }
    if (K & 32) {   // BK=32 tail (patch embed K=800); nt even -> buf0 idle since kt nt-2
        int k0 = nt << 6;
        int g0 = 2 * w * 64 + lane;        // A: 128 rows x 4 chunks = 512 slots
        int g1 = (2 * w + 1) * 64 + lane;
        gload16(A + (size_t)(row0 + (g0 >> 2)) * K + k0 + (g0 & 3) * 8, &As[0][0] + 2 * w * 512);
        gload16(A + (size_t)(row0 + (g1 >> 2)) * K + k0 + (g1 & 3) * 8, &As[0][0] + (2 * w + 1) * 512);
        if constexpr (BN == 64) {
            int gb = w * 64 + lane;        // B: 64 rows x 4 chunks = 256 slots
            gload16(BT + (size_t)(col0 + (gb >> 2)) * K + k0 + (gb & 3) * 8, &Bs[0][0] + w * 512);
        } else {
            int gb0 = 2 * w * 64 + lane;   // B: 128 rows x 4 chunks = 512 slots
            int gb1 = (2 * w + 1) * 64 + lane;
            gload16(BT + (size_t)(col0 + (gb0 >> 2)) * K + k0 + (gb0 & 3) * 8, &Bs[0][0] + 2 * w * 512);
            gload16(BT + (size_t)(col0 + (gb1 >> 2)) * K + k0 + (gb1 & 3) * 8, &Bs[0][0] + (2 * w + 1) * 512);
        }
        asm volatile("s_waitcnt vmcnt(0)" ::: "memory");
        __builtin_amdgcn_s_barrier();
        bf16x8 af[4], bfv[NJ];
#pragma unroll
        for (int i = 0; i < 4; ++i)
            af[i] = *(const bf16x8*)&As[0][(moff + i * 16 + l16) * 32 + quad * 8];
#pragma unroll
        for (int j = 0; j < NJ; ++j)
            bfv[j] = *(const bf16x8*)&Bs[0][(noff + j * 16 + l16) * 32 + quad * 8];
        asm volatile("s_waitcnt lgkmcnt(0)" ::: "memory");
        __builtin_amdgcn_sched_barrier(0);
#pragma unroll
        for (int i = 0; i < 4; ++i)
#pragma unroll
            for (int j = 0; j < NJ; ++j)
                acc[i][j] = __builtin_amdgcn_mfma_f32_16x16x32_bf16(af[i], bfv[j], acc[i][j], 0, 0, 0);
    }

    // ---- epilogue: repack C tile through LDS (As, now free) for 16B stores ----
    __syncthreads();                           // all waves' LDS reads complete
    int rquad = quad << 2;
    if (Cb) {
        // bf16 output tile [128][BN], 16B-chunk XOR swizzle (chunk ^= row&7)
        ushort_t* Ct = &As[0][0];              // BN=128: 32KB (all of As); BN=64: 16KB
#pragma unroll
        for (int j = 0; j < NJ; ++j) {
            int colL = noff + j * 16 + l16;
            float bv = bias ? bias[col0 + colL] : 0.0f;
#pragma unroll
            for (int i = 0; i < 4; ++i) {
#pragma unroll
                for (int r = 0; r < 4; ++r) {
                    int row = moff + i * 16 + rquad + r;
                    float v = acc[i][j][r] + bv;
                    if (do_gelu) v = gelu_f(v);
                    Ct[row * BN + ((((colL >> 3) ^ (row & 7)) << 3) | (colL & 7))] = f2b(v);
                }
            }
        }
        __syncthreads();
        constexpr int CPR = BN / 8;            // 16B chunks per row
        constexpr int NS = 128 * CPR / 256;    // chunks per thread (4 or 8)
#pragma unroll
        for (int s = 0; s < NS; ++s) {
            int c = t + 256 * s;
            int row = c / CPR, ch = c % CPR;
            bf16x8 val = *(const bf16x8*)&Ct[row * BN + ((ch ^ (row & 7)) << 3)];
            *(bf16x8*)&Cb[(size_t)(row0 + row) * N + col0 + ch * 8] = val;
        }
    } else if constexpr (BN == 64) {
        // fp32 output tile [128][64] (+vectorized residual), 4-float-chunk XOR swizzle
        float* Ctf = (float*)&As[0][0];        // 128*64*4B = 32KB (all of As)
#pragma unroll
        for (int j = 0; j < NJ; ++j) {
            int colL = noff + j * 16 + l16;
            float bv = bias ? bias[col0 + colL] : 0.0f;
#pragma unroll
            for (int i = 0; i < 4; ++i) {
#pragma unroll
                for (int r = 0; r < 4; ++r) {
                    int row = moff + i * 16 + rquad + r;
                    float v = acc[i][j][r] + bv;
                    if (do_gelu) v = gelu_f(v);
                    Ctf[row * 64 + ((((colL >> 2) ^ (row & 7)) << 2) | (colL & 3))] = v;
                }
            }
        }
        __syncthreads();
#pragma unroll
        for (int s = 0; s < 8; ++s) {          // 128 rows x 16 chunks / 256 threads
            int c = t + 256 * s;
            int row = c >> 4, ch = c & 15;
            floatx4 val = *(const floatx4*)&Ctf[row * 64 + ((ch ^ (row & 7)) << 2)];
            if (residual) {
                floatx4 rv = *(const floatx4*)&residual[(size_t)(row0 + row) * N + col0 + ch * 4];
                val += rv;
            }
            *(floatx4*)&Cf[(size_t)(row0 + row) * N + col0 + ch * 4] = val;
        }
    } else {
        // BN=128 fp32 path (unused by launcher): legacy scalar fallback
#pragma unroll
        for (int j = 0; j < NJ; ++j) {
            int col = col0 + noff + j * 16 + l16;
            float bv = bias ? bias[col] : 0.0f;
#pragma unroll
            for (int i = 0; i < 4; ++i) {
#pragma unroll
                for (int r = 0; r < 4; ++r) {
                    int row = row0 + moff + i * 16 + rquad + r;
                    float v = acc[i][j][r] + bv;
                    if (do_gelu) v = gelu_f(v);
                    if (residual) v += residual[(size_t)row * N + col];
                    if (Cf) Cf[(size_t)row * N + col] = v;
                }
            }
        }
    }
}

// ---------------- assemble tokens + embeddings -> h fp32 (float4 vectorized) ----------
__global__ void assemble_kernel(const float* __restrict__ obs,
                                const int* __restrict__ rtg,
                                const int* __restrict__ act,
                                const int* __restrict__ rew,
                                const float* __restrict__ retE,
                                const float* __restrict__ actE,
                                const float* __restrict__ rewE,
                                const float* __restrict__ posE,
                                const float* __restrict__ typeE,
                                float* __restrict__ h) {
    int idx = blockIdx.x * 256 + threadIdx.x;
    if (idx >= ROWS * (D_ / 4)) return;
    int d4 = idx & (D_ / 4 - 1);
    int bl = idx / (D_ / 4);
    int l = bl % L_, b = bl / L_;
    int t = l / S_, off = l % S_;
    int bt = b * T_ + t;
    floatx4 v;
    int ty;
    if (off < LOBS) {
        v = *(const floatx4*)&obs[((size_t)bt * LOBS + off) * D_ + d4 * 4];
        ty = 0;
    } else if (off == LOBS) {
        v = *(const floatx4*)&retE[(size_t)rtg[bt] * D_ + d4 * 4];
        ty = 1;
    } else if (off == LOBS + 1) {
        v = *(const floatx4*)&actE[(size_t)act[bt] * D_ + d4 * 4];
        ty = 2;
    } else {
        v = *(const floatx4*)&rewE[(size_t)rew[bt] * D_ + d4 * 4];
        ty = 3;
    }
    v += *(const floatx4*)&posE[(size_t)l * D_ + d4 * 4];
    v += *(const floatx4*)&typeE[(size_t)ty * D_ + d4 * 4];
    *(floatx4*)&h[(size_t)bl * D_ + d4 * 4] = v;
}

// ---------------- LayerNorm fp32 in -> bf16 out: one row per WAVE, no barriers -------
__global__ __launch_bounds__(256) void ln_fast(const float* __restrict__ x,
                                               const float* __restrict__ g,
                                               const float* __restrict__ bb,
                                               ushort_t* __restrict__ y) {
    int row = blockIdx.x * 4 + (threadIdx.x >> 6);
    int lane = threadIdx.x & 63;
    const float* xr = x + (size_t)row * D_ + lane * 8;
    floatx4 a = *(const floatx4*)xr;
    floatx4 c = *(const floatx4*)(xr + 4);
    float s = a[0] + a[1] + a[2] + a[3] + c[0] + c[1] + c[2] + c[3];
#pragma unroll
    for (int off = 1; off < 64; off <<= 1) s += __shfl_xor(s, off, 64);
    float mean = s * (1.0f / 512.0f);
    float vs = 0.f;
#pragma unroll
    for (int j = 0; j < 4; ++j) { float d = a[j] - mean; vs += d * d; }
#pragma unroll
    for (int j = 0; j < 4; ++j) { float d = c[j] - mean; vs += d * d; }
#pragma unroll
    for (int off = 1; off < 64; off <<= 1) vs += __shfl_xor(vs, off, 64);
    float rstd = rsqrtf(vs * (1.0f / 512.0f) + 1e-5f);
    const float* gp = g + lane * 8;
    const float* bp = bb + lane * 8;
    floatx4 g0 = *(const floatx4*)gp, g1 = *(const floatx4*)(gp + 4);
    floatx4 b0 = *(const floatx4*)bp, b1 = *(const floatx4*)(bp + 4);
    bf16x8 out;
#pragma unroll
    for (int j = 0; j < 4; ++j) out[j]     = (short)f2b((a[j] - mean) * rstd * g0[j] + b0[j]);
#pragma unroll
    for (int j = 0; j < 4; ++j) out[j + 4] = (short)f2b((c[j] - mean) * rstd * g1[j] + b1[j]);
    *(bf16x8*)&y[(size_t)row * D_ + lane * 8] = out;
}

// ---------------- V pre-transpose: 64x64 tiles, 16B loads/stores via LDS -------------
__global__ __launch_bounds__(256) void vt_prep(const ushort_t* __restrict__ qkvb,
                                               ushort_t* __restrict__ vtg)
{
    __shared__ ushort_t tile[64][72];          // pad 8: col-read conflict-free
    int bh = blockIdx.y; int b = bh >> 3, hh = bh & 7;
    int l0 = blockIdx.x * 64;
    int t = threadIdx.x;
    int rowl = t >> 2, c0 = (t & 3) * 16;
    int lsrc = l0 + rowl; if (lsrc >= L_) lsrc = L_ - 1;
    const ushort_t* src = &qkvb[((size_t)b * L_ + lsrc) * 1536 + 1024 + hh * 64 + c0];
    *(bf16x8*)&tile[rowl][c0]     = *(const bf16x8*)src;
    *(bf16x8*)&tile[rowl][c0 + 8] = *(const bf16x8*)(src + 8);
    __syncthreads();
#pragma unroll
    for (int s = 0; s < 2; ++s) {              // 64 d x 8 l-chunks = 512 / 256 threads
        int c = t + 256 * s;
        int d = c >> 3, lc = c & 7;
        int lg = l0 + lc * 8;
        if (lg < L_) {                         // L_%8==0: chunk fully valid or fully out
            bf16x8 v;
#pragma unroll
            for (int k = 0; k < 8; ++k) v[k] = (short)tile[lc * 8 + k][d];
            *(bf16x8*)&vtg[((size_t)bh * 64 + d) * L_ + lg] = v;
        }
    }
}

// ---------------- MFMA flash attention: LDS-staged K/V shared across waves, ----------
// ---------------- dbuf prefetch, SINGLE barrier per tile (vmcnt+bar at top, ----------
// ---------------- prefetch post-barrier), XOR-swizzled --------------------------------
__global__ __launch_bounds__(256) void attn_mfma(const ushort_t* __restrict__ qkvb,
                                                 const ushort_t* __restrict__ vtg,
                                                 ushort_t* __restrict__ outb)
{
    int bh = blockIdx.x; int hh = bh & 7, b = bh >> 3;
    int qt = 19 - blockIdx.y;            // long blocks first (tail scheduling)
    int q0 = qt << 6;
    int t = threadIdx.x, lane = t & 63, w = t >> 6;
    int l16 = lane & 15, quad = lane >> 4;
    __shared__ ushort_t Ks[2][64 * 64];
    __shared__ ushort_t Vs[2][64 * 64];
    __shared__ ushort_t Ps[64][72];
    const ushort_t* base = qkvb + (size_t)b * (L_ * 1536);
    const ushort_t* vbase = vtg + (size_t)bh * 64 * L_;

    int qrow_l = q0 + w * 16 + l16; if (qrow_l >= L_) qrow_l = L_ - 1;
    const ushort_t* qp = base + (size_t)qrow_l * 1536 + hh * 64 + quad * 8;
    bf16x8 aq0 = *(const bf16x8*)qp;
    bf16x8 aq1 = *(const bf16x8*)(qp + 32);
    int qg[4], stepq[4], obsq[4];
#pragma unroll
    for (int r = 0; r < 4; ++r) {
        qg[r] = q0 + w * 16 + quad * 4 + r;
        stepq[r] = qg[r] / S_;
        obsq[r] = (qg[r] - stepq[r] * S_) < LOBS;
    }
    int qlast = q0 + 63; if (qlast > L_ - 1) qlast = L_ - 1;
    int kend_max = qlast;
    int we = (qlast / S_) * S_ + LOBS - 1;
    if (we > kend_max) kend_max = we;
    int ntiles = (kend_max >> 6) + 1;

    int sub = lane >> 3, jj = lane & 7;
    int jsw = jj ^ sub;                       // swizzled 16B-chunk (row&7 == sub)
    int rk0 = (w << 4) + sub, rk1 = rk0 + 8;
    const ushort_t* kcol = base + 512 + hh * 64 + jsw * 8;
    const ushort_t* vr0 = vbase + (size_t)rk0 * L_;
    const ushort_t* vr1 = vbase + (size_t)rk1 * L_;
    ushort_t* ldsK0 = &Ks[0][0] + (w << 10);
    ushort_t* ldsK1 = ldsK0 + 512;
    ushort_t* ldsV0 = &Vs[0][0] + (w << 10);
    ushort_t* ldsV1 = ldsV0 + 512;

    // prologue: stage tile 0 into buffer 0 (completion handled at iter-0 top)
    gload16(kcol + (size_t)rk0 * 1536, ldsK0);
    gload16(kcol + (size_t)rk1 * 1536, ldsK1);
    gload16(vr0 + jsw * 8, ldsV0);
    gload16(vr1 + jsw * 8, ldsV1);

    float psum[4] = {0.f, 0.f, 0.f, 0.f};
    floatx4 O[4];
#pragma unroll
    for (int nb = 0; nb < 4; ++nb) O[nb] = (floatx4){0.f, 0.f, 0.f, 0.f};

    int swz = (quad ^ (l16 & 7)) << 4;        // read-side swizzled byte offset
    int buf = 0;
    for (int kt = 0; kt < ntiles; ++kt) {
        int nxt = buf ^ 1;
        // prefetch-kt (issued last iter / prologue) landed -- own, then all waves.
        // Also: all reads of buf[nxt] (iter kt-1) complete before this barrier.
        asm volatile("s_waitcnt vmcnt(0)" ::: "memory");
        __builtin_amdgcn_s_barrier();
        if (kt + 1 < ntiles) {                // prefetch next tile (uniform branch)
            int k0n = (kt + 1) << 6;
            int g0 = k0n + rk0; if (g0 > L_ - 1) g0 = L_ - 1;
            int g1 = k0n + rk1; if (g1 > L_ - 1) g1 = L_ - 1;
            gload16(kcol + (size_t)g0 * 1536, ldsK0 + (nxt << 12));
            gload16(kcol + (size_t)g1 * 1536, ldsK1 + (nxt << 12));
            int cv = k0n + jsw * 8; if (cv > L_ - 8) cv = L_ - 8;
            gload16(vr0 + cv, ldsV0 + (nxt << 12));
            gload16(vr1 + cv, ldsV1 + (nxt << 12));
        }
        int k0 = kt << 6;
        const ushort_t* Kb = &Ks[0][0] + (buf << 12);
        const ushort_t* Vb = &Vs[0][0] + (buf << 12);
        floatx4 sc4[4];
        __builtin_amdgcn_s_setprio(1);
#pragma unroll
        for (int nb = 0; nb < 4; ++nb) {
            const char* kp = (const char*)(Kb + ((nb * 16 + l16) << 6));
            bf16x8 bk0 = *(const bf16x8*)(kp + swz);
            bf16x8 bk1 = *(const bf16x8*)(kp + (swz ^ 64));
            floatx4 z = (floatx4){0.f, 0.f, 0.f, 0.f};
            z = __builtin_amdgcn_mfma_f32_16x16x32_bf16(aq0, bk0, z, 0, 0, 0);
            z = __builtin_amdgcn_mfma_f32_16x16x32_bf16(aq1, bk1, z, 0, 0, 0);
            sc4[nb] = z;
        }
        __builtin_amdgcn_s_setprio(0);
        if (kt < qt) {
#pragma unroll
            for (int nb = 0; nb < 4; ++nb)
#pragma unroll
                for (int r = 0; r < 4; ++r) {
                    float p = __expf(sc4[nb][r] * 0.125f);
                    psum[r] += p;
                    Ps[w * 16 + quad * 4 + r][nb * 16 + l16] = f2b(p);
                }
        } else {
#pragma unroll
            for (int nb = 0; nb < 4; ++nb) {
                int kg = k0 + nb * 16 + l16;
                int stepk = kg / S_;
                int kobs = (kg - stepk * S_) < LOBS;
#pragma unroll
                for (int r = 0; r < 4; ++r) {
                    int allowed = (kg <= qg[r]) || (obsq[r] && kobs && (stepk == stepq[r]));
                    float p = allowed ? __expf(sc4[nb][r] * 0.125f) : 0.0f;
                    psum[r] += p;
                    Ps[w * 16 + quad * 4 + r][nb * 16 + l16] = f2b(p);
                }
            }
        }
        // Ps rows are per-wave (write+read same wave) -- no barrier needed.
        bf16x8 ap0 = *(const bf16x8*)&Ps[w * 16 + l16][quad * 8];
        bf16x8 ap1 = *(const bf16x8*)&Ps[w * 16 + l16][quad * 8 + 32];
        __builtin_amdgcn_s_setprio(1);
#pragma unroll
        for (int nb = 0; nb < 4; ++nb) {
            const char* vp = (const char*)(Vb + ((nb * 16 + l16) << 6));
            bf16x8 bv0 = *(const bf16x8*)(vp + swz);
            bf16x8 bv1 = *(const bf16x8*)(vp + (swz ^ 64));
            O[nb] = __builtin_amdgcn_mfma_f32_16x16x32_bf16(ap0, bv0, O[nb], 0, 0, 0);
            O[nb] = __builtin_amdgcn_mfma_f32_16x16x32_bf16(ap1, bv1, O[nb], 0, 0, 0);
        }
        __builtin_amdgcn_s_setprio(0);
        buf = nxt;                             // no end barrier (top of next iter covers)
    }
#pragma unroll
    for (int off = 1; off < 16; off <<= 1)
#pragma unroll
        for (int r = 0; r < 4; ++r)
            psum[r] += __shfl_xor(psum[r], off, 64);
#pragma unroll
    for (int r = 0; r < 4; ++r) {
        if (qg[r] < L_) {
            float inv = 1.0f / psum[r];
#pragma unroll
            for (int nb = 0; nb < 4; ++nb)
                outb[((size_t)b * L_ + qg[r]) * 512 + hh * 64 + nb * 16 + l16] =
                    f2b(O[nb][r] * inv);
        }
    }
}

// ---------------- heads: LDS-staged, unrolled; one block per (b,t) ----------------
__global__ __launch_bounds__(256) void heads_fast(const float* __restrict__ h,
                            const float* __restrict__ hW_ret, const float* __restrict__ hb_ret,
                            const float* __restrict__ hW_act, const float* __restrict__ hb_act,
                            const float* __restrict__ hW_rew, const float* __restrict__ hb_rew,
                            float* __restrict__ out) {
    int bt = blockIdx.x;
    int b = bt >> 5, t = bt & 31;
    __shared__ float hr[D_], ha[D_], hw[D_];
    size_t base = ((size_t)b * L_ + (size_t)t * S_) * D_;
    int tid = threadIdx.x;
    for (int i = tid; i < D_; i += 256) {
        hr[i] = h[base + (size_t)(LOBS - 1) * D_ + i];
        ha[i] = h[base + (size_t)LOBS * D_ + i];
        hw[i] = h[base + (size_t)(LOBS + 1) * D_ + i];
    }
    __syncthreads();
    if (tid < NRET) {
        float acc = hb_ret[tid];
#pragma unroll 16
        for (int k = 0; k < D_; ++k) acc = fmaf(hr[k], hW_ret[(size_t)k * NRET + tid], acc);
        out[(size_t)bt * NRET + tid] = acc;
    } else if (tid < NRET + NACT) {
        int n = tid - NRET;
        float acc = hb_act[n];
#pragma unroll 16
        for (int k = 0; k < D_; ++k) acc = fmaf(ha[k], hW_act[(size_t)k * NACT + n], acc);
        out[(size_t)(B_ * T_ * NRET) + (size_t)bt * NACT + n] = acc;
    } else if (tid < NRET + NACT + NREW) {
        int n = tid - NRET - NACT;
        float acc = hb_rew[n];
#pragma unroll 16
        for (int k = 0; k < D_; ++k) acc = fmaf(hw[k], hW_rew[(size_t)k * NREW + n], acc);
        out[(size_t)(B_ * T_ * (NRET + NACT)) + (size_t)bt * NREW + n] = acc;
    }
}

static inline int cdiv_i(long long a, int b) { return (int)((a + b - 1) / b); }

extern "C" void kernel_launch(void* const* d_in, const int* in_sizes, int n_in,
                              void* d_out, int out_size, void* d_ws, size_t ws_size,
                              hipStream_t stream) {
    if (ws_size < (size_t)WS_FLOATS * sizeof(float)) {
        sentinel_kernel<<<(out_size + 255) / 256, 256, 0, stream>>>((float*)d_out, out_size);
        return;
    }
    const float* frames  = (const float*)d_in[0];
    const int*   rtg     = (const int*)d_in[1];
    const int*   actions = (const int*)d_in[2];
    const int*   rewards = (const int*)d_in[3];

    float* ws   = (float*)d_ws;
    float* h    = ws + OFF_H;
    ushort_t* ab1  = (ushort_t*)(ws + OFF_AB1);
    ushort_t* ab2  = (ushort_t*)(ws + OFF_AB2);
    ushort_t* qkvb = (ushort_t*)(ws + OFF_QKVB);
    ushort_t* ffnb = (ushort_t*)(ws + OFF_FFNB);
    ushort_t* vtg  = (ushort_t*)(ws + OFF_FFNB);
    ushort_t* xpb  = (ushort_t*)(ws + OFF_FFNB);
    float*    obs  = ws + OFF_FFNB + 3686400;
    ushort_t* wpatchT = (ushort_t*)(ws + OFF_WB);
    ushort_t* wqkvT = wpatchT + PKP * D_;
    ushort_t* woT   = wqkvT + NL_ * D_ * 3 * D_;
    ushort_t* w1T   = woT + NL_ * D_ * D_;
    ushort_t* w2T   = w1T + NL_ * D_ * DFF_;

    // ---- weight transpose + fp32->bf16 ----
    transpose_patchw_kernel<<<dim3(16, 25), 256, 0, stream>>>((const float*)d_in[4], wpatchT);
    transpose_cvt_kernel<<<dim3(48, 16, NL_), 256, 0, stream>>>((const float*)d_in[11], wqkvT, D_, 3 * D_);
    transpose_cvt_kernel<<<dim3(16, 16, NL_), 256, 0, stream>>>((const float*)d_in[13], woT, D_, D_);
    transpose_cvt_kernel<<<dim3(64, 16, NL_), 256, 0, stream>>>((const float*)d_in[19], w1T, D_, DFF_);
    transpose_cvt_kernel<<<dim3(16, 64, NL_), 256, 0, stream>>>((const float*)d_in[21], w2T, DFF_, D_);

    // ---- patchify + patch embed ----
    patchify_kernel<<<cdiv_i((long long)OBS_ROWS * PKP, 256), 256, 0, stream>>>(frames, xpb);
    gemm_mfma<64><<<dim3(D_ / 64, OBS_ROWS / 128), 256, 0, stream>>>(
        xpb, wpatchT, (const float*)d_in[5], nullptr, obs, nullptr, OBS_ROWS, D_, PKP, 0);

    // ---- assemble sequence ----
    assemble_kernel<<<cdiv_i((long long)ROWS * (D_ / 4), 256), 256, 0, stream>>>(
        obs, rtg, actions, rewards,
        (const float*)d_in[6], (const float*)d_in[7], (const float*)d_in[8],
        (const float*)d_in[9], (const float*)d_in[10], h);

    // ---- transformer layers ----
    for (int i = 0; i < NL_; ++i) {
        ln_fast<<<ROWS / 4, 256, 0, stream>>>(h, (const float*)d_in[15] + i * D_,
                                              (const float*)d_in[16] + i * D_, ab1);
        gemm_mfma<64><<<dim3(3 * D_ / 64, ROWS / 128), 256, 0, stream>>>(
            ab1, wqkvT + (size_t)i * D_ * 3 * D_, (const float*)d_in[12] + i * 3 * D_,
            nullptr, nullptr, qkvb, ROWS, 3 * D_, D_, 0);
        vt_prep<<<dim3(20, 64), 256, 0, stream>>>(qkvb, vtg);
        attn_mfma<<<dim3(64, 20), 256, 0, stream>>>(qkvb, vtg, ab2);
        gemm_mfma<64><<<dim3(D_ / 64, ROWS / 128), 256, 0, stream>>>(
            ab2, woT + (size_t)i * D_ * D_, (const float*)d_in[14] + i * D_,
            h, h, nullptr, ROWS, D_, D_, 0);
        ln_fast<<<ROWS / 4, 256, 0, stream>>>(h, (const float*)d_in[17] + i * D_,
                                              (const float*)d_in[18] + i * D_, ab1);
        gemm_mfma<128><<<dim3(DFF_ / 128, ROWS / 128), 256, 0, stream>>>(
            ab1, w1T + (size_t)i * D_ * DFF_, (const float*)d_in[20] + i * DFF_,
            nullptr, nullptr, ffnb, ROWS, DFF_, D_, 1);
        gemm_mfma<64><<<dim3(D_ / 64, ROWS / 128), 256, 0, stream>>>(
            ffnb, w2T + (size_t)i * DFF_ * D_, (const float*)d_in[22] + i * D_,
            h, h, nullptr, ROWS, D_, DFF_, 0);
    }

    // ---- heads ----
    heads_fast<<<B_ * T_, 256, 0, stream>>>(h,
        (const float*)d_in[23], (const float*)d_in[24],
        (const float*)d_in[25], (const float*)d_in[26],
        (const float*)d_in[27], (const float*)d_in[28], (float*)d_out);
}

// Round 12
// 1328.425 us; speedup vs baseline: 1.1698x; 1.0013x over previous
//
#include <hip/hip_runtime.h>
#include <hip/hip_bf16.h>
#include <math.h>

typedef unsigned short ushort_t;
typedef __attribute__((ext_vector_type(8))) short bf16x8;
typedef __attribute__((ext_vector_type(4))) float floatx4;

#define B_   8
#define T_   32
#define C_   4
#define HW_  84
#define P_   14
#define GP_  6
#define LOBS 36
#define S_   39
#define L_   (T_ * S_)          // 1248
#define D_   512
#define NH_  8
#define DH_  64
#define NL_  6
#define DFF_ 2048
#define NRET 120
#define NACT 18
#define NREW 3

#define ROWS (B_ * L_)          // 9984
#define OBS_ROWS (B_ * T_ * LOBS) // 9216
#define PK   (C_ * P_ * P_)     // 784
#define PKP  800                 // PK padded to %32

// workspace layout (float units)
#define OFF_H     0                         // fp32 9984*512
#define OFF_AB1   5111808                   // bf16 9984*512
#define OFF_AB2   (OFF_AB1 + 2555904)
#define OFF_QKVB  (OFF_AB2 + 2555904)       // bf16 9984*1536
#define OFF_FFNB  (OFF_QKVB + 7667712)      // bf16 9984*2048 (aliased: VtG / Xp+obs)
#define OFF_WB    (OFF_FFNB + 10223616)     // bf16 transposed weights
#define WS_FLOATS (OFF_WB + 9641984 + 16)

static __device__ __forceinline__ ushort_t f2b(float x) {
    union { float f; unsigned int u; } v; v.f = x;
    unsigned int r = v.u + 0x7FFFu + ((v.u >> 16) & 1u);
    return (ushort_t)(r >> 16);
}

// exact-GELU via Abramowitz-Stegun 7.1.26 erf (|err| <= 1.5e-7, far below bf16 ulp)
static __device__ __forceinline__ float gelu_f(float v) {
    float z = fabsf(v) * 0.70710678118654752f;
    float t = 1.0f / (1.0f + 0.3275911f * z);
    float p = fmaf(t, 1.061405429f, -1.453152027f);
    p = fmaf(t, p, 1.421413741f);
    p = fmaf(t, p, -0.284496736f);
    p = fmaf(t, p, 0.254829592f);
    float e = 1.0f - p * t * __expf(-z * z);
    float s = v < 0.0f ? -e : e;
    return 0.5f * v * (1.0f + s);
}

static __device__ __forceinline__ void gload16(const ushort_t* g, ushort_t* l) {
    __builtin_amdgcn_global_load_lds(
        (const __attribute__((address_space(1))) void*)g,
        (__attribute__((address_space(3))) void*)l, 16, 0, 0);
}

__global__ void sentinel_kernel(float* out, int n) {
    int i = blockIdx.x * 256 + threadIdx.x;
    if (i < n) out[i] = 100.0f;
}

// ---------------- weight transpose+convert: [K][N] fp32 -> [N][K] bf16, per layer -------
__global__ __launch_bounds__(256) void transpose_cvt_kernel(
    const float* __restrict__ src, ushort_t* __restrict__ dst, int K, int N)
{
    __shared__ float tile[32][33];
    int layer = blockIdx.z;
    int n0 = blockIdx.x * 32, k0 = blockIdx.y * 32;
    int tx = threadIdx.x & 31, ty = threadIdx.x >> 5;   // 32 x 8
    const float* s = src + (size_t)layer * K * N;
    ushort_t* d = dst + (size_t)layer * N * K;
#pragma unroll
    for (int r = 0; r < 32; r += 8)
        tile[ty + r][tx] = s[(size_t)(k0 + ty + r) * N + n0 + tx];
    __syncthreads();
#pragma unroll
    for (int r = 0; r < 32; r += 8)
        d[(size_t)(n0 + ty + r) * K + k0 + tx] = f2b(tile[tx][ty + r]);
}

// patch_W [784][512] fp32 -> [512][800] bf16 (k-pad zeros)
__global__ __launch_bounds__(256) void transpose_patchw_kernel(
    const float* __restrict__ src, ushort_t* __restrict__ dst)
{
    __shared__ float tile[32][33];
    int n0 = blockIdx.x * 32, k0 = blockIdx.y * 32;
    int tx = threadIdx.x & 31, ty = threadIdx.x >> 5;
#pragma unroll
    for (int r = 0; r < 32; r += 8) {
        int k = k0 + ty + r;
        tile[ty + r][tx] = (k < PK) ? src[(size_t)k * D_ + n0 + tx] : 0.0f;
    }
    __syncthreads();
#pragma unroll
    for (int r = 0; r < 32; r += 8)
        dst[(size_t)(n0 + ty + r) * PKP + k0 + tx] = f2b(tile[tx][ty + r]);
}

// ---------------- patchify: frames fp32 -> Xp bf16 (9216 x 800) ----------------
__global__ void patchify_kernel(const float* __restrict__ frames, ushort_t* __restrict__ Xp) {
    int idx = blockIdx.x * 256 + threadIdx.x;
    if (idx >= OBS_ROWS * PKP) return;
    int r = idx / PKP, c = idx % PKP;
    if (c >= PK) { Xp[idx] = 0; return; }
    int bt = r / LOBS, p = r % LOBS;
    int gy = p / GP_, gx = p % GP_;
    int ch = c / (P_ * P_), rem = c % (P_ * P_);
    int py = rem / P_, px = rem % P_;
    size_t src = (((size_t)bt * C_ + ch) * HW_ + gy * P_ + py) * HW_ + gx * P_ + px;
    Xp[idx] = f2b(frames[src]);
}

// ---------------- MFMA GEMM: 128xBN tile (BN=128 for FFN1, 64 elsewhere), -------------
// ---------------- BK=64, dbuf, SINGLE barrier per K-step, compiler-scheduled ----------
// ---------------- ds_read->MFMA interleave (no forced lgkm drain), XOR-swizzled LDS, --
// ---------------- XCD swizzle, LDS-repacked 16B epilogue. -----------------------------
template<int BN>
__global__ __launch_bounds__(256) void gemm_mfma(
    const ushort_t* __restrict__ A, const ushort_t* __restrict__ BT,
    const float* __restrict__ bias, const float* __restrict__ residual,
    float* __restrict__ Cf, ushort_t* __restrict__ Cb,
    int M, int N, int K, int do_gelu)
{
    constexpr int NJ = BN / 32;            // B frags / MFMA cols per wave (4 or 2)
    __shared__ ushort_t As[2][128 * 64];
    __shared__ ushort_t Bs[2][BN * 64];
    int t = threadIdx.x, lane = t & 63, w = t >> 6;

    // T1: bijective XCD swizzle (m204) -- consecutive blocks per XCD share A-panel
    int nx = gridDim.x;
    int nwg = nx * (int)gridDim.y;
    int orig = blockIdx.y * nx + blockIdx.x;
    int qq = nwg >> 3, rr = nwg & 7;
    int xcd = orig & 7, loc = orig >> 3;
    int wg = (xcd < rr ? xcd * (qq + 1) : rr * (qq + 1) + (xcd - rr) * qq) + loc;
    int row0 = (wg / nx) * 128, col0 = (wg % nx) * BN;

    // 4 waves as 2M x 2N; each wave 64 x (BN/2)
    int moff = (w & 1) << 6, noff = (w >> 1) * (BN / 2);
    int l16 = lane & 15, quad = lane >> 4;
    floatx4 acc[4][NJ];
#pragma unroll
    for (int i = 0; i < 4; ++i)
#pragma unroll
        for (int j = 0; j < NJ; ++j) acc[i][j] = (floatx4){0.f, 0.f, 0.f, 0.f};

    // staging: LDS linear [row][64] (128B rows); source pre-swizzled chunk^=row&7.
    int rsub = lane >> 3;
    int csw = (lane & 7) ^ rsub;
    const ushort_t* gA = A + (size_t)(row0 + w * 8 + rsub) * K + csw * 8;
    const ushort_t* gB = BT + (size_t)(col0 + w * 8 + rsub) * K + csw * 8;
    ushort_t* lA = &As[0][0] + w * 512;
    ushort_t* lB = &Bs[0][0] + w * 512;

    int nt = K >> 6;
    // prologue: tile 0 -> buf 0
#pragma unroll
    for (int s = 0; s < 4; ++s) gload16(gA + (size_t)s * 32 * K, lA + s * 2048);
#pragma unroll
    for (int s = 0; s < NJ; ++s) gload16(gB + (size_t)s * 32 * K, lB + s * 2048);

    int ch0 = (quad ^ (l16 & 7)) * 8;   // read-side swizzled chunk offset (ushorts), k-half 0
    for (int kt = 0; kt < nt; ++kt) {
        int cur = kt & 1, nxt = cur ^ 1;
        // stage-kt (issued last iter, ~1 iter in flight) complete -- own lanes...
        asm volatile("s_waitcnt vmcnt(0)" ::: "memory");
        // ...and everyone's; also: all reads of buf[nxt] (iter kt-1) are done
        // (each wave's compiler-inserted lgkm waits preceded its MFMAs preceded
        // this barrier).
        __builtin_amdgcn_s_barrier();
        if (kt + 1 < nt) {                 // stage next tile into buf[nxt] (safe now)
            int k0n = (kt + 1) << 6;
#pragma unroll
            for (int s = 0; s < 4; ++s)
                gload16(gA + (size_t)s * 32 * K + k0n, lA + nxt * 8192 + s * 2048);
#pragma unroll
            for (int s = 0; s < NJ; ++s)
                gload16(gB + (size_t)s * 32 * K + k0n, lB + nxt * (BN * 64) + s * 2048);
        }
        bf16x8 af0[4], af1[4], bf0[NJ], bf1[NJ];
#pragma unroll
        for (int i = 0; i < 4; ++i) {
            const ushort_t* pa = &As[cur][(moff + i * 16 + l16) * 64];
            af0[i] = *(const bf16x8*)(pa + ch0);
            af1[i] = *(const bf16x8*)(pa + (ch0 ^ 32));
        }
#pragma unroll
        for (int j = 0; j < NJ; ++j) {
            const ushort_t* pb = &Bs[cur][(noff + j * 16 + l16) * 64];
            bf0[j] = *(const bf16x8*)(pb + ch0);
            bf1[j] = *(const bf16x8*)(pb + (ch0 ^ 32));
        }
        // NO forced lgkmcnt(0) drain here: the compiler emits fine-grained
        // lgkmcnt(N) between each ds_read and its consuming MFMA (m97 behavior),
        // so MFMA-0 starts as soon as its fragments land and overlaps the rest.
        __builtin_amdgcn_s_setprio(1);
#pragma unroll
        for (int i = 0; i < 4; ++i)
#pragma unroll
            for (int j = 0; j < NJ; ++j) {
                acc[i][j] = __builtin_amdgcn_mfma_f32_16x16x32_bf16(af0[i], bf0[j], acc[i][j], 0, 0, 0);
                acc[i][j] = __builtin_amdgcn_mfma_f32_16x16x32_bf16(af1[i], bf1[j], acc[i][j], 0, 0, 0);
            }
        __builtin_amdgcn_s_setprio(0);
    }
    if (K & 32) {   // BK=32 tail (patch embed K=800); nt even -> buf0 idle since kt nt-2
        int k0 = nt << 6;
        int g0 = 2 * w * 64 + lane;        // A: 128 rows x 4 chunks = 512 slots
        int g1 = (2 * w + 1) * 64 + lane;
        gload16(A + (size_t)(row0 + (g0 >> 2)) * K + k0 + (g0 & 3) * 8, &As[0][0] + 2 * w * 512);
        gload16(A + (size_t)(row0 + (g1 >> 2)) * K + k0 + (g1 & 3) * 8, &As[0][0] + (2 * w + 1) * 512);
        if constexpr (BN == 64) {
            int gb = w * 64 + lane;        // B: 64 rows x 4 chunks = 256 slots
            gload16(BT + (size_t)(col0 + (gb >> 2)) * K + k0 + (gb & 3) * 8, &Bs[0][0] + w * 512);
        } else {
            int gb0 = 2 * w * 64 + lane;   // B: 128 rows x 4 chunks = 512 slots
            int gb1 = (2 * w + 1) * 64 + lane;
            gload16(BT + (size_t)(col0 + (gb0 >> 2)) * K + k0 + (gb0 & 3) * 8, &Bs[0][0] + 2 * w * 512);
            gload16(BT + (size_t)(col0 + (gb1 >> 2)) * K + k0 + (gb1 & 3) * 8, &Bs[0][0] + (2 * w + 1) * 512);
        }
        asm volatile("s_waitcnt vmcnt(0)" ::: "memory");
        __builtin_amdgcn_s_barrier();
        bf16x8 af[4], bfv[NJ];
#pragma unroll
        for (int i = 0; i < 4; ++i)
            af[i] = *(const bf16x8*)&As[0][(moff + i * 16 + l16) * 32 + quad * 8];
#pragma unroll
        for (int j = 0; j < NJ; ++j)
            bfv[j] = *(const bf16x8*)&Bs[0][(noff + j * 16 + l16) * 32 + quad * 8];
#pragma unroll
        for (int i = 0; i < 4; ++i)
#pragma unroll
            for (int j = 0; j < NJ; ++j)
                acc[i][j] = __builtin_amdgcn_mfma_f32_16x16x32_bf16(af[i], bfv[j], acc[i][j], 0, 0, 0);
    }

    // ---- epilogue: repack C tile through LDS (As, now free) for 16B stores ----
    __syncthreads();                           // all waves' LDS reads complete
    int rquad = quad << 2;
    if (Cb) {
        // bf16 output tile [128][BN], 16B-chunk XOR swizzle (chunk ^= row&7)
        ushort_t* Ct = &As[0][0];              // BN=128: 32KB (all of As); BN=64: 16KB
#pragma unroll
        for (int j = 0; j < NJ; ++j) {
            int colL = noff + j * 16 + l16;
            float bv = bias ? bias[col0 + colL] : 0.0f;
#pragma unroll
            for (int i = 0; i < 4; ++i) {
#pragma unroll
                for (int r = 0; r < 4; ++r) {
                    int row = moff + i * 16 + rquad + r;
                    float v = acc[i][j][r] + bv;
                    if (do_gelu) v = gelu_f(v);
                    Ct[row * BN + ((((colL >> 3) ^ (row & 7)) << 3) | (colL & 7))] = f2b(v);
                }
            }
        }
        __syncthreads();
        constexpr int CPR = BN / 8;            // 16B chunks per row
        constexpr int NS = 128 * CPR / 256;    // chunks per thread (4 or 8)
#pragma unroll
        for (int s = 0; s < NS; ++s) {
            int c = t + 256 * s;
            int row = c / CPR, ch = c % CPR;
            bf16x8 val = *(const bf16x8*)&Ct[row * BN + ((ch ^ (row & 7)) << 3)];
            *(bf16x8*)&Cb[(size_t)(row0 + row) * N + col0 + ch * 8] = val;
        }
    } else if constexpr (BN == 64) {
        // fp32 output tile [128][64] (+vectorized residual), 4-float-chunk XOR swizzle
        float* Ctf = (float*)&As[0][0];        // 128*64*4B = 32KB (all of As)
#pragma unroll
        for (int j = 0; j < NJ; ++j) {
            int colL = noff + j * 16 + l16;
            float bv = bias ? bias[col0 + colL] : 0.0f;
#pragma unroll
            for (int i = 0; i < 4; ++i) {
#pragma unroll
                for (int r = 0; r < 4; ++r) {
                    int row = moff + i * 16 + rquad + r;
                    float v = acc[i][j][r] + bv;
                    if (do_gelu) v = gelu_f(v);
                    Ctf[row * 64 + ((((colL >> 2) ^ (row & 7)) << 2) | (colL & 3))] = v;
                }
            }
        }
        __syncthreads();
#pragma unroll
        for (int s = 0; s < 8; ++s) {          // 128 rows x 16 chunks / 256 threads
            int c = t + 256 * s;
            int row = c >> 4, ch = c & 15;
            floatx4 val = *(const floatx4*)&Ctf[row * 64 + ((ch ^ (row & 7)) << 2)];
            if (residual) {
                floatx4 rv = *(const floatx4*)&residual[(size_t)(row0 + row) * N + col0 + ch * 4];
                val += rv;
            }
            *(floatx4*)&Cf[(size_t)(row0 + row) * N + col0 + ch * 4] = val;
        }
    } else {
        // BN=128 fp32 path (unused by launcher): legacy scalar fallback
#pragma unroll
        for (int j = 0; j < NJ; ++j) {
            int col = col0 + noff + j * 16 + l16;
            float bv = bias ? bias[col] : 0.0f;
#pragma unroll
            for (int i = 0; i < 4; ++i) {
#pragma unroll
                for (int r = 0; r < 4; ++r) {
                    int row = row0 + moff + i * 16 + rquad + r;
                    float v = acc[i][j][r] + bv;
                    if (do_gelu) v = gelu_f(v);
                    if (residual) v += residual[(size_t)row * N + col];
                    if (Cf) Cf[(size_t)row * N + col] = v;
                }
            }
        }
    }
}

// ---------------- assemble tokens + embeddings -> h fp32 (float4 vectorized) ----------
__global__ void assemble_kernel(const float* __restrict__ obs,
                                const int* __restrict__ rtg,
                                const int* __restrict__ act,
                                const int* __restrict__ rew,
                                const float* __restrict__ retE,
                                const float* __restrict__ actE,
                                const float* __restrict__ rewE,
                                const float* __restrict__ posE,
                                const float* __restrict__ typeE,
                                float* __restrict__ h) {
    int idx = blockIdx.x * 256 + threadIdx.x;
    if (idx >= ROWS * (D_ / 4)) return;
    int d4 = idx & (D_ / 4 - 1);
    int bl = idx / (D_ / 4);
    int l = bl % L_, b = bl / L_;
    int t = l / S_, off = l % S_;
    int bt = b * T_ + t;
    floatx4 v;
    int ty;
    if (off < LOBS) {
        v = *(const floatx4*)&obs[((size_t)bt * LOBS + off) * D_ + d4 * 4];
        ty = 0;
    } else if (off == LOBS) {
        v = *(const floatx4*)&retE[(size_t)rtg[bt] * D_ + d4 * 4];
        ty = 1;
    } else if (off == LOBS + 1) {
        v = *(const floatx4*)&actE[(size_t)act[bt] * D_ + d4 * 4];
        ty = 2;
    } else {
        v = *(const floatx4*)&rewE[(size_t)rew[bt] * D_ + d4 * 4];
        ty = 3;
    }
    v += *(const floatx4*)&posE[(size_t)l * D_ + d4 * 4];
    v += *(const floatx4*)&typeE[(size_t)ty * D_ + d4 * 4];
    *(floatx4*)&h[(size_t)bl * D_ + d4 * 4] = v;
}

// ---------------- LayerNorm fp32 in -> bf16 out: one row per WAVE, no barriers -------
__global__ __launch_bounds__(256) void ln_fast(const float* __restrict__ x,
                                               const float* __restrict__ g,
                                               const float* __restrict__ bb,
                                               ushort_t* __restrict__ y) {
    int row = blockIdx.x * 4 + (threadIdx.x >> 6);
    int lane = threadIdx.x & 63;
    const float* xr = x + (size_t)row * D_ + lane * 8;
    floatx4 a = *(const floatx4*)xr;
    floatx4 c = *(const floatx4*)(xr + 4);
    float s = a[0] + a[1] + a[2] + a[3] + c[0] + c[1] + c[2] + c[3];
#pragma unroll
    for (int off = 1; off < 64; off <<= 1) s += __shfl_xor(s, off, 64);
    float mean = s * (1.0f / 512.0f);
    float vs = 0.f;
#pragma unroll
    for (int j = 0; j < 4; ++j) { float d = a[j] - mean; vs += d * d; }
#pragma unroll
    for (int j = 0; j < 4; ++j) { float d = c[j] - mean; vs += d * d; }
#pragma unroll
    for (int off = 1; off < 64; off <<= 1) vs += __shfl_xor(vs, off, 64);
    float rstd = rsqrtf(vs * (1.0f / 512.0f) + 1e-5f);
    const float* gp = g + lane * 8;
    const float* bp = bb + lane * 8;
    floatx4 g0 = *(const floatx4*)gp, g1 = *(const floatx4*)(gp + 4);
    floatx4 b0 = *(const floatx4*)bp, b1 = *(const floatx4*)(bp + 4);
    bf16x8 out;
#pragma unroll
    for (int j = 0; j < 4; ++j) out[j]     = (short)f2b((a[j] - mean) * rstd * g0[j] + b0[j]);
#pragma unroll
    for (int j = 0; j < 4; ++j) out[j + 4] = (short)f2b((c[j] - mean) * rstd * g1[j] + b1[j]);
    *(bf16x8*)&y[(size_t)row * D_ + lane * 8] = out;
}

// ---------------- V pre-transpose: 64x64 tiles, 16B loads/stores via LDS -------------
__global__ __launch_bounds__(256) void vt_prep(const ushort_t* __restrict__ qkvb,
                                               ushort_t* __restrict__ vtg)
{
    __shared__ ushort_t tile[64][72];          // pad 8: col-read conflict-free
    int bh = blockIdx.y; int b = bh >> 3, hh = bh & 7;
    int l0 = blockIdx.x * 64;
    int t = threadIdx.x;
    int rowl = t >> 2, c0 = (t & 3) * 16;
    int lsrc = l0 + rowl; if (lsrc >= L_) lsrc = L_ - 1;
    const ushort_t* src = &qkvb[((size_t)b * L_ + lsrc) * 1536 + 1024 + hh * 64 + c0];
    *(bf16x8*)&tile[rowl][c0]     = *(const bf16x8*)src;
    *(bf16x8*)&tile[rowl][c0 + 8] = *(const bf16x8*)(src + 8);
    __syncthreads();
#pragma unroll
    for (int s = 0; s < 2; ++s) {              // 64 d x 8 l-chunks = 512 / 256 threads
        int c = t + 256 * s;
        int d = c >> 3, lc = c & 7;
        int lg = l0 + lc * 8;
        if (lg < L_) {                         // L_%8==0: chunk fully valid or fully out
            bf16x8 v;
#pragma unroll
            for (int k = 0; k < 8; ++k) v[k] = (short)tile[lc * 8 + k][d];
            *(bf16x8*)&vtg[((size_t)bh * 64 + d) * L_ + lg] = v;
        }
    }
}

// ---------------- MFMA flash attention: LDS-staged K/V shared across waves, ----------
// ---------------- dbuf prefetch, SINGLE barrier per tile (vmcnt+bar at top, ----------
// ---------------- prefetch post-barrier), XOR-swizzled --------------------------------
__global__ __launch_bounds__(256) void attn_mfma(const ushort_t* __restrict__ qkvb,
                                                 const ushort_t* __restrict__ vtg,
                                                 ushort_t* __restrict__ outb)
{
    int bh = blockIdx.x; int hh = bh & 7, b = bh >> 3;
    int qt = 19 - blockIdx.y;            // long blocks first (tail scheduling)
    int q0 = qt << 6;
    int t = threadIdx.x, lane = t & 63, w = t >> 6;
    int l16 = lane & 15, quad = lane >> 4;
    __shared__ ushort_t Ks[2][64 * 64];
    __shared__ ushort_t Vs[2][64 * 64];
    __shared__ ushort_t Ps[64][72];
    const ushort_t* base = qkvb + (size_t)b * (L_ * 1536);
    const ushort_t* vbase = vtg + (size_t)bh * 64 * L_;

    int qrow_l = q0 + w * 16 + l16; if (qrow_l >= L_) qrow_l = L_ - 1;
    const ushort_t* qp = base + (size_t)qrow_l * 1536 + hh * 64 + quad * 8;
    bf16x8 aq0 = *(const bf16x8*)qp;
    bf16x8 aq1 = *(const bf16x8*)(qp + 32);
    int qg[4], stepq[4], obsq[4];
#pragma unroll
    for (int r = 0; r < 4; ++r) {
        qg[r] = q0 + w * 16 + quad * 4 + r;
        stepq[r] = qg[r] / S_;
        obsq[r] = (qg[r] - stepq[r] * S_) < LOBS;
    }
    int qlast = q0 + 63; if (qlast > L_ - 1) qlast = L_ - 1;
    int kend_max = qlast;
    int we = (qlast / S_) * S_ + LOBS - 1;
    if (we > kend_max) kend_max = we;
    int ntiles = (kend_max >> 6) + 1;

    int sub = lane >> 3, jj = lane & 7;
    int jsw = jj ^ sub;                       // swizzled 16B-chunk (row&7 == sub)
    int rk0 = (w << 4) + sub, rk1 = rk0 + 8;
    const ushort_t* kcol = base + 512 + hh * 64 + jsw * 8;
    const ushort_t* vr0 = vbase + (size_t)rk0 * L_;
    const ushort_t* vr1 = vbase + (size_t)rk1 * L_;
    ushort_t* ldsK0 = &Ks[0][0] + (w << 10);
    ushort_t* ldsK1 = ldsK0 + 512;
    ushort_t* ldsV0 = &Vs[0][0] + (w << 10);
    ushort_t* ldsV1 = ldsV0 + 512;

    // prologue: stage tile 0 into buffer 0 (completion handled at iter-0 top)
    gload16(kcol + (size_t)rk0 * 1536, ldsK0);
    gload16(kcol + (size_t)rk1 * 1536, ldsK1);
    gload16(vr0 + jsw * 8, ldsV0);
    gload16(vr1 + jsw * 8, ldsV1);

    float psum[4] = {0.f, 0.f, 0.f, 0.f};
    floatx4 O[4];
#pragma unroll
    for (int nb = 0; nb < 4; ++nb) O[nb] = (floatx4){0.f, 0.f, 0.f, 0.f};

    int swz = (quad ^ (l16 & 7)) << 4;        // read-side swizzled byte offset
    int buf = 0;
    for (int kt = 0; kt < ntiles; ++kt) {
        int nxt = buf ^ 1;
        // prefetch-kt (issued last iter / prologue) landed -- own, then all waves.
        // Also: all reads of buf[nxt] (iter kt-1) complete before this barrier.
        asm volatile("s_waitcnt vmcnt(0)" ::: "memory");
        __builtin_amdgcn_s_barrier();
        if (kt + 1 < ntiles) {                // prefetch next tile (uniform branch)
            int k0n = (kt + 1) << 6;
            int g0 = k0n + rk0; if (g0 > L_ - 1) g0 = L_ - 1;
            int g1 = k0n + rk1; if (g1 > L_ - 1) g1 = L_ - 1;
            gload16(kcol + (size_t)g0 * 1536, ldsK0 + (nxt << 12));
            gload16(kcol + (size_t)g1 * 1536, ldsK1 + (nxt << 12));
            int cv = k0n + jsw * 8; if (cv > L_ - 8) cv = L_ - 8;
            gload16(vr0 + cv, ldsV0 + (nxt << 12));
            gload16(vr1 + cv, ldsV1 + (nxt << 12));
        }
        int k0 = kt << 6;
        const ushort_t* Kb = &Ks[0][0] + (buf << 12);
        const ushort_t* Vb = &Vs[0][0] + (buf << 12);
        floatx4 sc4[4];
        __builtin_amdgcn_s_setprio(1);
#pragma unroll
        for (int nb = 0; nb < 4; ++nb) {
            const char* kp = (const char*)(Kb + ((nb * 16 + l16) << 6));
            bf16x8 bk0 = *(const bf16x8*)(kp + swz);
            bf16x8 bk1 = *(const bf16x8*)(kp + (swz ^ 64));
            floatx4 z = (floatx4){0.f, 0.f, 0.f, 0.f};
            z = __builtin_amdgcn_mfma_f32_16x16x32_bf16(aq0, bk0, z, 0, 0, 0);
            z = __builtin_amdgcn_mfma_f32_16x16x32_bf16(aq1, bk1, z, 0, 0, 0);
            sc4[nb] = z;
        }
        __builtin_amdgcn_s_setprio(0);
        if (kt < qt) {
#pragma unroll
            for (int nb = 0; nb < 4; ++nb)
#pragma unroll
                for (int r = 0; r < 4; ++r) {
                    float p = __expf(sc4[nb][r] * 0.125f);
                    psum[r] += p;
                    Ps[w * 16 + quad * 4 + r][nb * 16 + l16] = f2b(p);
                }
        } else {
#pragma unroll
            for (int nb = 0; nb < 4; ++nb) {
                int kg = k0 + nb * 16 + l16;
                int stepk = kg / S_;
                int kobs = (kg - stepk * S_) < LOBS;
#pragma unroll
                for (int r = 0; r < 4; ++r) {
                    int allowed = (kg <= qg[r]) || (obsq[r] && kobs && (stepk == stepq[r]));
                    float p = allowed ? __expf(sc4[nb][r] * 0.125f) : 0.0f;
                    psum[r] += p;
                    Ps[w * 16 + quad * 4 + r][nb * 16 + l16] = f2b(p);
                }
            }
        }
        // Ps rows are per-wave (write+read same wave) -- no barrier needed.
        bf16x8 ap0 = *(const bf16x8*)&Ps[w * 16 + l16][quad * 8];
        bf16x8 ap1 = *(const bf16x8*)&Ps[w * 16 + l16][quad * 8 + 32];
        __builtin_amdgcn_s_setprio(1);
#pragma unroll
        for (int nb = 0; nb < 4; ++nb) {
            const char* vp = (const char*)(Vb + ((nb * 16 + l16) << 6));
            bf16x8 bv0 = *(const bf16x8*)(vp + swz);
            bf16x8 bv1 = *(const bf16x8*)(vp + (swz ^ 64));
            O[nb] = __builtin_amdgcn_mfma_f32_16x16x32_bf16(ap0, bv0, O[nb], 0, 0, 0);
            O[nb] = __builtin_amdgcn_mfma_f32_16x16x32_bf16(ap1, bv1, O[nb], 0, 0, 0);
        }
        __builtin_amdgcn_s_setprio(0);
        buf = nxt;                             // no end barrier (top of next iter covers)
    }
#pragma unroll
    for (int off = 1; off < 16; off <<= 1)
#pragma unroll
        for (int r = 0; r < 4; ++r)
            psum[r] += __shfl_xor(psum[r], off, 64);
#pragma unroll
    for (int r = 0; r < 4; ++r) {
        if (qg[r] < L_) {
            float inv = 1.0f / psum[r];
#pragma unroll
            for (int nb = 0; nb < 4; ++nb)
                outb[((size_t)b * L_ + qg[r]) * 512 + hh * 64 + nb * 16 + l16] =
                    f2b(O[nb][r] * inv);
        }
    }
}

// ---------------- heads: LDS-staged, unrolled; one block per (b,t) ----------------
__global__ __launch_bounds__(256) void heads_fast(const float* __restrict__ h,
                            const float* __restrict__ hW_ret, const float* __restrict__ hb_ret,
                            const float* __restrict__ hW_act, const float* __restrict__ hb_act,
                            const float* __restrict__ hW_rew, const float* __restrict__ hb_rew,
                            float* __restrict__ out) {
    int bt = blockIdx.x;
    int b = bt >> 5, t = bt & 31;
    __shared__ float hr[D_], ha[D_], hw[D_];
    size_t base = ((size_t)b * L_ + (size_t)t * S_) * D_;
    int tid = threadIdx.x;
    for (int i = tid; i < D_; i += 256) {
        hr[i] = h[base + (size_t)(LOBS - 1) * D_ + i];
        ha[i] = h[base + (size_t)LOBS * D_ + i];
        hw[i] = h[base + (size_t)(LOBS + 1) * D_ + i];
    }
    __syncthreads();
    if (tid < NRET) {
        float acc = hb_ret[tid];
#pragma unroll 16
        for (int k = 0; k < D_; ++k) acc = fmaf(hr[k], hW_ret[(size_t)k * NRET + tid], acc);
        out[(size_t)bt * NRET + tid] = acc;
    } else if (tid < NRET + NACT) {
        int n = tid - NRET;
        float acc = hb_act[n];
#pragma unroll 16
        for (int k = 0; k < D_; ++k) acc = fmaf(ha[k], hW_act[(size_t)k * NACT + n], acc);
        out[(size_t)(B_ * T_ * NRET) + (size_t)bt * NACT + n] = acc;
    } else if (tid < NRET + NACT + NREW) {
        int n = tid - NRET - NACT;
        float acc = hb_rew[n];
#pragma unroll 16
        for (int k = 0; k < D_; ++k) acc = fmaf(hw[k], hW_rew[(size_t)k * NREW + n], acc);
        out[(size_t)(B_ * T_ * (NRET + NACT)) + (size_t)bt * NREW + n] = acc;
    }
}

static inline int cdiv_i(long long a, int b) { return (int)((a + b - 1) / b); }

extern "C" void kernel_launch(void* const* d_in, const int* in_sizes, int n_in,
                              void* d_out, int out_size, void* d_ws, size_t ws_size,
                              hipStream_t stream) {
    if (ws_size < (size_t)WS_FLOATS * sizeof(float)) {
        sentinel_kernel<<<(out_size + 255) / 256, 256, 0, stream>>>((float*)d_out, out_size);
        return;
    }
    const float* frames  = (const float*)d_in[0];
    const int*   rtg     = (const int*)d_in[1];
    const int*   actions = (const int*)d_in[2];
    const int*   rewards = (const int*)d_in[3];

    float* ws   = (float*)d_ws;
    float* h    = ws + OFF_H;
    ushort_t* ab1  = (ushort_t*)(ws + OFF_AB1);
    ushort_t* ab2  = (ushort_t*)(ws + OFF_AB2);
    ushort_t* qkvb = (ushort_t*)(ws + OFF_QKVB);
    ushort_t* ffnb = (ushort_t*)(ws + OFF_FFNB);
    ushort_t* vtg  = (ushort_t*)(ws + OFF_FFNB);
    ushort_t* xpb  = (ushort_t*)(ws + OFF_FFNB);
    float*    obs  = ws + OFF_FFNB + 3686400;
    ushort_t* wpatchT = (ushort_t*)(ws + OFF_WB);
    ushort_t* wqkvT = wpatchT + PKP * D_;
    ushort_t* woT   = wqkvT + NL_ * D_ * 3 * D_;
    ushort_t* w1T   = woT + NL_ * D_ * D_;
    ushort_t* w2T   = w1T + NL_ * D_ * DFF_;

    // ---- weight transpose + fp32->bf16 ----
    transpose_patchw_kernel<<<dim3(16, 25), 256, 0, stream>>>((const float*)d_in[4], wpatchT);
    transpose_cvt_kernel<<<dim3(48, 16, NL_), 256, 0, stream>>>((const float*)d_in[11], wqkvT, D_, 3 * D_);
    transpose_cvt_kernel<<<dim3(16, 16, NL_), 256, 0, stream>>>((const float*)d_in[13], woT, D_, D_);
    transpose_cvt_kernel<<<dim3(64, 16, NL_), 256, 0, stream>>>((const float*)d_in[19], w1T, D_, DFF_);
    transpose_cvt_kernel<<<dim3(16, 64, NL_), 256, 0, stream>>>((const float*)d_in[21], w2T, DFF_, D_);

    // ---- patchify + patch embed ----
    patchify_kernel<<<cdiv_i((long long)OBS_ROWS * PKP, 256), 256, 0, stream>>>(frames, xpb);
    gemm_mfma<64><<<dim3(D_ / 64, OBS_ROWS / 128), 256, 0, stream>>>(
        xpb, wpatchT, (const float*)d_in[5], nullptr, obs, nullptr, OBS_ROWS, D_, PKP, 0);

    // ---- assemble sequence ----
    assemble_kernel<<<cdiv_i((long long)ROWS * (D_ / 4), 256), 256, 0, stream>>>(
        obs, rtg, actions, rewards,
        (const float*)d_in[6], (const float*)d_in[7], (const float*)d_in[8],
        (const float*)d_in[9], (const float*)d_in[10], h);

    // ---- transformer layers ----
    for (int i = 0; i < NL_; ++i) {
        ln_fast<<<ROWS / 4, 256, 0, stream>>>(h, (const float*)d_in[15] + i * D_,
                                              (const float*)d_in[16] + i * D_, ab1);
        gemm_mfma<64><<<dim3(3 * D_ / 64, ROWS / 128), 256, 0, stream>>>(
            ab1, wqkvT + (size_t)i * D_ * 3 * D_, (const float*)d_in[12] + i * 3 * D_,
            nullptr, nullptr, qkvb, ROWS, 3 * D_, D_, 0);
        vt_prep<<<dim3(20, 64), 256, 0, stream>>>(qkvb, vtg);
        attn_mfma<<<dim3(64, 20), 256, 0, stream>>>(qkvb, vtg, ab2);
        gemm_mfma<64><<<dim3(D_ / 64, ROWS / 128), 256, 0, stream>>>(
            ab2, woT + (size_t)i * D_ * D_, (const float*)d_in[14] + i * D_,
            h, h, nullptr, ROWS, D_, D_, 0);
        ln_fast<<<ROWS / 4, 256, 0, stream>>>(h, (const float*)d_in[17] + i * D_,
                                              (const float*)d_in[18] + i * D_, ab1);
        gemm_mfma<128><<<dim3(DFF_ / 128, ROWS / 128), 256, 0, stream>>>(
            ab1, w1T + (size_t)i * D_ * DFF_, (const float*)d_in[20] + i * DFF_,
            nullptr, nullptr, ffnb, ROWS, DFF_, D_, 1);
        gemm_mfma<64><<<dim3(D_ / 64, ROWS / 128), 256, 0, stream>>>(
            ffnb, w2T + (size_t)i * DFF_ * D_, (const float*)d_in[22] + i * D_,
            h, h, nullptr, ROWS, D_, DFF_, 0);
    }

    // ---- heads ----
    heads_fast<<<B_ * T_, 256, 0, stream>>>(h,
        (const float*)d_in[23], (const float*)d_in[24],
        (const float*)d_in[25], (const float*)d_in[26],
        (const float*)d_in[27], (const float*)d_in[28], (float*)d_out);
}